// Round 2
// baseline (1512.007 us; speedup 1.0000x reference)
//
#include <hip/hip_runtime.h>
#include <cmath>

#define CDIV(a,b) (((a)+(b)-1)/(b))

typedef unsigned short bf16_t;

__device__ __forceinline__ float bf2f(unsigned short b) {
    unsigned u = ((unsigned)b) << 16;
    float f;
    __builtin_memcpy(&f, &u, 4);
    return f;
}
__device__ __forceinline__ unsigned short f2bf(float f) {
    unsigned u;
    __builtin_memcpy(&u, &f, 4);
    u = (u + 0x7FFFu + ((u >> 16) & 1u)) >> 16;
    return (unsigned short)u;
}

// ---------------- edge-index width detection ----------------
// If edge_index is int64 on device, every odd int32 word is the (zero) high
// half of a value < 2^31. 64 random int32 node ids being all zero: P ~ 0.
__global__ void k_detect(const int* __restrict__ ei, int* __restrict__ flag) {
    int t = threadIdx.x;  // 64 threads
    unsigned v = (unsigned)ei[2 * t + 1];
    unsigned long long m = __ballot(v != 0u);
    if (t == 0) *flag = (m == 0ULL) ? 1 : 0;  // 1 => int64 layout
}

__device__ __forceinline__ int edge_src(const int* ei, int E, int f, int i) {
    return f ? ei[2 * (size_t)i] : ei[i];
}
__device__ __forceinline__ int edge_dst(const int* ei, int E, int f, int i) {
    return f ? ei[2 * ((size_t)E + (size_t)i)] : ei[(size_t)E + (size_t)i];
}

// ---------------- CSR build ----------------

__global__ void k_hist(const int* __restrict__ ei, int E, const int* __restrict__ flag,
                       int* __restrict__ cnt, int N) {
    int i = blockIdx.x * 256 + threadIdx.x;
    if (i >= E) return;
    int d = edge_dst(ei, E, *flag, i);
    if ((unsigned)d < (unsigned)N) atomicAdd(&cnt[d], 1);
}

__global__ void k_blockred(const int* __restrict__ cnt, int* __restrict__ bsum, int total) {
    __shared__ int sd[256];
    int b = blockIdx.x, t = threadIdx.x;
    int base = b * 1024 + t * 4;
    int s = 0;
#pragma unroll
    for (int i = 0; i < 4; i++) { int idx = base + i; if (idx < total) s += cnt[idx]; }
    sd[t] = s; __syncthreads();
    for (int off = 128; off > 0; off >>= 1) { if (t < off) sd[t] += sd[t + off]; __syncthreads(); }
    if (t == 0) bsum[b] = sd[0];
}

__global__ void k_scanpartials(int* bsum, int nb) {
    __shared__ int sd[256];
    int t = threadIdx.x;
    int v = (t < nb) ? bsum[t] : 0;
    sd[t] = v; __syncthreads();
    for (int off = 1; off < 256; off <<= 1) {
        int y = (t >= off) ? sd[t - off] : 0;
        __syncthreads();
        sd[t] += y;
        __syncthreads();
    }
    if (t < nb) bsum[t] = sd[t] - v;   // exclusive
}

__global__ void k_scanwrite(const int* __restrict__ cnt, const int* __restrict__ bsum,
                            int* __restrict__ rowptr, int* __restrict__ cursor,
                            float* __restrict__ dis, int total, int N) {
    __shared__ int sd[256];
    int b = blockIdx.x, t = threadIdx.x;
    int base = b * 1024 + t * 4;
    int v[4]; int s = 0;
#pragma unroll
    for (int i = 0; i < 4; i++) { int idx = base + i; v[i] = (idx < total) ? cnt[idx] : 0; s += v[i]; }
    sd[t] = s; __syncthreads();
    for (int off = 1; off < 256; off <<= 1) {
        int y = (t >= off) ? sd[t - off] : 0;
        __syncthreads();
        sd[t] += y;
        __syncthreads();
    }
    int pre = bsum[b] + sd[t] - s;
#pragma unroll
    for (int i = 0; i < 4; i++) {
        int idx = base + i;
        if (idx < total) {
            rowptr[idx] = pre;
            if (idx < N) { cursor[idx] = pre; dis[idx] = rsqrtf((float)v[i] + 1.0f); }
            pre += v[i];
        }
    }
}

__global__ void k_fill(const int* __restrict__ ei, int E, const int* __restrict__ flag,
                       int* __restrict__ cursor, int* __restrict__ csr, int N) {
    int i = blockIdx.x * 256 + threadIdx.x;
    if (i >= E) return;
    int f = *flag;
    int s = edge_src(ei, E, f, i);
    int d = edge_dst(ei, E, f, i);
    if ((unsigned)d < (unsigned)N && (unsigned)s < (unsigned)N) {
        int p = atomicAdd(&cursor[d], 1);
        csr[p] = s;
    }
}

// ---------------- fp32-accumulate GEMM: C[i][j] = sum_k A[i][k] * W[j][k] ----
// A: [N,K] row-major (f32 or bf16), W: [M,K] row-major f32.
// BM=BN=64, 256 threads, 4x4 microtile. ACT: 0=none, 1=leaky-relu.

template <int BK, bool ABF, bool CBF, bool BIAS, int ACT>
__global__ __launch_bounds__(256) void gemm_nt(
        const void* __restrict__ Av, const float* __restrict__ W,
        const float* __restrict__ bias, void* __restrict__ Cv,
        int N, int K, int M) {
    constexpr int BM = 64, BN = 64;
    constexpr int CH = BK / 4;          // 4-elem chunks per tile-row
    constexpr int NL = BM * CH;
    __shared__ __align__(16) float As[BK][BM + 4];
    __shared__ __align__(16) float Bs[BK][BN + 4];
    int t = threadIdx.x;
    int tx = t & 15, ty = t >> 4;
    int bm0 = blockIdx.x * BM;
    int bn0 = blockIdx.y * BN;
    float acc[4][4] = {};

    for (int k0 = 0; k0 < K; k0 += BK) {
        for (int idx = t; idx < NL; idx += 256) {
            int row = idx / CH, kc = (idx % CH) * 4;
            int g = bm0 + row;
            float x0 = 0.f, x1 = 0.f, x2 = 0.f, x3 = 0.f;
            if (g < N) {
                if (ABF) {
                    const bf16_t* A = (const bf16_t*)Av;
                    ushort4 v = *(const ushort4*)&A[(size_t)g * K + k0 + kc];
                    x0 = bf2f(v.x); x1 = bf2f(v.y); x2 = bf2f(v.z); x3 = bf2f(v.w);
                } else {
                    const float* A = (const float*)Av;
                    float4 v = *(const float4*)&A[(size_t)g * K + k0 + kc];
                    x0 = v.x; x1 = v.y; x2 = v.z; x3 = v.w;
                }
            }
            As[kc + 0][row] = x0; As[kc + 1][row] = x1;
            As[kc + 2][row] = x2; As[kc + 3][row] = x3;
        }
        for (int idx = t; idx < NL; idx += 256) {
            int row = idx / CH, kc = (idx % CH) * 4;
            int g = bn0 + row;
            float4 v = make_float4(0.f, 0.f, 0.f, 0.f);
            if (g < M) v = *(const float4*)&W[(size_t)g * K + k0 + kc];
            Bs[kc + 0][row] = v.x; Bs[kc + 1][row] = v.y;
            Bs[kc + 2][row] = v.z; Bs[kc + 3][row] = v.w;
        }
        __syncthreads();
#pragma unroll
        for (int kk = 0; kk < BK; kk++) {
            float4 a = *(const float4*)&As[kk][ty * 4];
            float4 b = *(const float4*)&Bs[kk][tx * 4];
            float av[4] = {a.x, a.y, a.z, a.w};
            float bv[4] = {b.x, b.y, b.z, b.w};
#pragma unroll
            for (int m = 0; m < 4; m++)
#pragma unroll
                for (int n = 0; n < 4; n++) acc[m][n] += av[m] * bv[n];
        }
        __syncthreads();
    }

#pragma unroll
    for (int m = 0; m < 4; m++) {
        int r = bm0 + ty * 4 + m;
        if (r >= N) continue;
        int c = bn0 + tx * 4;
        if (c + 3 >= M) continue;     // M always multiple of 64 here
        float vv[4];
#pragma unroll
        for (int n = 0; n < 4; n++) {
            float x = acc[m][n];
            if (BIAS) x += bias[c + n];
            if (ACT == 1) x = x > 0.f ? x : 0.1f * x;
            vv[n] = x;
        }
        if (CBF) {
            bf16_t* C = (bf16_t*)Cv;
            ushort4 o;
            o.x = f2bf(vv[0]); o.y = f2bf(vv[1]); o.z = f2bf(vv[2]); o.w = f2bf(vv[3]);
            *(ushort4*)&C[(size_t)r * M + c] = o;
        } else {
            float* C = (float*)Cv;
            float4 o; o.x = vv[0]; o.y = vv[1]; o.z = vv[2]; o.w = vv[3];
            *(float4*)&C[(size_t)r * M + c] = o;
        }
    }
}

// ---------------- fused aggregation + self-loop + bias + leaky-relu ---------
// One wave per node; FPL = F/64 consecutive bf16 per lane; fp32 accumulate.

template <int F>
__global__ __launch_bounds__(256) void k_agg(
        const bf16_t* __restrict__ H, const int* __restrict__ rowptr,
        const int* __restrict__ csr, const float* __restrict__ dis,
        const float* __restrict__ bias, bf16_t* __restrict__ out, int N) {
    constexpr int FPL = F / 64;
    int wv = (int)((blockIdx.x * blockDim.x + threadIdx.x) >> 6);
    int lane = threadIdx.x & 63;
    if (wv >= N) return;
    float di = dis[wv];
    int s = rowptr[wv], e = rowptr[wv + 1];
    float acc[FPL];
    {
        const bf16_t* Hi = H + (size_t)wv * F + lane * FPL;
        float sl = di * di;   // self-loop norm = 1/deg
        if (FPL == 2) {
            ushort2 v = *(const ushort2*)Hi;
            acc[0] = bf2f(v.x) * sl; acc[1] = bf2f(v.y) * sl;
        } else {
            ushort4 v = *(const ushort4*)Hi;
            acc[0] = bf2f(v.x) * sl; acc[1] = bf2f(v.y) * sl;
            acc[2] = bf2f(v.z) * sl; acc[3] = bf2f(v.w) * sl;
        }
    }
    for (int p = s; p < e; p++) {
        int src = csr[p];
        float nr = dis[src] * di;
        const bf16_t* Hs = H + (size_t)src * F + lane * FPL;
        if (FPL == 2) {
            ushort2 v = *(const ushort2*)Hs;
            acc[0] += bf2f(v.x) * nr; acc[1] += bf2f(v.y) * nr;
        } else {
            ushort4 v = *(const ushort4*)Hs;
            acc[0] += bf2f(v.x) * nr; acc[1] += bf2f(v.y) * nr;
            acc[2] += bf2f(v.z) * nr; acc[3] += bf2f(v.w) * nr;
        }
    }
    const float* bp = bias + lane * FPL;
    float o[FPL];
#pragma unroll
    for (int f = 0; f < FPL; f++) {
        float v = acc[f] + bp[f];
        o[f] = v > 0.f ? v : 0.1f * v;
    }
    bf16_t* op = out + (size_t)wv * F + lane * FPL;
    if (FPL == 2) {
        ushort2 w; w.x = f2bf(o[0]); w.y = f2bf(o[1]);
        *(ushort2*)op = w;
    } else {
        ushort4 w; w.x = f2bf(o[0]); w.y = f2bf(o[1]); w.z = f2bf(o[2]); w.w = f2bf(o[3]);
        *(ushort4*)op = w;
    }
}

// ---------------- final head: dot(g2_row, L3w) + b, sigmoid ----------------

__global__ void k_head(const float* __restrict__ g2, const float* __restrict__ w,
                       const float* __restrict__ b, float* __restrict__ out, int G) {
    int wv = (int)((blockIdx.x * blockDim.x + threadIdx.x) >> 6);
    int lane = threadIdx.x & 63;
    if (wv >= G) return;
    const float2* gp = (const float2*)(g2 + (size_t)wv * 128);
    const float2* wp = (const float2*)w;
    float2 gv = gp[lane], wl = wp[lane];
    float s = gv.x * wl.x + gv.y * wl.y;
    for (int off = 32; off > 0; off >>= 1) s += __shfl_xor(s, off, 64);
    if (lane == 0) out[wv] = 1.f / (1.f + expf(-(s + b[0])));
}

// ---------------- launch ----------------

extern "C" void kernel_launch(void* const* d_in, const int* in_sizes, int n_in,
                              void* d_out, int out_size, void* d_ws, size_t ws_size,
                              hipStream_t stream) {
    const float* x   = (const float*)d_in[0];
    const int*   ei  = (const int*)d_in[1];
    const float* W1  = (const float*)d_in[2];  const float* b1  = (const float*)d_in[3];
    const float* W2  = (const float*)d_in[4];  const float* b2  = (const float*)d_in[5];
    const float* W3  = (const float*)d_in[6];  const float* b3  = (const float*)d_in[7];
    const float* L1w = (const float*)d_in[8];  const float* L1b = (const float*)d_in[9];
    const float* L2w = (const float*)d_in[10]; const float* L2b = (const float*)d_in[11];
    const float* L3w = (const float*)d_in[12]; const float* L3b = (const float*)d_in[13];
    float* out = (float*)d_out;

    const int C = 40;
    const int N = in_sizes[0] / C;     // 200000
    const int E = in_sizes[1] / 2;     // 1000000
    const int G = N / 40;              // 5000
    const int H1 = 128, H2 = 256, H3 = 128, M1 = 512, M2 = 128;

    // ---- workspace layout (CSR ints first, 256B-aligned chunks) ----
    char* wsb = (char*)d_ws;
    size_t off = 0;
    auto alloc = [&](size_t bytes) -> void* {
        void* p = wsb + off;
        off += (bytes + 255) & ~(size_t)255;
        return p;
    };
    int*    flag   = (int*)alloc(4);
    int*    cnt    = (int*)alloc(4 * (size_t)(N + 1));
    int*    rowptr = (int*)alloc(4 * (size_t)(N + 1));
    int*    cursor = (int*)alloc(4 * (size_t)N);
    int*    csr    = (int*)alloc(4 * (size_t)E);
    int*    bsum   = (int*)alloc(4 * 512);
    float*  dis    = (float*)alloc(4 * (size_t)N);
    bf16_t* Hb     = (bf16_t*)alloc(2 * (size_t)N * H2);   // ping [N,256] bf16
    bf16_t* Xb     = (bf16_t*)alloc(2 * (size_t)N * H2);   // pong [N,256] bf16
    float*  g1     = (float*)alloc(4 * (size_t)G * M1);
    float*  g2     = (float*)alloc(4 * (size_t)G * M2);
    if (off > ws_size) return;   // fail cleanly (out stays zero) instead of faulting

    // ---- CSR by dst + deg_inv_sqrt ----
    hipMemsetAsync(cnt, 0, sizeof(int) * (size_t)(N + 1), stream);
    k_detect<<<1, 64, 0, stream>>>(ei, flag);
    k_hist<<<CDIV(E, 256), 256, 0, stream>>>(ei, E, flag, cnt, N);
    int total = N + 1;
    int nb = CDIV(total, 1024);        // 196 <= 256
    k_blockred<<<nb, 256, 0, stream>>>(cnt, bsum, total);
    k_scanpartials<<<1, 256, 0, stream>>>(bsum, nb);
    k_scanwrite<<<nb, 256, 0, stream>>>(cnt, bsum, rowptr, cursor, dis, total, N);
    k_fill<<<CDIV(E, 256), 256, 0, stream>>>(ei, E, flag, cursor, csr, N);

    // ---- conv1 ----
    gemm_nt<8, false, true, false, 0><<<dim3(CDIV(N, 64), H1 / 64), 256, 0, stream>>>(x, W1, nullptr, Hb, N, C, H1);
    k_agg<128><<<CDIV(N, 4), 256, 0, stream>>>(Hb, rowptr, csr, dis, b1, Xb, N);
    // ---- conv2 ----
    gemm_nt<16, true, true, false, 0><<<dim3(CDIV(N, 64), H2 / 64), 256, 0, stream>>>(Xb, W2, nullptr, Hb, N, H1, H2);
    k_agg<256><<<CDIV(N, 4), 256, 0, stream>>>(Hb, rowptr, csr, dis, b2, Xb, N);
    // ---- conv3 ----
    gemm_nt<16, true, true, false, 0><<<dim3(CDIV(N, 64), H3 / 64), 256, 0, stream>>>(Xb, W3, nullptr, Hb, N, H2, H3);
    k_agg<128><<<CDIV(N, 4), 256, 0, stream>>>(Hb, rowptr, csr, dis, b3, Xb, N);
    // ---- readout MLP ----
    const int K1 = 40 * H3; // 5120 ; Xb viewed as [G, 5120] bf16
    gemm_nt<16, true, false, true, 1><<<dim3(CDIV(G, 64), M1 / 64), 256, 0, stream>>>(Xb, L1w, L1b, g1, G, K1, M1);
    gemm_nt<16, false, false, true, 1><<<dim3(CDIV(G, 64), M2 / 64), 256, 0, stream>>>(g1, L2w, L2b, g2, G, M1, M2);
    k_head<<<CDIV(G, 4), 256, 0, stream>>>(g2, L3w, L3b, out, G);
}

// Round 4
// 1090.322 us; speedup vs baseline: 1.3868x; 1.3868x over previous
//
#include <hip/hip_runtime.h>
#include <cmath>

#define CDIV(a,b) (((a)+(b)-1)/(b))

typedef unsigned short bf16_t;
using short8 = __attribute__((ext_vector_type(8))) short;
using f32x4  = __attribute__((ext_vector_type(4))) float;

__device__ __forceinline__ float bf2f(unsigned short b) {
    unsigned u = ((unsigned)b) << 16;
    float f;
    __builtin_memcpy(&f, &u, 4);
    return f;
}
__device__ __forceinline__ unsigned short f2bf(float f) {
    unsigned u;
    __builtin_memcpy(&u, &f, 4);
    u = (u + 0x7FFFu + ((u >> 16) & 1u)) >> 16;
    return (unsigned short)u;
}

// ---------------- edge-index width detection ----------------
__global__ void k_detect(const int* __restrict__ ei, int* __restrict__ flag) {
    int t = threadIdx.x;  // 64 threads
    unsigned v = (unsigned)ei[2 * t + 1];
    unsigned long long m = __ballot(v != 0u);
    if (t == 0) *flag = (m == 0ULL) ? 1 : 0;  // 1 => int64 layout
}

__device__ __forceinline__ int edge_src(const int* ei, int E, int f, int i) {
    return f ? ei[2 * (size_t)i] : ei[i];
}
__device__ __forceinline__ int edge_dst(const int* ei, int E, int f, int i) {
    return f ? ei[2 * ((size_t)E + (size_t)i)] : ei[(size_t)E + (size_t)i];
}

// ---------------- CSR build ----------------

__global__ void k_hist(const int* __restrict__ ei, int E, const int* __restrict__ flag,
                       int* __restrict__ cnt, int N) {
    int i = blockIdx.x * 256 + threadIdx.x;
    if (i >= E) return;
    int d = edge_dst(ei, E, *flag, i);
    if ((unsigned)d < (unsigned)N) atomicAdd(&cnt[d], 1);
}

__global__ void k_blockred(const int* __restrict__ cnt, int* __restrict__ bsum, int total) {
    __shared__ int sd[256];
    int b = blockIdx.x, t = threadIdx.x;
    int base = b * 1024 + t * 4;
    int s = 0;
#pragma unroll
    for (int i = 0; i < 4; i++) { int idx = base + i; if (idx < total) s += cnt[idx]; }
    sd[t] = s; __syncthreads();
    for (int off = 128; off > 0; off >>= 1) { if (t < off) sd[t] += sd[t + off]; __syncthreads(); }
    if (t == 0) bsum[b] = sd[0];
}

__global__ void k_scanpartials(int* bsum, int nb) {
    __shared__ int sd[256];
    int t = threadIdx.x;
    int v = (t < nb) ? bsum[t] : 0;
    sd[t] = v; __syncthreads();
    for (int off = 1; off < 256; off <<= 1) {
        int y = (t >= off) ? sd[t - off] : 0;
        __syncthreads();
        sd[t] += y;
        __syncthreads();
    }
    if (t < nb) bsum[t] = sd[t] - v;   // exclusive
}

__global__ void k_scanwrite(const int* __restrict__ cnt, const int* __restrict__ bsum,
                            int* __restrict__ rowptr, int* __restrict__ cursor,
                            float* __restrict__ dis, int total, int N) {
    __shared__ int sd[256];
    int b = blockIdx.x, t = threadIdx.x;
    int base = b * 1024 + t * 4;
    int v[4]; int s = 0;
#pragma unroll
    for (int i = 0; i < 4; i++) { int idx = base + i; v[i] = (idx < total) ? cnt[idx] : 0; s += v[i]; }
    sd[t] = s; __syncthreads();
    for (int off = 1; off < 256; off <<= 1) {
        int y = (t >= off) ? sd[t - off] : 0;
        __syncthreads();
        sd[t] += y;
        __syncthreads();
    }
    int pre = bsum[b] + sd[t] - s;
#pragma unroll
    for (int i = 0; i < 4; i++) {
        int idx = base + i;
        if (idx < total) {
            rowptr[idx] = pre;
            if (idx < N) { cursor[idx] = pre; dis[idx] = rsqrtf((float)v[i] + 1.0f); }
            pre += v[i];
        }
    }
}

__global__ void k_fill(const int* __restrict__ ei, int E, const int* __restrict__ flag,
                       int* __restrict__ cursor, int* __restrict__ csr, int N) {
    int i = blockIdx.x * 256 + threadIdx.x;
    if (i >= E) return;
    int f = *flag;
    int s = edge_src(ei, E, f, i);
    int d = edge_dst(ei, E, f, i);
    if ((unsigned)d < (unsigned)N && (unsigned)s < (unsigned)N) {
        int p = atomicAdd(&cursor[d], 1);
        csr[p] = s;
    }
}

// ---------------- MFMA GEMM: C[i][j] = sum_k A[i][k] * W[j][k] ----------------
// A: [N,K] row-major (bf16 if ABF else fp32), W: [M,K] row-major fp32
// (converted to bf16 during LDS staging). 128x128 tile, 4 waves (2x2),
// each wave 64x64 = 4x4 frags of mfma_f32_16x16x32_bf16. BK=64.
// K must be a multiple of 8; chunks beyond K are zero-padded (handles K=40).
// M must be a multiple of 128 (true for all call sites).

template <bool ABF, bool CBF, bool BIAS, int ACT>
__global__ __launch_bounds__(256) void gemm_mfma(
        const void* __restrict__ Av, const float* __restrict__ W,
        const float* __restrict__ bias, void* __restrict__ Cv,
        int N, int K, int M) {
    constexpr int BM = 128, BN = 128, BK = 64;
    constexpr int LDK = BK + 8;                 // +16B pad
    __shared__ __align__(16) unsigned short Als[BM][LDK];
    __shared__ __align__(16) unsigned short Bls[BN][LDK];

    int t = threadIdx.x;
    int lane = t & 63, wid = t >> 6;
    int quad = lane >> 4, l15 = lane & 15;
    int wave_m = wid & 1, wave_n = wid >> 1;    // 2x2 waves over the 128x128 tile
    int bm0 = blockIdx.x * BM;
    int bn0 = blockIdx.y * BN;

    f32x4 acc[4][4] = {};

    for (int k0 = 0; k0 < K; k0 += BK) {
        // ---- stage A tile: 128 rows x 8 chunks = 1024 chunks of 8 elems ----
#pragma unroll
        for (int it = 0; it < 4; it++) {
            int idx = t + it * 256;
            int row = idx >> 3, c = idx & 7;
            int g = bm0 + row;
            int kk = k0 + c * 8;
            short8 v = {};
            if (g < N && kk + 8 <= K) {
                if (ABF) {
                    v = *(const short8*)((const bf16_t*)Av + (size_t)g * K + kk);
                } else {
                    const float4* p = (const float4*)((const float*)Av + (size_t)g * K + kk);
                    float4 a = p[0], b = p[1];
                    v[0] = (short)f2bf(a.x); v[1] = (short)f2bf(a.y);
                    v[2] = (short)f2bf(a.z); v[3] = (short)f2bf(a.w);
                    v[4] = (short)f2bf(b.x); v[5] = (short)f2bf(b.y);
                    v[6] = (short)f2bf(b.z); v[7] = (short)f2bf(b.w);
                }
            }
            *(short8*)&Als[row][c * 8] = v;
        }
        // ---- stage W tile (fp32 -> bf16) ----
#pragma unroll
        for (int it = 0; it < 4; it++) {
            int idx = t + it * 256;
            int row = idx >> 3, c = idx & 7;
            int g = bn0 + row;
            int kk = k0 + c * 8;
            short8 v = {};
            if (g < M && kk + 8 <= K) {
                const float4* p = (const float4*)(W + (size_t)g * K + kk);
                float4 a = p[0], b = p[1];
                v[0] = (short)f2bf(a.x); v[1] = (short)f2bf(a.y);
                v[2] = (short)f2bf(a.z); v[3] = (short)f2bf(a.w);
                v[4] = (short)f2bf(b.x); v[5] = (short)f2bf(b.y);
                v[6] = (short)f2bf(b.z); v[7] = (short)f2bf(b.w);
            }
            *(short8*)&Bls[row][c * 8] = v;
        }
        __syncthreads();

        // ---- MFMA over the two K=32 steps ----
#pragma unroll
        for (int ks = 0; ks < 2; ks++) {
            short8 af[4], bfr[4];
            int ko = ks * 32 + quad * 8;
#pragma unroll
            for (int mt = 0; mt < 4; mt++)
                af[mt] = *(const short8*)&Als[wave_m * 64 + mt * 16 + l15][ko];
#pragma unroll
            for (int nt = 0; nt < 4; nt++)
                bfr[nt] = *(const short8*)&Bls[wave_n * 64 + nt * 16 + l15][ko];
#pragma unroll
            for (int mt = 0; mt < 4; mt++)
#pragma unroll
                for (int nt = 0; nt < 4; nt++)
                    acc[mt][nt] = __builtin_amdgcn_mfma_f32_16x16x32_bf16(
                        af[mt], bfr[nt], acc[mt][nt], 0, 0, 0);
        }
        __syncthreads();
    }

    // ---- epilogue: D row = quad*4 + reg, col = l15 ----
#pragma unroll
    for (int mt = 0; mt < 4; mt++) {
        int rbase = bm0 + wave_m * 64 + mt * 16 + quad * 4;
#pragma unroll
        for (int nt = 0; nt < 4; nt++) {
            int col = bn0 + wave_n * 64 + nt * 16 + l15;
            float bv = BIAS ? bias[col] : 0.f;
#pragma unroll
            for (int r = 0; r < 4; r++) {
                int row = rbase + r;
                if (row >= N) continue;
                float x = acc[mt][nt][r];
                if (BIAS) x += bv;
                if (ACT == 1) x = x > 0.f ? x : 0.1f * x;
                if (CBF) ((bf16_t*)Cv)[(size_t)row * M + col] = f2bf(x);
                else     ((float*)Cv)[(size_t)row * M + col] = x;
            }
        }
    }
}

// ---------------- fused aggregation + self-loop + bias + leaky-relu ---------

template <int F>
__global__ __launch_bounds__(256) void k_agg(
        const bf16_t* __restrict__ H, const int* __restrict__ rowptr,
        const int* __restrict__ csr, const float* __restrict__ dis,
        const float* __restrict__ bias, bf16_t* __restrict__ out, int N) {
    constexpr int FPL = F / 64;
    int wv = (int)((blockIdx.x * blockDim.x + threadIdx.x) >> 6);
    int lane = threadIdx.x & 63;
    if (wv >= N) return;
    float di = dis[wv];
    int s = rowptr[wv], e = rowptr[wv + 1];
    float acc[FPL];
    {
        const bf16_t* Hi = H + (size_t)wv * F + lane * FPL;
        float sl = di * di;   // self-loop norm = 1/deg
        if (FPL == 2) {
            ushort2 v = *(const ushort2*)Hi;
            acc[0] = bf2f(v.x) * sl; acc[1] = bf2f(v.y) * sl;
        } else {
            ushort4 v = *(const ushort4*)Hi;
            acc[0] = bf2f(v.x) * sl; acc[1] = bf2f(v.y) * sl;
            acc[2] = bf2f(v.z) * sl; acc[3] = bf2f(v.w) * sl;
        }
    }
    for (int p = s; p < e; p++) {
        int src = csr[p];
        float nr = dis[src] * di;
        const bf16_t* Hs = H + (size_t)src * F + lane * FPL;
        if (FPL == 2) {
            ushort2 v = *(const ushort2*)Hs;
            acc[0] += bf2f(v.x) * nr; acc[1] += bf2f(v.y) * nr;
        } else {
            ushort4 v = *(const ushort4*)Hs;
            acc[0] += bf2f(v.x) * nr; acc[1] += bf2f(v.y) * nr;
            acc[2] += bf2f(v.z) * nr; acc[3] += bf2f(v.w) * nr;
        }
    }
    const float* bp = bias + lane * FPL;
    float o[FPL];
#pragma unroll
    for (int f = 0; f < FPL; f++) {
        float v = acc[f] + bp[f];
        o[f] = v > 0.f ? v : 0.1f * v;
    }
    bf16_t* op = out + (size_t)wv * F + lane * FPL;
    if (FPL == 2) {
        ushort2 w; w.x = f2bf(o[0]); w.y = f2bf(o[1]);
        *(ushort2*)op = w;
    } else {
        ushort4 w; w.x = f2bf(o[0]); w.y = f2bf(o[1]); w.z = f2bf(o[2]); w.w = f2bf(o[3]);
        *(ushort4*)op = w;
    }
}

// ---------------- final head: dot(g2_row, L3w) + b, sigmoid ----------------

__global__ void k_head(const float* __restrict__ g2, const float* __restrict__ w,
                       const float* __restrict__ b, float* __restrict__ out, int G) {
    int wv = (int)((blockIdx.x * blockDim.x + threadIdx.x) >> 6);
    int lane = threadIdx.x & 63;
    if (wv >= G) return;
    const float2* gp = (const float2*)(g2 + (size_t)wv * 128);
    const float2* wp = (const float2*)w;
    float2 gv = gp[lane], wl = wp[lane];
    float s = gv.x * wl.x + gv.y * wl.y;
    for (int off = 32; off > 0; off >>= 1) s += __shfl_xor(s, off, 64);
    if (lane == 0) out[wv] = 1.f / (1.f + expf(-(s + b[0])));
}

// ---------------- launch ----------------

extern "C" void kernel_launch(void* const* d_in, const int* in_sizes, int n_in,
                              void* d_out, int out_size, void* d_ws, size_t ws_size,
                              hipStream_t stream) {
    const float* x   = (const float*)d_in[0];
    const int*   ei  = (const int*)d_in[1];
    const float* W1  = (const float*)d_in[2];  const float* b1  = (const float*)d_in[3];
    const float* W2  = (const float*)d_in[4];  const float* b2  = (const float*)d_in[5];
    const float* W3  = (const float*)d_in[6];  const float* b3  = (const float*)d_in[7];
    const float* L1w = (const float*)d_in[8];  const float* L1b = (const float*)d_in[9];
    const float* L2w = (const float*)d_in[10]; const float* L2b = (const float*)d_in[11];
    const float* L3w = (const float*)d_in[12]; const float* L3b = (const float*)d_in[13];
    float* out = (float*)d_out;

    const int C = 40;
    const int N = in_sizes[0] / C;     // 200000
    const int E = in_sizes[1] / 2;     // 1000000
    const int G = N / 40;              // 5000
    const int H1 = 128, H2 = 256, H3 = 128, M1 = 512, M2 = 128;

    // ---- workspace layout ----
    char* wsb = (char*)d_ws;
    size_t off = 0;
    auto alloc = [&](size_t bytes) -> void* {
        void* p = wsb + off;
        off += (bytes + 255) & ~(size_t)255;
        return p;
    };
    int*    flag   = (int*)alloc(4);
    int*    cnt    = (int*)alloc(4 * (size_t)(N + 1));
    int*    rowptr = (int*)alloc(4 * (size_t)(N + 1));
    int*    cursor = (int*)alloc(4 * (size_t)N);
    int*    csr    = (int*)alloc(4 * (size_t)E);
    int*    bsum   = (int*)alloc(4 * 512);
    float*  dis    = (float*)alloc(4 * (size_t)N);
    bf16_t* Hb     = (bf16_t*)alloc(2 * (size_t)N * H2);   // ping [N,256] bf16
    bf16_t* Xb     = (bf16_t*)alloc(2 * (size_t)N * H2);   // pong [N,256] bf16
    bf16_t* g1b    = (bf16_t*)alloc(2 * (size_t)G * M1);
    float*  g2     = (float*)alloc(4 * (size_t)G * M2);
    if (off > ws_size) return;   // fail cleanly instead of faulting

    // ---- CSR by dst + deg_inv_sqrt ----
    hipMemsetAsync(cnt, 0, sizeof(int) * (size_t)(N + 1), stream);
    k_detect<<<1, 64, 0, stream>>>(ei, flag);
    k_hist<<<CDIV(E, 256), 256, 0, stream>>>(ei, E, flag, cnt, N);
    int total = N + 1;
    int nb = CDIV(total, 1024);
    k_blockred<<<nb, 256, 0, stream>>>(cnt, bsum, total);
    k_scanpartials<<<1, 256, 0, stream>>>(bsum, nb);
    k_scanwrite<<<nb, 256, 0, stream>>>(cnt, bsum, rowptr, cursor, dis, total, N);
    k_fill<<<CDIV(E, 256), 256, 0, stream>>>(ei, E, flag, cursor, csr, N);

    const int NB = CDIV(N, 128);       // 1563
    const int GB = CDIV(G, 128);       // 40

    // ---- conv1: H = x @ W1^T (K=40 zero-padded in staging) ----
    gemm_mfma<false, true, false, 0><<<dim3(NB, H1 / 128), 256, 0, stream>>>(x, W1, nullptr, Hb, N, C, H1);
    k_agg<128><<<CDIV(N, 4), 256, 0, stream>>>(Hb, rowptr, csr, dis, b1, Xb, N);
    // ---- conv2 ----
    gemm_mfma<true, true, false, 0><<<dim3(NB, H2 / 128), 256, 0, stream>>>(Xb, W2, nullptr, Hb, N, H1, H2);
    k_agg<256><<<CDIV(N, 4), 256, 0, stream>>>(Hb, rowptr, csr, dis, b2, Xb, N);
    // ---- conv3 ----
    gemm_mfma<true, true, false, 0><<<dim3(NB, H3 / 128), 256, 0, stream>>>(Xb, W3, nullptr, Hb, N, H2, H3);
    k_agg<128><<<CDIV(N, 4), 256, 0, stream>>>(Hb, rowptr, csr, dis, b3, Xb, N);
    // ---- readout MLP ----
    const int K1 = 40 * H3; // 5120 ; Xb viewed as [G, 5120] bf16
    gemm_mfma<true, true, true, 1><<<dim3(GB, M1 / 128), 256, 0, stream>>>(Xb, L1w, L1b, g1b, G, K1, M1);
    gemm_mfma<true, false, true, 1><<<dim3(GB, M2 / 128), 256, 0, stream>>>(g1b, L2w, L2b, g2, G, M1, M2);
    k_head<<<CDIV(G, 4), 256, 0, stream>>>(g2, L3w, L3b, out, G);
}

// Round 5
// 903.537 us; speedup vs baseline: 1.6734x; 1.2067x over previous
//
#include <hip/hip_runtime.h>
#include <cmath>

#define CDIV(a,b) (((a)+(b)-1)/(b))

typedef unsigned short bf16_t;
using short8 = __attribute__((ext_vector_type(8))) short;
using f32x4  = __attribute__((ext_vector_type(4))) float;

__device__ __forceinline__ float bf2f(unsigned short b) {
    unsigned u = ((unsigned)b) << 16;
    float f;
    __builtin_memcpy(&f, &u, 4);
    return f;
}
__device__ __forceinline__ unsigned short f2bf(float f) {
    unsigned u;
    __builtin_memcpy(&u, &f, 4);
    u = (u + 0x7FFFu + ((u >> 16) & 1u)) >> 16;
    return (unsigned short)u;
}

// ---------------- edge-index width detection ----------------
__global__ void k_detect(const int* __restrict__ ei, int* __restrict__ flag) {
    int t = threadIdx.x;  // 64 threads
    unsigned v = (unsigned)ei[2 * t + 1];
    unsigned long long m = __ballot(v != 0u);
    if (t == 0) *flag = (m == 0ULL) ? 1 : 0;  // 1 => int64 layout
}

__device__ __forceinline__ int edge_src(const int* ei, int E, int f, int i) {
    return f ? ei[2 * (size_t)i] : ei[i];
}
__device__ __forceinline__ int edge_dst(const int* ei, int E, int f, int i) {
    return f ? ei[2 * ((size_t)E + (size_t)i)] : ei[(size_t)E + (size_t)i];
}

// ---------------- CSR build ----------------

__global__ void k_hist(const int* __restrict__ ei, int E, const int* __restrict__ flag,
                       int* __restrict__ cnt, int N) {
    int i = blockIdx.x * 256 + threadIdx.x;
    if (i >= E) return;
    int d = edge_dst(ei, E, *flag, i);
    if ((unsigned)d < (unsigned)N) atomicAdd(&cnt[d], 1);
}

__global__ void k_blockred(const int* __restrict__ cnt, int* __restrict__ bsum, int total) {
    __shared__ int sd[256];
    int b = blockIdx.x, t = threadIdx.x;
    int base = b * 1024 + t * 4;
    int s = 0;
#pragma unroll
    for (int i = 0; i < 4; i++) { int idx = base + i; if (idx < total) s += cnt[idx]; }
    sd[t] = s; __syncthreads();
    for (int off = 128; off > 0; off >>= 1) { if (t < off) sd[t] += sd[t + off]; __syncthreads(); }
    if (t == 0) bsum[b] = sd[0];
}

__global__ void k_scanpartials(int* bsum, int nb) {
    __shared__ int sd[256];
    int t = threadIdx.x;
    int v = (t < nb) ? bsum[t] : 0;
    sd[t] = v; __syncthreads();
    for (int off = 1; off < 256; off <<= 1) {
        int y = (t >= off) ? sd[t - off] : 0;
        __syncthreads();
        sd[t] += y;
        __syncthreads();
    }
    if (t < nb) bsum[t] = sd[t] - v;   // exclusive
}

__global__ void k_scanwrite(const int* __restrict__ cnt, const int* __restrict__ bsum,
                            int* __restrict__ rowptr, int* __restrict__ cursor,
                            float* __restrict__ dis, int total, int N) {
    __shared__ int sd[256];
    int b = blockIdx.x, t = threadIdx.x;
    int base = b * 1024 + t * 4;
    int v[4]; int s = 0;
#pragma unroll
    for (int i = 0; i < 4; i++) { int idx = base + i; v[i] = (idx < total) ? cnt[idx] : 0; s += v[i]; }
    sd[t] = s; __syncthreads();
    for (int off = 1; off < 256; off <<= 1) {
        int y = (t >= off) ? sd[t - off] : 0;
        __syncthreads();
        sd[t] += y;
        __syncthreads();
    }
    int pre = bsum[b] + sd[t] - s;
#pragma unroll
    for (int i = 0; i < 4; i++) {
        int idx = base + i;
        if (idx < total) {
            rowptr[idx] = pre;
            if (idx < N) { cursor[idx] = pre; dis[idx] = rsqrtf((float)v[i] + 1.0f); }
            pre += v[i];
        }
    }
}

__global__ void k_fill(const int* __restrict__ ei, int E, const int* __restrict__ flag,
                       int* __restrict__ cursor, int* __restrict__ csr, int N) {
    int i = blockIdx.x * 256 + threadIdx.x;
    if (i >= E) return;
    int f = *flag;
    int s = edge_src(ei, E, f, i);
    int d = edge_dst(ei, E, f, i);
    if ((unsigned)d < (unsigned)N && (unsigned)s < (unsigned)N) {
        int p = atomicAdd(&cursor[d], 1);
        csr[p] = s;
    }
}

// ---------------- MFMA GEMM: C[i][j] = sum_k A[i][k] * W[j][k] ----------------
// A: [N,K] row-major (bf16 if ABF else fp32), W: [M,K] row-major fp32
// (converted to bf16 during LDS staging). 128x128 tile, 4 waves (2x2),
// each wave 64x64 = 4x4 frags of mfma_f32_16x16x32_bf16. BK=64.
// SPLIT: blockIdx.z selects K-segment [z*Kseg, z*Kseg+Kseg); fp32 partials
// written to Cv + z*N*M (bias/act deferred to k_red).

template <bool ABF, bool CBF, bool BIAS, int ACT, bool SPLIT>
__global__ __launch_bounds__(256) void gemm_mfma(
        const void* __restrict__ Av, const float* __restrict__ W,
        const float* __restrict__ bias, void* __restrict__ Cv,
        int N, int K, int M, int Kseg) {
    constexpr int BM = 128, BN = 128, BK = 64;
    constexpr int LDK = BK + 8;                 // +16B pad
    __shared__ __align__(16) unsigned short Als[BM][LDK];
    __shared__ __align__(16) unsigned short Bls[BN][LDK];

    int t = threadIdx.x;
    int lane = t & 63, wid = t >> 6;
    int quad = lane >> 4, l15 = lane & 15;
    int wave_m = wid & 1, wave_n = wid >> 1;
    int bm0 = blockIdx.x * BM;
    int bn0 = blockIdx.y * BN;
    int kbeg = SPLIT ? (int)blockIdx.z * Kseg : 0;
    int kend = SPLIT ? min(kbeg + Kseg, K) : K;

    f32x4 acc[4][4] = {};

    for (int k0 = kbeg; k0 < kend; k0 += BK) {
        // ---- stage A tile: 128 rows x 8 chunks of 8 elems ----
#pragma unroll
        for (int it = 0; it < 4; it++) {
            int idx = t + it * 256;
            int row = idx >> 3, c = idx & 7;
            int g = bm0 + row;
            int kk = k0 + c * 8;
            short8 v = {};
            if (g < N && kk + 8 <= K) {
                if (ABF) {
                    v = *(const short8*)((const bf16_t*)Av + (size_t)g * K + kk);
                } else {
                    const float4* p = (const float4*)((const float*)Av + (size_t)g * K + kk);
                    float4 a = p[0], b = p[1];
                    v[0] = (short)f2bf(a.x); v[1] = (short)f2bf(a.y);
                    v[2] = (short)f2bf(a.z); v[3] = (short)f2bf(a.w);
                    v[4] = (short)f2bf(b.x); v[5] = (short)f2bf(b.y);
                    v[6] = (short)f2bf(b.z); v[7] = (short)f2bf(b.w);
                }
            }
            *(short8*)&Als[row][c * 8] = v;
        }
        // ---- stage W tile (fp32 -> bf16) ----
#pragma unroll
        for (int it = 0; it < 4; it++) {
            int idx = t + it * 256;
            int row = idx >> 3, c = idx & 7;
            int g = bn0 + row;
            int kk = k0 + c * 8;
            short8 v = {};
            if (g < M && kk + 8 <= K) {
                const float4* p = (const float4*)(W + (size_t)g * K + kk);
                float4 a = p[0], b = p[1];
                v[0] = (short)f2bf(a.x); v[1] = (short)f2bf(a.y);
                v[2] = (short)f2bf(a.z); v[3] = (short)f2bf(a.w);
                v[4] = (short)f2bf(b.x); v[5] = (short)f2bf(b.y);
                v[6] = (short)f2bf(b.z); v[7] = (short)f2bf(b.w);
            }
            *(short8*)&Bls[row][c * 8] = v;
        }
        __syncthreads();

#pragma unroll
        for (int ks = 0; ks < 2; ks++) {
            short8 af[4], bfr[4];
            int ko = ks * 32 + quad * 8;
#pragma unroll
            for (int mt = 0; mt < 4; mt++)
                af[mt] = *(const short8*)&Als[wave_m * 64 + mt * 16 + l15][ko];
#pragma unroll
            for (int nt = 0; nt < 4; nt++)
                bfr[nt] = *(const short8*)&Bls[wave_n * 64 + nt * 16 + l15][ko];
#pragma unroll
            for (int mt = 0; mt < 4; mt++)
#pragma unroll
                for (int nt = 0; nt < 4; nt++)
                    acc[mt][nt] = __builtin_amdgcn_mfma_f32_16x16x32_bf16(
                        af[mt], bfr[nt], acc[mt][nt], 0, 0, 0);
        }
        __syncthreads();
    }

    // ---- epilogue: D row = quad*4 + reg, col = l15 ----
    float* Pz = SPLIT ? ((float*)Cv + (size_t)blockIdx.z * N * M) : nullptr;
#pragma unroll
    for (int mt = 0; mt < 4; mt++) {
        int rbase = bm0 + wave_m * 64 + mt * 16 + quad * 4;
#pragma unroll
        for (int nt = 0; nt < 4; nt++) {
            int col = bn0 + wave_n * 64 + nt * 16 + l15;
            float bv = BIAS ? bias[col] : 0.f;
#pragma unroll
            for (int r = 0; r < 4; r++) {
                int row = rbase + r;
                if (row >= N) continue;
                float x = acc[mt][nt][r];
                if (SPLIT) {
                    Pz[(size_t)row * M + col] = x;
                } else {
                    if (BIAS) x += bv;
                    if (ACT == 1) x = x > 0.f ? x : 0.1f * x;
                    if (CBF) ((bf16_t*)Cv)[(size_t)row * M + col] = f2bf(x);
                    else     ((float*)Cv)[(size_t)row * M + col] = x;
                }
            }
        }
    }
}

// ---------------- split-K reduce + bias + leaky-relu ----------------
// part: [S][GM] fp32; out: bf16 or fp32 [GM]; M power of two.

template <int S, bool CBF, int ACT>
__global__ __launch_bounds__(256) void k_red(
        const float* __restrict__ part, const float* __restrict__ bias,
        void* __restrict__ out, int GM, int Mmask) {
    int i = (blockIdx.x * 256 + threadIdx.x) * 4;
    if (i >= GM) return;
    float4 s = *(const float4*)&part[i];
#pragma unroll
    for (int z = 1; z < S; z++) {
        float4 p = *(const float4*)&part[(size_t)z * GM + i];
        s.x += p.x; s.y += p.y; s.z += p.z; s.w += p.w;
    }
    float4 b = *(const float4*)&bias[i & Mmask];
    float v[4] = {s.x + b.x, s.y + b.y, s.z + b.z, s.w + b.w};
#pragma unroll
    for (int j = 0; j < 4; j++)
        if (ACT == 1) v[j] = v[j] > 0.f ? v[j] : 0.1f * v[j];
    if (CBF) {
        ushort4 o; o.x = f2bf(v[0]); o.y = f2bf(v[1]); o.z = f2bf(v[2]); o.w = f2bf(v[3]);
        *(ushort4*)((bf16_t*)out + i) = o;
    } else {
        float4 o; o.x = v[0]; o.y = v[1]; o.z = v[2]; o.w = v[3];
        *(float4*)((float*)out + i) = o;
    }
}

// ---------------- fused aggregation + self-loop + bias + leaky-relu ---------

template <int F>
__global__ __launch_bounds__(256) void k_agg(
        const bf16_t* __restrict__ H, const int* __restrict__ rowptr,
        const int* __restrict__ csr, const float* __restrict__ dis,
        const float* __restrict__ bias, bf16_t* __restrict__ out, int N) {
    constexpr int FPL = F / 64;
    int wv = (int)((blockIdx.x * blockDim.x + threadIdx.x) >> 6);
    int lane = threadIdx.x & 63;
    if (wv >= N) return;
    float di = dis[wv];
    int s = rowptr[wv], e = rowptr[wv + 1];
    float acc[FPL];
    {
        const bf16_t* Hi = H + (size_t)wv * F + lane * FPL;
        float sl = di * di;   // self-loop norm = 1/deg
        if (FPL == 2) {
            ushort2 v = *(const ushort2*)Hi;
            acc[0] = bf2f(v.x) * sl; acc[1] = bf2f(v.y) * sl;
        } else {
            ushort4 v = *(const ushort4*)Hi;
            acc[0] = bf2f(v.x) * sl; acc[1] = bf2f(v.y) * sl;
            acc[2] = bf2f(v.z) * sl; acc[3] = bf2f(v.w) * sl;
        }
    }
    for (int p = s; p < e; p++) {
        int src = csr[p];
        float nr = dis[src] * di;
        const bf16_t* Hs = H + (size_t)src * F + lane * FPL;
        if (FPL == 2) {
            ushort2 v = *(const ushort2*)Hs;
            acc[0] += bf2f(v.x) * nr; acc[1] += bf2f(v.y) * nr;
        } else {
            ushort4 v = *(const ushort4*)Hs;
            acc[0] += bf2f(v.x) * nr; acc[1] += bf2f(v.y) * nr;
            acc[2] += bf2f(v.z) * nr; acc[3] += bf2f(v.w) * nr;
        }
    }
    const float* bp = bias + lane * FPL;
    float o[FPL];
#pragma unroll
    for (int f = 0; f < FPL; f++) {
        float v = acc[f] + bp[f];
        o[f] = v > 0.f ? v : 0.1f * v;
    }
    bf16_t* op = out + (size_t)wv * F + lane * FPL;
    if (FPL == 2) {
        ushort2 w; w.x = f2bf(o[0]); w.y = f2bf(o[1]);
        *(ushort2*)op = w;
    } else {
        ushort4 w; w.x = f2bf(o[0]); w.y = f2bf(o[1]); w.z = f2bf(o[2]); w.w = f2bf(o[3]);
        *(ushort4*)op = w;
    }
}

// ---------------- final head: dot(g2_row, L3w) + b, sigmoid ----------------

__global__ void k_head(const float* __restrict__ g2, const float* __restrict__ w,
                       const float* __restrict__ b, float* __restrict__ out, int G) {
    int wv = (int)((blockIdx.x * blockDim.x + threadIdx.x) >> 6);
    int lane = threadIdx.x & 63;
    if (wv >= G) return;
    const float2* gp = (const float2*)(g2 + (size_t)wv * 128);
    const float2* wp = (const float2*)w;
    float2 gv = gp[lane], wl = wp[lane];
    float s = gv.x * wl.x + gv.y * wl.y;
    for (int off = 32; off > 0; off >>= 1) s += __shfl_xor(s, off, 64);
    if (lane == 0) out[wv] = 1.f / (1.f + expf(-(s + b[0])));
}

// ---------------- launch ----------------

extern "C" void kernel_launch(void* const* d_in, const int* in_sizes, int n_in,
                              void* d_out, int out_size, void* d_ws, size_t ws_size,
                              hipStream_t stream) {
    const float* x   = (const float*)d_in[0];
    const int*   ei  = (const int*)d_in[1];
    const float* W1  = (const float*)d_in[2];  const float* b1  = (const float*)d_in[3];
    const float* W2  = (const float*)d_in[4];  const float* b2  = (const float*)d_in[5];
    const float* W3  = (const float*)d_in[6];  const float* b3  = (const float*)d_in[7];
    const float* L1w = (const float*)d_in[8];  const float* L1b = (const float*)d_in[9];
    const float* L2w = (const float*)d_in[10]; const float* L2b = (const float*)d_in[11];
    const float* L3w = (const float*)d_in[12]; const float* L3b = (const float*)d_in[13];
    float* out = (float*)d_out;

    const int C = 40;
    const int N = in_sizes[0] / C;     // 200000
    const int E = in_sizes[1] / 2;     // 1000000
    const int G = N / 40;              // 5000
    const int H1 = 128, H2 = 256, H3 = 128, M1 = 512, M2 = 128;

    // ---- workspace layout ----
    char* wsb = (char*)d_ws;
    size_t off = 0;
    auto alloc = [&](size_t bytes) -> void* {
        void* p = wsb + off;
        off += (bytes + 255) & ~(size_t)255;
        return p;
    };
    int*    flag   = (int*)alloc(4);
    int*    cnt    = (int*)alloc(4 * (size_t)(N + 1));
    int*    rowptr = (int*)alloc(4 * (size_t)(N + 1));
    int*    cursor = (int*)alloc(4 * (size_t)N);
    int*    csr    = (int*)alloc(4 * (size_t)E);
    int*    bsum   = (int*)alloc(4 * 512);
    float*  dis    = (float*)alloc(4 * (size_t)N);
    bf16_t* Hb     = (bf16_t*)alloc(2 * (size_t)N * H2);   // ping [N,256] bf16
    bf16_t* Xb     = (bf16_t*)alloc(2 * (size_t)N * H2);   // pong [N,256] bf16
    bf16_t* g1b    = (bf16_t*)alloc(2 * (size_t)G * M1);
    float*  g2     = (float*)alloc(4 * (size_t)G * M2);
    if (off > ws_size) return;   // fail cleanly instead of faulting
    // split-K partial buffers alias Hb (dead after the last k_agg):
    // MLP1: 8*G*M1*4 = 81.9 MB, MLP2: 4*G*M2*4 = 10.2 MB; Hb = 102.4 MB.
    float* part = (float*)Hb;

    // ---- CSR by dst + deg_inv_sqrt ----
    hipMemsetAsync(cnt, 0, sizeof(int) * (size_t)(N + 1), stream);
    k_detect<<<1, 64, 0, stream>>>(ei, flag);
    k_hist<<<CDIV(E, 256), 256, 0, stream>>>(ei, E, flag, cnt, N);
    int total = N + 1;
    int nb = CDIV(total, 1024);
    k_blockred<<<nb, 256, 0, stream>>>(cnt, bsum, total);
    k_scanpartials<<<1, 256, 0, stream>>>(bsum, nb);
    k_scanwrite<<<nb, 256, 0, stream>>>(cnt, bsum, rowptr, cursor, dis, total, N);
    k_fill<<<CDIV(E, 256), 256, 0, stream>>>(ei, E, flag, cursor, csr, N);

    const int NB = CDIV(N, 128);       // 1563
    const int GB = CDIV(G, 128);       // 40

    // ---- conv1: H = x @ W1^T (K=40 zero-padded in staging) ----
    gemm_mfma<false, true, false, 0, false><<<dim3(NB, H1 / 128), 256, 0, stream>>>(x, W1, nullptr, Hb, N, C, H1, 0);
    k_agg<128><<<CDIV(N, 4), 256, 0, stream>>>(Hb, rowptr, csr, dis, b1, Xb, N);
    // ---- conv2 ----
    gemm_mfma<true, true, false, 0, false><<<dim3(NB, H2 / 128), 256, 0, stream>>>(Xb, W2, nullptr, Hb, N, H1, H2, 0);
    k_agg<256><<<CDIV(N, 4), 256, 0, stream>>>(Hb, rowptr, csr, dis, b2, Xb, N);
    // ---- conv3 ----
    gemm_mfma<true, true, false, 0, false><<<dim3(NB, H3 / 128), 256, 0, stream>>>(Xb, W3, nullptr, Hb, N, H2, H3, 0);
    k_agg<128><<<CDIV(N, 4), 256, 0, stream>>>(Hb, rowptr, csr, dis, b3, Xb, N);

    // ---- readout MLP1: split-K S=8, Kseg=640 ----
    const int K1 = 40 * H3; // 5120 ; Xb viewed as [G, 5120] bf16
    gemm_mfma<true, false, false, 0, true><<<dim3(GB, M1 / 128, 8), 256, 0, stream>>>(Xb, L1w, nullptr, part, G, K1, M1, K1 / 8);
    k_red<8, true, 1><<<CDIV(G * M1 / 4, 256), 256, 0, stream>>>(part, L1b, g1b, G * M1, M1 - 1);
    // ---- readout MLP2: split-K S=4, Kseg=128 ----
    gemm_mfma<true, false, false, 0, true><<<dim3(GB, M2 / 128, 4), 256, 0, stream>>>(g1b, L2w, nullptr, part, G, M1, M2, M1 / 4);
    k_red<4, false, 1><<<CDIV(G * M2 / 4, 256), 256, 0, stream>>>(part, L2b, g2, G * M2, M2 - 1);
    k_head<<<CDIV(G, 4), 256, 0, stream>>>(g2, L3w, L3b, out, G);
}

// Round 6
// 899.330 us; speedup vs baseline: 1.6813x; 1.0047x over previous
//
#include <hip/hip_runtime.h>
#include <cmath>

#define CDIV(a,b) (((a)+(b)-1)/(b))

typedef unsigned short bf16_t;
using short8 = __attribute__((ext_vector_type(8))) short;
using f32x4  = __attribute__((ext_vector_type(4))) float;
using u16x2  = __attribute__((ext_vector_type(2))) unsigned short;
using u16x4  = __attribute__((ext_vector_type(4))) unsigned short;

__device__ __forceinline__ float bf2f(unsigned short b) {
    unsigned u = ((unsigned)b) << 16;
    float f;
    __builtin_memcpy(&f, &u, 4);
    return f;
}
__device__ __forceinline__ unsigned short f2bf(float f) {
    unsigned u;
    __builtin_memcpy(&u, &f, 4);
    u = (u + 0x7FFFu + ((u >> 16) & 1u)) >> 16;
    return (unsigned short)u;
}

// ---------------- edge-index width detection ----------------
__global__ void k_detect(const int* __restrict__ ei, int* __restrict__ flag) {
    int t = threadIdx.x;  // 64 threads
    unsigned v = (unsigned)ei[2 * t + 1];
    unsigned long long m = __ballot(v != 0u);
    if (t == 0) *flag = (m == 0ULL) ? 1 : 0;  // 1 => int64 layout
}

__device__ __forceinline__ int edge_src(const int* ei, int E, int f, int i) {
    return f ? ei[2 * (size_t)i] : ei[i];
}
__device__ __forceinline__ int edge_dst(const int* ei, int E, int f, int i) {
    return f ? ei[2 * ((size_t)E + (size_t)i)] : ei[(size_t)E + (size_t)i];
}

// ---------------- CSR build ----------------

__global__ void k_hist(const int* __restrict__ ei, int E, const int* __restrict__ flag,
                       int* __restrict__ cnt, int N) {
    int i = blockIdx.x * 256 + threadIdx.x;
    if (i >= E) return;
    int d = edge_dst(ei, E, *flag, i);
    if ((unsigned)d < (unsigned)N) atomicAdd(&cnt[d], 1);
}

__global__ void k_blockred(const int* __restrict__ cnt, int* __restrict__ bsum, int total) {
    __shared__ int sd[256];
    int b = blockIdx.x, t = threadIdx.x;
    int base = b * 1024 + t * 4;
    int s = 0;
#pragma unroll
    for (int i = 0; i < 4; i++) { int idx = base + i; if (idx < total) s += cnt[idx]; }
    sd[t] = s; __syncthreads();
    for (int off = 128; off > 0; off >>= 1) { if (t < off) sd[t] += sd[t + off]; __syncthreads(); }
    if (t == 0) bsum[b] = sd[0];
}

__global__ void k_scanpartials(int* bsum, int nb) {
    __shared__ int sd[256];
    int t = threadIdx.x;
    int v = (t < nb) ? bsum[t] : 0;
    sd[t] = v; __syncthreads();
    for (int off = 1; off < 256; off <<= 1) {
        int y = (t >= off) ? sd[t - off] : 0;
        __syncthreads();
        sd[t] += y;
        __syncthreads();
    }
    if (t < nb) bsum[t] = sd[t] - v;   // exclusive
}

__global__ void k_scanwrite(const int* __restrict__ cnt, const int* __restrict__ bsum,
                            int* __restrict__ rowptr, int* __restrict__ cursor,
                            float* __restrict__ dis, int total, int N) {
    __shared__ int sd[256];
    int b = blockIdx.x, t = threadIdx.x;
    int base = b * 1024 + t * 4;
    int v[4]; int s = 0;
#pragma unroll
    for (int i = 0; i < 4; i++) { int idx = base + i; v[i] = (idx < total) ? cnt[idx] : 0; s += v[i]; }
    sd[t] = s; __syncthreads();
    for (int off = 1; off < 256; off <<= 1) {
        int y = (t >= off) ? sd[t - off] : 0;
        __syncthreads();
        sd[t] += y;
        __syncthreads();
    }
    int pre = bsum[b] + sd[t] - s;
#pragma unroll
    for (int i = 0; i < 4; i++) {
        int idx = base + i;
        if (idx < total) {
            rowptr[idx] = pre;
            if (idx < N) { cursor[idx] = pre; dis[idx] = rsqrtf((float)v[i] + 1.0f); }
            pre += v[i];
        }
    }
}

__global__ void k_fill(const int* __restrict__ ei, int E, const int* __restrict__ flag,
                       int* __restrict__ cursor, int* __restrict__ csr, int N) {
    int i = blockIdx.x * 256 + threadIdx.x;
    if (i >= E) return;
    int f = *flag;
    int s = edge_src(ei, E, f, i);
    int d = edge_dst(ei, E, f, i);
    if ((unsigned)d < (unsigned)N && (unsigned)s < (unsigned)N) {
        int p = atomicAdd(&cursor[d], 1);
        csr[p] = s;
    }
}

// ---------------- pad/convert x: [N,40] fp32 -> [N,64] bf16 (zero-padded) ----

__global__ __launch_bounds__(256) void k_pad(const float* __restrict__ x,
                                             bf16_t* __restrict__ xb, int N) {
    int i = blockIdx.x * 256 + threadIdx.x;
    int row = i >> 6, col = i & 63;
    if (row >= N) return;
    float v = (col < 40) ? x[(size_t)row * 40 + col] : 0.f;
    xb[(size_t)row * 64 + col] = f2bf(v);
}

// ---------------- MFMA GEMM: C[i][j] = sum_k A[i][k] * W[j][k] ----------------
// A: [N,K] row-major (bf16 if ABF else fp32), W: [M,KW] row-major fp32
// (bf16-converted in staging; K-KW zero-padded, KW multiple of 8).
// 128x128 tile, 4 waves (2x2), 4x4 frags of mfma_f32_16x16x32_bf16, BK=64.
// SPLIT: blockIdx.z selects K-segment; fp32 partials to Cv + z*N*M.

template <bool ABF, bool CBF, bool BIAS, int ACT, bool SPLIT>
__global__ __launch_bounds__(256) void gemm_mfma(
        const void* __restrict__ Av, const float* __restrict__ W,
        const float* __restrict__ bias, void* __restrict__ Cv,
        int N, int K, int M, int Kseg, int KW) {
    constexpr int BM = 128, BN = 128, BK = 64;
    constexpr int LDK = BK + 8;
    __shared__ __align__(16) unsigned short Als[BM][LDK];
    __shared__ __align__(16) unsigned short Bls[BN][LDK];

    int t = threadIdx.x;
    int lane = t & 63, wid = t >> 6;
    int quad = lane >> 4, l15 = lane & 15;
    int wave_m = wid & 1, wave_n = wid >> 1;
    int bm0 = blockIdx.x * BM;
    int bn0 = blockIdx.y * BN;
    int kbeg = SPLIT ? (int)blockIdx.z * Kseg : 0;
    int kend = SPLIT ? min(kbeg + Kseg, K) : K;

    f32x4 acc[4][4] = {};

    for (int k0 = kbeg; k0 < kend; k0 += BK) {
        // ---- stage A tile ----
#pragma unroll
        for (int it = 0; it < 4; it++) {
            int idx = t + it * 256;
            int row = idx >> 3, c = idx & 7;
            int g = bm0 + row;
            int kk = k0 + c * 8;
            short8 v = {};
            if (g < N && kk + 8 <= K) {
                if (ABF) {
                    v = *(const short8*)((const bf16_t*)Av + (size_t)g * K + kk);
                } else {
                    const float4* p = (const float4*)((const float*)Av + (size_t)g * K + kk);
                    float4 a = p[0], b = p[1];
                    v[0] = (short)f2bf(a.x); v[1] = (short)f2bf(a.y);
                    v[2] = (short)f2bf(a.z); v[3] = (short)f2bf(a.w);
                    v[4] = (short)f2bf(b.x); v[5] = (short)f2bf(b.y);
                    v[6] = (short)f2bf(b.z); v[7] = (short)f2bf(b.w);
                }
            }
            *(short8*)&Als[row][c * 8] = v;
        }
        // ---- stage W tile (fp32 -> bf16, rows of length KW, zero-pad to K) ----
#pragma unroll
        for (int it = 0; it < 4; it++) {
            int idx = t + it * 256;
            int row = idx >> 3, c = idx & 7;
            int g = bn0 + row;
            int kk = k0 + c * 8;
            short8 v = {};
            if (g < M && kk + 8 <= KW) {
                const float4* p = (const float4*)(W + (size_t)g * KW + kk);
                float4 a = p[0], b = p[1];
                v[0] = (short)f2bf(a.x); v[1] = (short)f2bf(a.y);
                v[2] = (short)f2bf(a.z); v[3] = (short)f2bf(a.w);
                v[4] = (short)f2bf(b.x); v[5] = (short)f2bf(b.y);
                v[6] = (short)f2bf(b.z); v[7] = (short)f2bf(b.w);
            }
            *(short8*)&Bls[row][c * 8] = v;
        }
        __syncthreads();

#pragma unroll
        for (int ks = 0; ks < 2; ks++) {
            short8 af[4], bfr[4];
            int ko = ks * 32 + quad * 8;
#pragma unroll
            for (int mt = 0; mt < 4; mt++)
                af[mt] = *(const short8*)&Als[wave_m * 64 + mt * 16 + l15][ko];
#pragma unroll
            for (int nt = 0; nt < 4; nt++)
                bfr[nt] = *(const short8*)&Bls[wave_n * 64 + nt * 16 + l15][ko];
#pragma unroll
            for (int mt = 0; mt < 4; mt++)
#pragma unroll
                for (int nt = 0; nt < 4; nt++)
                    acc[mt][nt] = __builtin_amdgcn_mfma_f32_16x16x32_bf16(
                        af[mt], bfr[nt], acc[mt][nt], 0, 0, 0);
        }
        __syncthreads();
    }

    // ---- epilogue: D row = quad*4 + reg, col = l15 ----
    float* Pz = SPLIT ? ((float*)Cv + (size_t)blockIdx.z * N * M) : nullptr;
#pragma unroll
    for (int mt = 0; mt < 4; mt++) {
        int rbase = bm0 + wave_m * 64 + mt * 16 + quad * 4;
#pragma unroll
        for (int nt = 0; nt < 4; nt++) {
            int col = bn0 + wave_n * 64 + nt * 16 + l15;
            float bv = BIAS ? bias[col] : 0.f;
#pragma unroll
            for (int r = 0; r < 4; r++) {
                int row = rbase + r;
                if (row >= N) continue;
                float x = acc[mt][nt][r];
                if (SPLIT) {
                    __builtin_nontemporal_store(x, &Pz[(size_t)row * M + col]);
                } else {
                    if (BIAS) x += bv;
                    if (ACT == 1) x = x > 0.f ? x : 0.1f * x;
                    if (CBF) __builtin_nontemporal_store(f2bf(x), (bf16_t*)Cv + (size_t)row * M + col);
                    else     __builtin_nontemporal_store(x, (float*)Cv + (size_t)row * M + col);
                }
            }
        }
    }
}

// ---------------- split-K reduce + bias + leaky-relu ----------------

template <int S, bool CBF, int ACT>
__global__ __launch_bounds__(256) void k_red(
        const float* __restrict__ part, const float* __restrict__ bias,
        void* __restrict__ out, int GM, int Mmask) {
    int i = (blockIdx.x * 256 + threadIdx.x) * 4;
    if (i >= GM) return;
    float4 s = *(const float4*)&part[i];
#pragma unroll
    for (int z = 1; z < S; z++) {
        float4 p = *(const float4*)&part[(size_t)z * GM + i];
        s.x += p.x; s.y += p.y; s.z += p.z; s.w += p.w;
    }
    float4 b = *(const float4*)&bias[i & Mmask];
    float v[4] = {s.x + b.x, s.y + b.y, s.z + b.z, s.w + b.w};
#pragma unroll
    for (int j = 0; j < 4; j++)
        if (ACT == 1) v[j] = v[j] > 0.f ? v[j] : 0.1f * v[j];
    if (CBF) {
        u16x4 o = {f2bf(v[0]), f2bf(v[1]), f2bf(v[2]), f2bf(v[3])};
        __builtin_nontemporal_store(o, (u16x4*)((bf16_t*)out + i));
    } else {
        float4 o; o.x = v[0]; o.y = v[1]; o.z = v[2]; o.w = v[3];
        *(float4*)((float*)out + i) = o;
    }
}

// ---------------- fused aggregation (+optional bias+leaky-relu) -------------
// One wave per node; FPL = F/64 consecutive bf16 per lane; fp32 accumulate.
// 2-unrolled edge loop with dual accumulators (2 gathers in flight).

template <int F, bool BACT>
__global__ __launch_bounds__(256) void k_agg(
        const bf16_t* __restrict__ H, const int* __restrict__ rowptr,
        const int* __restrict__ csr, const float* __restrict__ dis,
        const float* __restrict__ bias, bf16_t* __restrict__ out, int N) {
    constexpr int FPL = F / 64;
    int wv = (int)((blockIdx.x * blockDim.x + threadIdx.x) >> 6);
    int lane = threadIdx.x & 63;
    if (wv >= N) return;
    float di = dis[wv];
    int s = rowptr[wv], e = rowptr[wv + 1];

    auto load_row = [&](const bf16_t* p, float (&r)[FPL]) {
        if constexpr (FPL == 1) {
            r[0] = bf2f(*p);
        } else if constexpr (FPL == 2) {
            u16x2 v = *(const u16x2*)p;
            r[0] = bf2f(v[0]); r[1] = bf2f(v[1]);
        } else {
            u16x4 v = *(const u16x4*)p;
            r[0] = bf2f(v[0]); r[1] = bf2f(v[1]); r[2] = bf2f(v[2]); r[3] = bf2f(v[3]);
        }
    };

    float acc[FPL], acc2[FPL];
    {
        float r[FPL];
        load_row(H + (size_t)wv * F + lane * FPL, r);
        float sl = di * di;   // self-loop norm = 1/deg
#pragma unroll
        for (int f = 0; f < FPL; f++) { acc[f] = r[f] * sl; acc2[f] = 0.f; }
    }
    int p = s;
    for (; p + 2 <= e; p += 2) {
        int s0 = csr[p], s1 = csr[p + 1];
        float n0 = dis[s0] * di, n1 = dis[s1] * di;
        float r0[FPL], r1[FPL];
        load_row(H + (size_t)s0 * F + lane * FPL, r0);
        load_row(H + (size_t)s1 * F + lane * FPL, r1);
#pragma unroll
        for (int f = 0; f < FPL; f++) { acc[f] += r0[f] * n0; acc2[f] += r1[f] * n1; }
    }
    if (p < e) {
        int s0 = csr[p];
        float n0 = dis[s0] * di;
        float r0[FPL];
        load_row(H + (size_t)s0 * F + lane * FPL, r0);
#pragma unroll
        for (int f = 0; f < FPL; f++) acc[f] += r0[f] * n0;
    }

    float o[FPL];
#pragma unroll
    for (int f = 0; f < FPL; f++) {
        float v = acc[f] + acc2[f];
        if (BACT) {
            v += bias[lane * FPL + f];
            v = v > 0.f ? v : 0.1f * v;
        }
        o[f] = v;
    }
    bf16_t* op = out + (size_t)wv * F + lane * FPL;
    if constexpr (FPL == 1) {
        __builtin_nontemporal_store(f2bf(o[0]), op);
    } else if constexpr (FPL == 2) {
        u16x2 w = {f2bf(o[0]), f2bf(o[1])};
        __builtin_nontemporal_store(w, (u16x2*)op);
    } else {
        u16x4 w = {f2bf(o[0]), f2bf(o[1]), f2bf(o[2]), f2bf(o[3])};
        __builtin_nontemporal_store(w, (u16x4*)op);
    }
}

// ---------------- final head: dot(g2_row, L3w) + b, sigmoid ----------------

__global__ void k_head(const float* __restrict__ g2, const float* __restrict__ w,
                       const float* __restrict__ b, float* __restrict__ out, int G) {
    int wv = (int)((blockIdx.x * blockDim.x + threadIdx.x) >> 6);
    int lane = threadIdx.x & 63;
    if (wv >= G) return;
    const float2* gp = (const float2*)(g2 + (size_t)wv * 128);
    const float2* wp = (const float2*)w;
    float2 gv = gp[lane], wl = wp[lane];
    float s = gv.x * wl.x + gv.y * wl.y;
    for (int off = 32; off > 0; off >>= 1) s += __shfl_xor(s, off, 64);
    if (lane == 0) out[wv] = 1.f / (1.f + expf(-(s + b[0])));
}

// ---------------- launch ----------------

extern "C" void kernel_launch(void* const* d_in, const int* in_sizes, int n_in,
                              void* d_out, int out_size, void* d_ws, size_t ws_size,
                              hipStream_t stream) {
    const float* x   = (const float*)d_in[0];
    const int*   ei  = (const int*)d_in[1];
    const float* W1  = (const float*)d_in[2];  const float* b1  = (const float*)d_in[3];
    const float* W2  = (const float*)d_in[4];  const float* b2  = (const float*)d_in[5];
    const float* W3  = (const float*)d_in[6];  const float* b3  = (const float*)d_in[7];
    const float* L1w = (const float*)d_in[8];  const float* L1b = (const float*)d_in[9];
    const float* L2w = (const float*)d_in[10]; const float* L2b = (const float*)d_in[11];
    const float* L3w = (const float*)d_in[12]; const float* L3b = (const float*)d_in[13];
    float* out = (float*)d_out;

    const int C = 40;
    const int N = in_sizes[0] / C;     // 200000
    const int E = in_sizes[1] / 2;     // 1000000
    const int G = N / 40;              // 5000
    const int H1d = 128, H2d = 256, H3d = 128, M1 = 512, M2 = 128;

    // ---- workspace layout ----
    char* wsb = (char*)d_ws;
    size_t off = 0;
    auto alloc = [&](size_t bytes) -> void* {
        void* p = wsb + off;
        off += (bytes + 255) & ~(size_t)255;
        return p;
    };
    int*    flag   = (int*)alloc(4);
    int*    cnt    = (int*)alloc(4 * (size_t)(N + 1));
    int*    rowptr = (int*)alloc(4 * (size_t)(N + 1));
    int*    cursor = (int*)alloc(4 * (size_t)N);
    int*    csr    = (int*)alloc(4 * (size_t)E);
    int*    bsum   = (int*)alloc(4 * 512);
    float*  dis    = (float*)alloc(4 * (size_t)N);
    bf16_t* Hb     = (bf16_t*)alloc(2 * (size_t)N * H2d);   // ping [N,256] bf16 (102.4 MB)
    bf16_t* Xb     = (bf16_t*)alloc(2 * (size_t)N * H2d);   // pong [N,256] bf16 (102.4 MB)
    bf16_t* g1b    = (bf16_t*)alloc(2 * (size_t)G * M1);
    float*  g2     = (float*)alloc(4 * (size_t)G * M2);
    if (off > ws_size) return;   // fail cleanly instead of faulting

    // aliasing (all within dead regions at time of use):
    bf16_t* xb   = Hb;            // [N,64]  pad(x)          — dead after agg1
    bf16_t* A1b  = Xb;            // [N,64]  agg(x)          — dead after GEMM1
    bf16_t* H1   = Hb;            // [N,128] lrelu(A1 W1+b1) — overwrites xb
    bf16_t* A2   = Xb;            // [N,128] agg(H1)         — overwrites A1b
    bf16_t* H2   = Hb;            // [N,256] lrelu(A2 W2+b2) — overwrites H1
    bf16_t* H3p  = Xb;            // [N,128] H2 W3           — overwrites A2
    bf16_t* X3   = Hb;            // [N,128] lrelu(agg(H3p)+b3) — overwrites H2
    float*  part = (float*)Xb;    // split-K partials (81.9 MB) — overwrites H3p

    // ---- CSR by dst + deg_inv_sqrt ----
    hipMemsetAsync(cnt, 0, sizeof(int) * (size_t)(N + 1), stream);
    k_detect<<<1, 64, 0, stream>>>(ei, flag);
    k_hist<<<CDIV(E, 256), 256, 0, stream>>>(ei, E, flag, cnt, N);
    int total = N + 1;
    int nb = CDIV(total, 1024);
    k_blockred<<<nb, 256, 0, stream>>>(cnt, bsum, total);
    k_scanpartials<<<1, 256, 0, stream>>>(bsum, nb);
    k_scanwrite<<<nb, 256, 0, stream>>>(cnt, bsum, rowptr, cursor, dis, total, N);
    k_fill<<<CDIV(E, 256), 256, 0, stream>>>(ei, E, flag, cursor, csr, N);

    const int NB = CDIV(N, 128);       // 1563
    const int GB = CDIV(G, 128);       // 40
    const int AGG_G = CDIV(N, 4);      // 4 waves/block

    // ---- conv1 (aggregate-first in 40->64-dim) ----
    k_pad<<<CDIV(N * 64, 256), 256, 0, stream>>>(x, xb, N);
    k_agg<64, false><<<AGG_G, 256, 0, stream>>>(xb, rowptr, csr, dis, nullptr, A1b, N);
    gemm_mfma<true, true, true, 1, false><<<dim3(NB, 1), 256, 0, stream>>>(A1b, W1, b1, H1, N, 64, H1d, 0, 40);
    // ---- conv2 (aggregate-first in 128-dim) ----
    k_agg<128, false><<<AGG_G, 256, 0, stream>>>(H1, rowptr, csr, dis, nullptr, A2, N);
    gemm_mfma<true, true, true, 1, false><<<dim3(NB, 2), 256, 0, stream>>>(A2, W2, b2, H2, N, H1d, H2d, 0, H1d);
    // ---- conv3 (transform-first: 256 -> 128, aggregate in 128-dim) ----
    gemm_mfma<true, true, false, 0, false><<<dim3(NB, 1), 256, 0, stream>>>(H2, W3, nullptr, H3p, N, H2d, H3d, 0, H2d);
    k_agg<128, true><<<AGG_G, 256, 0, stream>>>(H3p, rowptr, csr, dis, b3, X3, N);

    // ---- readout MLP1: split-K S=8, Kseg=640 ----
    const int K1 = 40 * H3d; // 5120 ; X3 viewed as [G, 5120] bf16
    gemm_mfma<true, false, false, 0, true><<<dim3(GB, M1 / 128, 8), 256, 0, stream>>>(X3, L1w, nullptr, part, G, K1, M1, K1 / 8, K1);
    k_red<8, true, 1><<<CDIV(G * M1 / 4, 256), 256, 0, stream>>>(part, L1b, g1b, G * M1, M1 - 1);
    // ---- readout MLP2: split-K S=4, Kseg=128 ----
    gemm_mfma<true, false, false, 0, true><<<dim3(GB, 1, 4), 256, 0, stream>>>(g1b, L2w, nullptr, part, G, M1, M2, M1 / 4, M1);
    k_red<4, false, 1><<<CDIV(G * M2 / 4, 256), 256, 0, stream>>>(part, L2b, g2, G * M2, M2 - 1);
    k_head<<<CDIV(G, 4), 256, 0, stream>>>(g2, L3w, L3b, out, G);
}

// Round 7
// 747.479 us; speedup vs baseline: 2.0228x; 1.2032x over previous
//
#include <hip/hip_runtime.h>
#include <cmath>

#define CDIV(a,b) (((a)+(b)-1)/(b))

typedef unsigned short bf16_t;
using short8 = __attribute__((ext_vector_type(8))) short;
using f32x4  = __attribute__((ext_vector_type(4))) float;
using u16x2  = __attribute__((ext_vector_type(2))) unsigned short;
using u16x4  = __attribute__((ext_vector_type(4))) unsigned short;
using u16x8  = __attribute__((ext_vector_type(8))) unsigned short;

__device__ __forceinline__ float bf2f(unsigned short b) {
    unsigned u = ((unsigned)b) << 16;
    float f;
    __builtin_memcpy(&f, &u, 4);
    return f;
}
__device__ __forceinline__ unsigned short f2bf(float f) {
    unsigned u;
    __builtin_memcpy(&u, &f, 4);
    u = (u + 0x7FFFu + ((u >> 16) & 1u)) >> 16;
    return (unsigned short)u;
}

// ---------------- edge-index width detection ----------------
__global__ void k_detect(const int* __restrict__ ei, int* __restrict__ flag) {
    int t = threadIdx.x;  // 64 threads
    unsigned v = (unsigned)ei[2 * t + 1];
    unsigned long long m = __ballot(v != 0u);
    if (t == 0) *flag = (m == 0ULL) ? 1 : 0;  // 1 => int64 layout
}

__device__ __forceinline__ int edge_src(const int* ei, int E, int f, int i) {
    return f ? ei[2 * (size_t)i] : ei[i];
}
__device__ __forceinline__ int edge_dst(const int* ei, int E, int f, int i) {
    return f ? ei[2 * ((size_t)E + (size_t)i)] : ei[(size_t)E + (size_t)i];
}

// ---------------- CSR build ----------------

__global__ void k_hist(const int* __restrict__ ei, int E, const int* __restrict__ flag,
                       int* __restrict__ cnt, int N) {
    int i = blockIdx.x * 256 + threadIdx.x;
    if (i >= E) return;
    int d = edge_dst(ei, E, *flag, i);
    if ((unsigned)d < (unsigned)N) atomicAdd(&cnt[d], 1);
}

__global__ void k_blockred(const int* __restrict__ cnt, int* __restrict__ bsum, int total) {
    __shared__ int sd[256];
    int b = blockIdx.x, t = threadIdx.x;
    int base = b * 1024 + t * 4;
    int s = 0;
#pragma unroll
    for (int i = 0; i < 4; i++) { int idx = base + i; if (idx < total) s += cnt[idx]; }
    sd[t] = s; __syncthreads();
    for (int off = 128; off > 0; off >>= 1) { if (t < off) sd[t] += sd[t + off]; __syncthreads(); }
    if (t == 0) bsum[b] = sd[0];
}

__global__ void k_scanpartials(int* bsum, int nb) {
    __shared__ int sd[256];
    int t = threadIdx.x;
    int v = (t < nb) ? bsum[t] : 0;
    sd[t] = v; __syncthreads();
    for (int off = 1; off < 256; off <<= 1) {
        int y = (t >= off) ? sd[t - off] : 0;
        __syncthreads();
        sd[t] += y;
        __syncthreads();
    }
    if (t < nb) bsum[t] = sd[t] - v;   // exclusive
}

__global__ void k_scanwrite(const int* __restrict__ cnt, const int* __restrict__ bsum,
                            int* __restrict__ rowptr, int* __restrict__ cursor,
                            float* __restrict__ dis, int total, int N) {
    __shared__ int sd[256];
    int b = blockIdx.x, t = threadIdx.x;
    int base = b * 1024 + t * 4;
    int v[4]; int s = 0;
#pragma unroll
    for (int i = 0; i < 4; i++) { int idx = base + i; v[i] = (idx < total) ? cnt[idx] : 0; s += v[i]; }
    sd[t] = s; __syncthreads();
    for (int off = 1; off < 256; off <<= 1) {
        int y = (t >= off) ? sd[t - off] : 0;
        __syncthreads();
        sd[t] += y;
        __syncthreads();
    }
    int pre = bsum[b] + sd[t] - s;
#pragma unroll
    for (int i = 0; i < 4; i++) {
        int idx = base + i;
        if (idx < total) {
            rowptr[idx] = pre;
            if (idx < N) { cursor[idx] = pre; dis[idx] = rsqrtf((float)v[i] + 1.0f); }
            pre += v[i];
        }
    }
}

__global__ void k_fill(const int* __restrict__ ei, int E, const int* __restrict__ flag,
                       int* __restrict__ cursor, int* __restrict__ csr, int N) {
    int i = blockIdx.x * 256 + threadIdx.x;
    if (i >= E) return;
    int f = *flag;
    int s = edge_src(ei, E, f, i);
    int d = edge_dst(ei, E, f, i);
    if ((unsigned)d < (unsigned)N && (unsigned)s < (unsigned)N) {
        int p = atomicAdd(&cursor[d], 1);
        csr[p] = s;
    }
}

// ---------------- pad/convert x: [N,40] fp32 -> [N,64] bf16 (zero-padded) ----

__global__ __launch_bounds__(256) void k_pad(const float* __restrict__ x,
                                             bf16_t* __restrict__ xb, int N) {
    int i = blockIdx.x * 256 + threadIdx.x;
    int row = i >> 6, col = i & 63;
    if (row >= N) return;
    float v = (col < 40) ? x[(size_t)row * 40 + col] : 0.f;
    xb[(size_t)row * 64 + col] = f2bf(v);
}

// ---------------- MFMA GEMM: C[i][j] = sum_k A[i][k] * W[j][k] ----------------
// A: [N,K] row-major (bf16 if ABF else fp32), W: [M,KW] row-major fp32
// (bf16-converted in staging; K-KW zero-padded, KW multiple of 8).
// 128x128 tile, 4 waves (2x2), 4x4 frags of mfma_f32_16x16x32_bf16, BK=64.
// SPLIT: blockIdx.z selects K-segment; fp32 partials to Cv + z*N*M.
// CBF non-split epilogue: LDS transpose -> coalesced u16x8 row stores.

template <bool ABF, bool CBF, bool BIAS, int ACT, bool SPLIT>
__global__ __launch_bounds__(256) void gemm_mfma(
        const void* __restrict__ Av, const float* __restrict__ W,
        const float* __restrict__ bias, void* __restrict__ Cv,
        int N, int K, int M, int Kseg, int KW) {
    constexpr int BM = 128, BN = 128, BK = 64;
    constexpr int LDK = BK + 8;
    // staging: A tile [0, BM*LDK), B tile [BM*LDK, 2*BM*LDK) = 36864 B total.
    // epilogue transpose reuses the same LDS: 4 waves x 64 x 68 = 34816 B.
    __shared__ __align__(16) unsigned short lds[2 * BM * LDK];
    unsigned short* Als = lds;
    unsigned short* Bls = lds + BM * LDK;

    int t = threadIdx.x;
    int lane = t & 63, wid = t >> 6;
    int quad = lane >> 4, l15 = lane & 15;
    int wave_m = wid & 1, wave_n = wid >> 1;
    int bm0 = blockIdx.x * BM;
    int bn0 = blockIdx.y * BN;
    int kbeg = SPLIT ? (int)blockIdx.z * Kseg : 0;
    int kend = SPLIT ? min(kbeg + Kseg, K) : K;

    f32x4 acc[4][4] = {};

    for (int k0 = kbeg; k0 < kend; k0 += BK) {
        // ---- stage A tile ----
#pragma unroll
        for (int it = 0; it < 4; it++) {
            int idx = t + it * 256;
            int row = idx >> 3, c = idx & 7;
            int g = bm0 + row;
            int kk = k0 + c * 8;
            short8 v = {};
            if (g < N && kk + 8 <= K) {
                if (ABF) {
                    v = *(const short8*)((const bf16_t*)Av + (size_t)g * K + kk);
                } else {
                    const float4* p = (const float4*)((const float*)Av + (size_t)g * K + kk);
                    float4 a = p[0], b = p[1];
                    v[0] = (short)f2bf(a.x); v[1] = (short)f2bf(a.y);
                    v[2] = (short)f2bf(a.z); v[3] = (short)f2bf(a.w);
                    v[4] = (short)f2bf(b.x); v[5] = (short)f2bf(b.y);
                    v[6] = (short)f2bf(b.z); v[7] = (short)f2bf(b.w);
                }
            }
            *(short8*)&Als[row * LDK + c * 8] = v;
        }
        // ---- stage W tile (fp32 -> bf16, rows of length KW, zero-pad to K) ----
#pragma unroll
        for (int it = 0; it < 4; it++) {
            int idx = t + it * 256;
            int row = idx >> 3, c = idx & 7;
            int g = bn0 + row;
            int kk = k0 + c * 8;
            short8 v = {};
            if (g < M && kk + 8 <= KW) {
                const float4* p = (const float4*)(W + (size_t)g * KW + kk);
                float4 a = p[0], b = p[1];
                v[0] = (short)f2bf(a.x); v[1] = (short)f2bf(a.y);
                v[2] = (short)f2bf(a.z); v[3] = (short)f2bf(a.w);
                v[4] = (short)f2bf(b.x); v[5] = (short)f2bf(b.y);
                v[6] = (short)f2bf(b.z); v[7] = (short)f2bf(b.w);
            }
            *(short8*)&Bls[row * LDK + c * 8] = v;
        }
        __syncthreads();

#pragma unroll
        for (int ks = 0; ks < 2; ks++) {
            short8 af[4], bfr[4];
            int ko = ks * 32 + quad * 8;
#pragma unroll
            for (int mt = 0; mt < 4; mt++)
                af[mt] = *(const short8*)&Als[(wave_m * 64 + mt * 16 + l15) * LDK + ko];
#pragma unroll
            for (int nt = 0; nt < 4; nt++)
                bfr[nt] = *(const short8*)&Bls[(wave_n * 64 + nt * 16 + l15) * LDK + ko];
#pragma unroll
            for (int mt = 0; mt < 4; mt++)
#pragma unroll
                for (int nt = 0; nt < 4; nt++)
                    acc[mt][nt] = __builtin_amdgcn_mfma_f32_16x16x32_bf16(
                        af[mt], bfr[nt], acc[mt][nt], 0, 0, 0);
        }
        __syncthreads();
    }

    if (!SPLIT && CBF) {
        // ---- coalesced epilogue: per-wave 64x64 patch through LDS ----
        constexpr int TST = 68;   // transpose row stride (shorts)
        unsigned short* tw = lds + wid * 64 * TST;
#pragma unroll
        for (int mt = 0; mt < 4; mt++) {
#pragma unroll
            for (int nt = 0; nt < 4; nt++) {
                int tcol = nt * 16 + l15;
                float bv = BIAS ? bias[bn0 + wave_n * 64 + tcol] : 0.f;
#pragma unroll
                for (int r = 0; r < 4; r++) {
                    float x = acc[mt][nt][r];
                    if (BIAS) x += bv;
                    if (ACT == 1) x = x > 0.f ? x : 0.1f * x;
                    tw[(mt * 16 + quad * 4 + r) * TST + tcol] = f2bf(x);
                }
            }
        }
        __syncthreads();
        bf16_t* C = (bf16_t*)Cv;
        int lrow0 = lane >> 3, lcol = (lane & 7) * 8;
#pragma unroll
        for (int it = 0; it < 8; it++) {
            int lrow = it * 8 + lrow0;
            int row = bm0 + wave_m * 64 + lrow;
            if (row < N) {
                u16x8 v = *(const u16x8*)&tw[lrow * TST + lcol];
                *(u16x8*)&C[(size_t)row * M + bn0 + wave_n * 64 + lcol] = v;
            }
        }
    } else {
        // ---- scalar epilogue (fp32 partials / fp32 out) ----
        float* Pz = SPLIT ? ((float*)Cv + (size_t)blockIdx.z * N * M) : (float*)Cv;
#pragma unroll
        for (int mt = 0; mt < 4; mt++) {
            int rbase = bm0 + wave_m * 64 + mt * 16 + quad * 4;
#pragma unroll
            for (int nt = 0; nt < 4; nt++) {
                int col = bn0 + wave_n * 64 + nt * 16 + l15;
                float bv = (BIAS && !SPLIT) ? bias[col] : 0.f;
#pragma unroll
                for (int r = 0; r < 4; r++) {
                    int row = rbase + r;
                    if (row >= N) continue;
                    float x = acc[mt][nt][r];
                    if (!SPLIT) {
                        if (BIAS) x += bv;
                        if (ACT == 1) x = x > 0.f ? x : 0.1f * x;
                    }
                    Pz[(size_t)row * M + col] = x;
                }
            }
        }
    }
}

// ---------------- split-K reduce + bias + leaky-relu ----------------

template <int S, bool CBF, int ACT>
__global__ __launch_bounds__(256) void k_red(
        const float* __restrict__ part, const float* __restrict__ bias,
        void* __restrict__ out, int GM, int Mmask) {
    int i = (blockIdx.x * 256 + threadIdx.x) * 4;
    if (i >= GM) return;
    float4 s = *(const float4*)&part[i];
#pragma unroll
    for (int z = 1; z < S; z++) {
        float4 p = *(const float4*)&part[(size_t)z * GM + i];
        s.x += p.x; s.y += p.y; s.z += p.z; s.w += p.w;
    }
    float4 b = *(const float4*)&bias[i & Mmask];
    float v[4] = {s.x + b.x, s.y + b.y, s.z + b.z, s.w + b.w};
#pragma unroll
    for (int j = 0; j < 4; j++)
        if (ACT == 1) v[j] = v[j] > 0.f ? v[j] : 0.1f * v[j];
    if (CBF) {
        u16x4 o = {f2bf(v[0]), f2bf(v[1]), f2bf(v[2]), f2bf(v[3])};
        *(u16x4*)((bf16_t*)out + i) = o;
    } else {
        float4 o; o.x = v[0]; o.y = v[1]; o.z = v[2]; o.w = v[3];
        *(float4*)((float*)out + i) = o;
    }
}

// ---------------- fused aggregation (+optional bias+leaky-relu) -------------
// One wave per node; FPL = F/64 consecutive bf16 per lane; fp32 accumulate.
// 2-unrolled edge loop with dual accumulators (2 gathers in flight).

template <int F, bool BACT>
__global__ __launch_bounds__(256) void k_agg(
        const bf16_t* __restrict__ H, const int* __restrict__ rowptr,
        const int* __restrict__ csr, const float* __restrict__ dis,
        const float* __restrict__ bias, bf16_t* __restrict__ out, int N) {
    constexpr int FPL = F / 64;
    int wv = (int)((blockIdx.x * blockDim.x + threadIdx.x) >> 6);
    int lane = threadIdx.x & 63;
    if (wv >= N) return;
    float di = dis[wv];
    int s = rowptr[wv], e = rowptr[wv + 1];

    auto load_row = [&](const bf16_t* p, float (&r)[FPL]) {
        if constexpr (FPL == 1) {
            r[0] = bf2f(*p);
        } else if constexpr (FPL == 2) {
            u16x2 v = *(const u16x2*)p;
            r[0] = bf2f(v[0]); r[1] = bf2f(v[1]);
        } else {
            u16x4 v = *(const u16x4*)p;
            r[0] = bf2f(v[0]); r[1] = bf2f(v[1]); r[2] = bf2f(v[2]); r[3] = bf2f(v[3]);
        }
    };

    float acc[FPL], acc2[FPL];
    {
        float r[FPL];
        load_row(H + (size_t)wv * F + lane * FPL, r);
        float sl = di * di;   // self-loop norm = 1/deg
#pragma unroll
        for (int f = 0; f < FPL; f++) { acc[f] = r[f] * sl; acc2[f] = 0.f; }
    }
    int p = s;
    for (; p + 2 <= e; p += 2) {
        int s0 = csr[p], s1 = csr[p + 1];
        float n0 = dis[s0] * di, n1 = dis[s1] * di;
        float r0[FPL], r1[FPL];
        load_row(H + (size_t)s0 * F + lane * FPL, r0);
        load_row(H + (size_t)s1 * F + lane * FPL, r1);
#pragma unroll
        for (int f = 0; f < FPL; f++) { acc[f] += r0[f] * n0; acc2[f] += r1[f] * n1; }
    }
    if (p < e) {
        int s0 = csr[p];
        float n0 = dis[s0] * di;
        float r0[FPL];
        load_row(H + (size_t)s0 * F + lane * FPL, r0);
#pragma unroll
        for (int f = 0; f < FPL; f++) acc[f] += r0[f] * n0;
    }

    float o[FPL];
#pragma unroll
    for (int f = 0; f < FPL; f++) {
        float v = acc[f] + acc2[f];
        if (BACT) {
            v += bias[lane * FPL + f];
            v = v > 0.f ? v : 0.1f * v;
        }
        o[f] = v;
    }
    bf16_t* op = out + (size_t)wv * F + lane * FPL;
    if constexpr (FPL == 1) {
        *op = f2bf(o[0]);
    } else if constexpr (FPL == 2) {
        u16x2 w = {f2bf(o[0]), f2bf(o[1])};
        *(u16x2*)op = w;
    } else {
        u16x4 w = {f2bf(o[0]), f2bf(o[1]), f2bf(o[2]), f2bf(o[3])};
        *(u16x4*)op = w;
    }
}

// ---------------- final head: dot(g2_row, L3w) + b, sigmoid ----------------

__global__ void k_head(const float* __restrict__ g2, const float* __restrict__ w,
                       const float* __restrict__ b, float* __restrict__ out, int G) {
    int wv = (int)((blockIdx.x * blockDim.x + threadIdx.x) >> 6);
    int lane = threadIdx.x & 63;
    if (wv >= G) return;
    const float2* gp = (const float2*)(g2 + (size_t)wv * 128);
    const float2* wp = (const float2*)w;
    float2 gv = gp[lane], wl = wp[lane];
    float s = gv.x * wl.x + gv.y * wl.y;
    for (int off = 32; off > 0; off >>= 1) s += __shfl_xor(s, off, 64);
    if (lane == 0) out[wv] = 1.f / (1.f + expf(-(s + b[0])));
}

// ---------------- launch ----------------

extern "C" void kernel_launch(void* const* d_in, const int* in_sizes, int n_in,
                              void* d_out, int out_size, void* d_ws, size_t ws_size,
                              hipStream_t stream) {
    const float* x   = (const float*)d_in[0];
    const int*   ei  = (const int*)d_in[1];
    const float* W1  = (const float*)d_in[2];  const float* b1  = (const float*)d_in[3];
    const float* W2  = (const float*)d_in[4];  const float* b2  = (const float*)d_in[5];
    const float* W3  = (const float*)d_in[6];  const float* b3  = (const float*)d_in[7];
    const float* L1w = (const float*)d_in[8];  const float* L1b = (const float*)d_in[9];
    const float* L2w = (const float*)d_in[10]; const float* L2b = (const float*)d_in[11];
    const float* L3w = (const float*)d_in[12]; const float* L3b = (const float*)d_in[13];
    float* out = (float*)d_out;

    const int C = 40;
    const int N = in_sizes[0] / C;     // 200000
    const int E = in_sizes[1] / 2;     // 1000000
    const int G = N / 40;              // 5000
    const int H1d = 128, H2d = 256, H3d = 128, M1 = 512, M2 = 128;

    // ---- workspace layout ----
    char* wsb = (char*)d_ws;
    size_t off = 0;
    auto alloc = [&](size_t bytes) -> void* {
        void* p = wsb + off;
        off += (bytes + 255) & ~(size_t)255;
        return p;
    };
    int*    flag   = (int*)alloc(4);
    int*    cnt    = (int*)alloc(4 * (size_t)(N + 1));
    int*    rowptr = (int*)alloc(4 * (size_t)(N + 1));
    int*    cursor = (int*)alloc(4 * (size_t)N);
    int*    csr    = (int*)alloc(4 * (size_t)E);
    int*    bsum   = (int*)alloc(4 * 512);
    float*  dis    = (float*)alloc(4 * (size_t)N);
    bf16_t* Hb     = (bf16_t*)alloc(2 * (size_t)N * H2d);   // ping [N,256] bf16 (102.4 MB)
    bf16_t* Xb     = (bf16_t*)alloc(2 * (size_t)N * H2d);   // pong [N,256] bf16 (102.4 MB)
    bf16_t* g1b    = (bf16_t*)alloc(2 * (size_t)G * M1);
    float*  g2     = (float*)alloc(4 * (size_t)G * M2);
    if (off > ws_size) return;   // fail cleanly instead of faulting

    // aliasing (all within dead regions at time of use):
    bf16_t* xb   = Hb;            // [N,64]  pad(x)          — dead after agg1
    bf16_t* A1b  = Xb;            // [N,64]  agg(x)          — dead after GEMM1
    bf16_t* H1   = Hb;            // [N,128] lrelu(A1 W1+b1) — overwrites xb
    bf16_t* A2   = Xb;            // [N,128] agg(H1)         — overwrites A1b
    bf16_t* H2   = Hb;            // [N,256] lrelu(A2 W2+b2) — overwrites H1
    bf16_t* H3p  = Xb;            // [N,128] H2 W3           — overwrites A2
    bf16_t* X3   = Hb;            // [N,128] lrelu(agg(H3p)+b3) — overwrites H2
    float*  part = (float*)Xb;    // split-K partials (81.9 MB) — overwrites H3p

    // ---- CSR by dst + deg_inv_sqrt ----
    hipMemsetAsync(cnt, 0, sizeof(int) * (size_t)(N + 1), stream);
    k_detect<<<1, 64, 0, stream>>>(ei, flag);
    k_hist<<<CDIV(E, 256), 256, 0, stream>>>(ei, E, flag, cnt, N);
    int total = N + 1;
    int nb = CDIV(total, 1024);
    k_blockred<<<nb, 256, 0, stream>>>(cnt, bsum, total);
    k_scanpartials<<<1, 256, 0, stream>>>(bsum, nb);
    k_scanwrite<<<nb, 256, 0, stream>>>(cnt, bsum, rowptr, cursor, dis, total, N);
    k_fill<<<CDIV(E, 256), 256, 0, stream>>>(ei, E, flag, cursor, csr, N);

    const int NB = CDIV(N, 128);       // 1563
    const int GB = CDIV(G, 128);       // 40
    const int AGG_G = CDIV(N, 4);      // 4 waves/block

    // ---- conv1 (aggregate-first in 40->64-dim) ----
    k_pad<<<CDIV(N * 64, 256), 256, 0, stream>>>(x, xb, N);
    k_agg<64, false><<<AGG_G, 256, 0, stream>>>(xb, rowptr, csr, dis, nullptr, A1b, N);
    gemm_mfma<true, true, true, 1, false><<<dim3(NB, 1), 256, 0, stream>>>(A1b, W1, b1, H1, N, 64, H1d, 0, 40);
    // ---- conv2 (aggregate-first in 128-dim) ----
    k_agg<128, false><<<AGG_G, 256, 0, stream>>>(H1, rowptr, csr, dis, nullptr, A2, N);
    gemm_mfma<true, true, true, 1, false><<<dim3(NB, 2), 256, 0, stream>>>(A2, W2, b2, H2, N, H1d, H2d, 0, H1d);
    // ---- conv3 (transform-first: 256 -> 128, aggregate in 128-dim) ----
    gemm_mfma<true, true, false, 0, false><<<dim3(NB, 1), 256, 0, stream>>>(H2, W3, nullptr, H3p, N, H2d, H3d, 0, H2d);
    k_agg<128, true><<<AGG_G, 256, 0, stream>>>(H3p, rowptr, csr, dis, b3, X3, N);

    // ---- readout MLP1: split-K S=8, Kseg=640 ----
    const int K1 = 40 * H3d; // 5120 ; X3 viewed as [G, 5120] bf16
    gemm_mfma<true, false, false, 0, true><<<dim3(GB, M1 / 128, 8), 256, 0, stream>>>(X3, L1w, nullptr, part, G, K1, M1, K1 / 8, K1);
    k_red<8, true, 1><<<CDIV(G * M1 / 4, 256), 256, 0, stream>>>(part, L1b, g1b, G * M1, M1 - 1);
    // ---- readout MLP2: split-K S=4, Kseg=128 ----
    gemm_mfma<true, false, false, 0, true><<<dim3(GB, 1, 4), 256, 0, stream>>>(g1b, L2w, nullptr, part, G, M1, M2, M1 / 4, M1);
    k_red<4, false, 1><<<CDIV(G * M2 / 4, 256), 256, 0, stream>>>(part, L2b, g2, G * M2, M2 - 1);
    k_head<<<CDIV(G, 4), 256, 0, stream>>>(g2, L3w, L3b, out, G);
}

// Round 8
// 738.427 us; speedup vs baseline: 2.0476x; 1.0123x over previous
//
#include <hip/hip_runtime.h>
#include <cmath>

#define CDIV(a,b) (((a)+(b)-1)/(b))

typedef unsigned short bf16_t;
using short8 = __attribute__((ext_vector_type(8))) short;
using f32x4  = __attribute__((ext_vector_type(4))) float;
using u16x2  = __attribute__((ext_vector_type(2))) unsigned short;
using u16x4  = __attribute__((ext_vector_type(4))) unsigned short;
using u16x8  = __attribute__((ext_vector_type(8))) unsigned short;

__device__ __forceinline__ float bf2f(unsigned short b) {
    unsigned u = ((unsigned)b) << 16;
    float f;
    __builtin_memcpy(&f, &u, 4);
    return f;
}
__device__ __forceinline__ unsigned short f2bf(float f) {
    unsigned u;
    __builtin_memcpy(&u, &f, 4);
    u = (u + 0x7FFFu + ((u >> 16) & 1u)) >> 16;
    return (unsigned short)u;
}

// ---------------- edge-index width detection ----------------
__global__ void k_detect(const int* __restrict__ ei, int* __restrict__ flag) {
    int t = threadIdx.x;  // 64 threads
    unsigned v = (unsigned)ei[2 * t + 1];
    unsigned long long m = __ballot(v != 0u);
    if (t == 0) *flag = (m == 0ULL) ? 1 : 0;  // 1 => int64 layout
}

__device__ __forceinline__ int edge_src(const int* ei, int E, int f, int i) {
    return f ? ei[2 * (size_t)i] : ei[i];
}
__device__ __forceinline__ int edge_dst(const int* ei, int E, int f, int i) {
    return f ? ei[2 * ((size_t)E + (size_t)i)] : ei[(size_t)E + (size_t)i];
}

// ---------------- CSR build ----------------

__global__ void k_hist(const int* __restrict__ ei, int E, const int* __restrict__ flag,
                       int* __restrict__ cnt, int N) {
    int i = blockIdx.x * 256 + threadIdx.x;
    if (i >= E) return;
    int d = edge_dst(ei, E, *flag, i);
    if ((unsigned)d < (unsigned)N) atomicAdd(&cnt[d], 1);
}

__global__ void k_blockred(const int* __restrict__ cnt, int* __restrict__ bsum, int total) {
    __shared__ int sd[256];
    int b = blockIdx.x, t = threadIdx.x;
    int base = b * 1024 + t * 4;
    int s = 0;
#pragma unroll
    for (int i = 0; i < 4; i++) { int idx = base + i; if (idx < total) s += cnt[idx]; }
    sd[t] = s; __syncthreads();
    for (int off = 128; off > 0; off >>= 1) { if (t < off) sd[t] += sd[t + off]; __syncthreads(); }
    if (t == 0) bsum[b] = sd[0];
}

__global__ void k_scanpartials(int* bsum, int nb) {
    __shared__ int sd[256];
    int t = threadIdx.x;
    int v = (t < nb) ? bsum[t] : 0;
    sd[t] = v; __syncthreads();
    for (int off = 1; off < 256; off <<= 1) {
        int y = (t >= off) ? sd[t - off] : 0;
        __syncthreads();
        sd[t] += y;
        __syncthreads();
    }
    if (t < nb) bsum[t] = sd[t] - v;   // exclusive
}

__global__ void k_scanwrite(const int* __restrict__ cnt, const int* __restrict__ bsum,
                            int* __restrict__ rowptr, int* __restrict__ cursor,
                            float* __restrict__ dis, int total, int N) {
    __shared__ int sd[256];
    int b = blockIdx.x, t = threadIdx.x;
    int base = b * 1024 + t * 4;
    int v[4]; int s = 0;
#pragma unroll
    for (int i = 0; i < 4; i++) { int idx = base + i; v[i] = (idx < total) ? cnt[idx] : 0; s += v[i]; }
    sd[t] = s; __syncthreads();
    for (int off = 1; off < 256; off <<= 1) {
        int y = (t >= off) ? sd[t - off] : 0;
        __syncthreads();
        sd[t] += y;
        __syncthreads();
    }
    int pre = bsum[b] + sd[t] - s;
#pragma unroll
    for (int i = 0; i < 4; i++) {
        int idx = base + i;
        if (idx < total) {
            rowptr[idx] = pre;
            if (idx < N) { cursor[idx] = pre; dis[idx] = rsqrtf((float)v[i] + 1.0f); }
            pre += v[i];
        }
    }
}

__global__ void k_fill(const int* __restrict__ ei, int E, const int* __restrict__ flag,
                       int* __restrict__ cursor, int* __restrict__ csr, int N) {
    int i = blockIdx.x * 256 + threadIdx.x;
    if (i >= E) return;
    int f = *flag;
    int s = edge_src(ei, E, f, i);
    int d = edge_dst(ei, E, f, i);
    if ((unsigned)d < (unsigned)N && (unsigned)s < (unsigned)N) {
        int p = atomicAdd(&cursor[d], 1);
        csr[p] = s;
    }
}

// ---------------- pad/convert x: [N,40] fp32 -> [N,64] bf16 (zero-padded) ----

__global__ __launch_bounds__(256) void k_pad(const float* __restrict__ x,
                                             bf16_t* __restrict__ xb, int N) {
    int i = blockIdx.x * 256 + threadIdx.x;
    int row = i >> 6, col = i & 63;
    if (row >= N) return;
    float v = (col < 40) ? x[(size_t)row * 40 + col] : 0.f;
    xb[(size_t)row * 64 + col] = f2bf(v);
}

// ---------------- MFMA GEMM: C[i][j] = sum_k A[i][k] * W[j][k] ----------------
// A: [N,K] row-major (bf16 if ABF else fp32), W: [M,KW] row-major fp32
// (bf16-converted in staging; K-KW zero-padded, KW multiple of 8).
// 128x128 tile, 4 waves (2x2), 4x4 frags of mfma_f32_16x16x32_bf16, BK=64.
// SPLIT: blockIdx.z selects K-segment; fp32 partials to Cv + z*N*M.
// CBF non-split epilogue: LDS transpose -> coalesced u16x8 row stores.

template <bool ABF, bool CBF, bool BIAS, int ACT, bool SPLIT>
__global__ __launch_bounds__(256) void gemm_mfma(
        const void* __restrict__ Av, const float* __restrict__ W,
        const float* __restrict__ bias, void* __restrict__ Cv,
        int N, int K, int M, int Kseg, int KW) {
    constexpr int BM = 128, BN = 128, BK = 64;
    constexpr int LDK = BK + 8;
    __shared__ __align__(16) unsigned short lds[2 * BM * LDK];
    unsigned short* Als = lds;
    unsigned short* Bls = lds + BM * LDK;

    int t = threadIdx.x;
    int lane = t & 63, wid = t >> 6;
    int quad = lane >> 4, l15 = lane & 15;
    int wave_m = wid & 1, wave_n = wid >> 1;
    int bm0 = blockIdx.x * BM;
    int bn0 = blockIdx.y * BN;
    int kbeg = SPLIT ? (int)blockIdx.z * Kseg : 0;
    int kend = SPLIT ? min(kbeg + Kseg, K) : K;

    f32x4 acc[4][4] = {};

    for (int k0 = kbeg; k0 < kend; k0 += BK) {
        // ---- stage A tile ----
#pragma unroll
        for (int it = 0; it < 4; it++) {
            int idx = t + it * 256;
            int row = idx >> 3, c = idx & 7;
            int g = bm0 + row;
            int kk = k0 + c * 8;
            short8 v = {};
            if (g < N && kk + 8 <= K) {
                if (ABF) {
                    v = *(const short8*)((const bf16_t*)Av + (size_t)g * K + kk);
                } else {
                    const float4* p = (const float4*)((const float*)Av + (size_t)g * K + kk);
                    float4 a = p[0], b = p[1];
                    v[0] = (short)f2bf(a.x); v[1] = (short)f2bf(a.y);
                    v[2] = (short)f2bf(a.z); v[3] = (short)f2bf(a.w);
                    v[4] = (short)f2bf(b.x); v[5] = (short)f2bf(b.y);
                    v[6] = (short)f2bf(b.z); v[7] = (short)f2bf(b.w);
                }
            }
            *(short8*)&Als[row * LDK + c * 8] = v;
        }
        // ---- stage W tile (fp32 -> bf16, rows of length KW, zero-pad to K) ----
#pragma unroll
        for (int it = 0; it < 4; it++) {
            int idx = t + it * 256;
            int row = idx >> 3, c = idx & 7;
            int g = bn0 + row;
            int kk = k0 + c * 8;
            short8 v = {};
            if (g < M && kk + 8 <= KW) {
                const float4* p = (const float4*)(W + (size_t)g * KW + kk);
                float4 a = p[0], b = p[1];
                v[0] = (short)f2bf(a.x); v[1] = (short)f2bf(a.y);
                v[2] = (short)f2bf(a.z); v[3] = (short)f2bf(a.w);
                v[4] = (short)f2bf(b.x); v[5] = (short)f2bf(b.y);
                v[6] = (short)f2bf(b.z); v[7] = (short)f2bf(b.w);
            }
            *(short8*)&Bls[row * LDK + c * 8] = v;
        }
        __syncthreads();

#pragma unroll
        for (int ks = 0; ks < 2; ks++) {
            short8 af[4], bfr[4];
            int ko = ks * 32 + quad * 8;
#pragma unroll
            for (int mt = 0; mt < 4; mt++)
                af[mt] = *(const short8*)&Als[(wave_m * 64 + mt * 16 + l15) * LDK + ko];
#pragma unroll
            for (int nt = 0; nt < 4; nt++)
                bfr[nt] = *(const short8*)&Bls[(wave_n * 64 + nt * 16 + l15) * LDK + ko];
#pragma unroll
            for (int mt = 0; mt < 4; mt++)
#pragma unroll
                for (int nt = 0; nt < 4; nt++)
                    acc[mt][nt] = __builtin_amdgcn_mfma_f32_16x16x32_bf16(
                        af[mt], bfr[nt], acc[mt][nt], 0, 0, 0);
        }
        __syncthreads();
    }

    if (!SPLIT && CBF) {
        // ---- coalesced epilogue: per-wave 64x64 patch through LDS ----
        constexpr int TST = 68;   // transpose row stride (shorts)
        unsigned short* tw = lds + wid * 64 * TST;
#pragma unroll
        for (int mt = 0; mt < 4; mt++) {
#pragma unroll
            for (int nt = 0; nt < 4; nt++) {
                int tcol = nt * 16 + l15;
                float bv = BIAS ? bias[bn0 + wave_n * 64 + tcol] : 0.f;
#pragma unroll
                for (int r = 0; r < 4; r++) {
                    float x = acc[mt][nt][r];
                    if (BIAS) x += bv;
                    if (ACT == 1) x = x > 0.f ? x : 0.1f * x;
                    tw[(mt * 16 + quad * 4 + r) * TST + tcol] = f2bf(x);
                }
            }
        }
        __syncthreads();
        bf16_t* C = (bf16_t*)Cv;
        int lrow0 = lane >> 3, lcol = (lane & 7) * 8;
#pragma unroll
        for (int it = 0; it < 8; it++) {
            int lrow = it * 8 + lrow0;
            int row = bm0 + wave_m * 64 + lrow;
            if (row < N) {
                u16x8 v = *(const u16x8*)&tw[lrow * TST + lcol];
                *(u16x8*)&C[(size_t)row * M + bn0 + wave_n * 64 + lcol] = v;
            }
        }
    } else {
        // ---- scalar epilogue (fp32 partials / fp32 out) ----
        float* Pz = SPLIT ? ((float*)Cv + (size_t)blockIdx.z * N * M) : (float*)Cv;
#pragma unroll
        for (int mt = 0; mt < 4; mt++) {
            int rbase = bm0 + wave_m * 64 + mt * 16 + quad * 4;
#pragma unroll
            for (int nt = 0; nt < 4; nt++) {
                int col = bn0 + wave_n * 64 + nt * 16 + l15;
                float bv = (BIAS && !SPLIT) ? bias[col] : 0.f;
#pragma unroll
                for (int r = 0; r < 4; r++) {
                    int row = rbase + r;
                    if (row >= N) continue;
                    float x = acc[mt][nt][r];
                    if (!SPLIT) {
                        if (BIAS) x += bv;
                        if (ACT == 1) x = x > 0.f ? x : 0.1f * x;
                    }
                    Pz[(size_t)row * M + col] = x;
                }
            }
        }
    }
}

// ---------------- split-K reduce + bias + leaky-relu ----------------

template <int S, bool CBF, int ACT>
__global__ __launch_bounds__(256) void k_red(
        const float* __restrict__ part, const float* __restrict__ bias,
        void* __restrict__ out, int GM, int Mmask) {
    int i = (blockIdx.x * 256 + threadIdx.x) * 4;
    if (i >= GM) return;
    float4 s = *(const float4*)&part[i];
#pragma unroll
    for (int z = 1; z < S; z++) {
        float4 p = *(const float4*)&part[(size_t)z * GM + i];
        s.x += p.x; s.y += p.y; s.z += p.z; s.w += p.w;
    }
    float4 b = *(const float4*)&bias[i & Mmask];
    float v[4] = {s.x + b.x, s.y + b.y, s.z + b.z, s.w + b.w};
#pragma unroll
    for (int j = 0; j < 4; j++)
        if (ACT == 1) v[j] = v[j] > 0.f ? v[j] : 0.1f * v[j];
    if (CBF) {
        u16x4 o = {f2bf(v[0]), f2bf(v[1]), f2bf(v[2]), f2bf(v[3])};
        *(u16x4*)((bf16_t*)out + i) = o;
    } else {
        float4 o; o.x = v[0]; o.y = v[1]; o.z = v[2]; o.w = v[3];
        *(float4*)((float*)out + i) = o;
    }
}

// ---------------- fused aggregation, quarter-wave gather --------------------
// One wave per node; each 16-lane quarter gathers a FULL row (FPQ = F/16
// bf16/lane) for one edge -> 4 edges in flight per wave-instruction;
// unroll-2 doubles that. fp32 accumulate per quarter, then 2-step
// __shfl_xor(16,32) cross-quarter reduction; quarter 0 applies self-loop
// result + bias/act and stores the row.

template <int F, bool BACT>
__global__ __launch_bounds__(256) void k_agg(
        const bf16_t* __restrict__ H, const int* __restrict__ rowptr,
        const int* __restrict__ csr, const float* __restrict__ dis,
        const float* __restrict__ bias, bf16_t* __restrict__ out, int N) {
    constexpr int FPQ = F / 16;   // 8 for F=128, 4 for F=64
    int wv = (int)((blockIdx.x * blockDim.x + threadIdx.x) >> 6);
    int lane = threadIdx.x & 63;
    if (wv >= N) return;
    int quad = lane >> 4, l15 = lane & 15;
    float di = dis[wv];
    int s = rowptr[wv], e = rowptr[wv + 1];

    auto load_row = [&](const bf16_t* p, float (&r)[FPQ]) {
        if constexpr (FPQ == 4) {
            u16x4 v = *(const u16x4*)p;
#pragma unroll
            for (int f = 0; f < 4; f++) r[f] = bf2f(v[f]);
        } else {
            u16x8 v = *(const u16x8*)p;
#pragma unroll
            for (int f = 0; f < 8; f++) r[f] = bf2f(v[f]);
        }
    };

    float acc[FPQ], acc2[FPQ];
#pragma unroll
    for (int f = 0; f < FPQ; f++) { acc[f] = 0.f; acc2[f] = 0.f; }
    if (quad == 0) {
        float r[FPQ];
        load_row(H + (size_t)wv * F + l15 * FPQ, r);
        float sl = di * di;   // self-loop norm = 1/deg
#pragma unroll
        for (int f = 0; f < FPQ; f++) acc[f] = r[f] * sl;
    }

    int p = s + quad;
    for (; p + 4 < e; p += 8) {
        int s0 = csr[p], s1 = csr[p + 4];
        float n0 = dis[s0] * di, n1 = dis[s1] * di;
        float r0[FPQ], r1[FPQ];
        load_row(H + (size_t)s0 * F + l15 * FPQ, r0);
        load_row(H + (size_t)s1 * F + l15 * FPQ, r1);
#pragma unroll
        for (int f = 0; f < FPQ; f++) { acc[f] += r0[f] * n0; acc2[f] += r1[f] * n1; }
    }
    if (p < e) {
        int s0 = csr[p];
        float n0 = dis[s0] * di;
        float r0[FPQ];
        load_row(H + (size_t)s0 * F + l15 * FPQ, r0);
#pragma unroll
        for (int f = 0; f < FPQ; f++) acc[f] += r0[f] * n0;
    }

    // cross-quarter reduction (quad bits are lane bits 4,5)
#pragma unroll
    for (int f = 0; f < FPQ; f++) {
        float v = acc[f] + acc2[f];
        v += __shfl_xor(v, 16, 64);
        v += __shfl_xor(v, 32, 64);
        acc[f] = v;
    }

    if (quad == 0) {
        float o[FPQ];
#pragma unroll
        for (int f = 0; f < FPQ; f++) {
            float v = acc[f];
            if (BACT) {
                v += bias[l15 * FPQ + f];
                v = v > 0.f ? v : 0.1f * v;
            }
            o[f] = v;
        }
        bf16_t* op = out + (size_t)wv * F + l15 * FPQ;
        if constexpr (FPQ == 4) {
            u16x4 w = {f2bf(o[0]), f2bf(o[1]), f2bf(o[2]), f2bf(o[3])};
            *(u16x4*)op = w;
        } else {
            u16x8 w = {f2bf(o[0]), f2bf(o[1]), f2bf(o[2]), f2bf(o[3]),
                       f2bf(o[4]), f2bf(o[5]), f2bf(o[6]), f2bf(o[7])};
            *(u16x8*)op = w;
        }
    }
}

// ---------------- final head: dot(g2_row, L3w) + b, sigmoid ----------------

__global__ void k_head(const float* __restrict__ g2, const float* __restrict__ w,
                       const float* __restrict__ b, float* __restrict__ out, int G) {
    int wv = (int)((blockIdx.x * blockDim.x + threadIdx.x) >> 6);
    int lane = threadIdx.x & 63;
    if (wv >= G) return;
    const float2* gp = (const float2*)(g2 + (size_t)wv * 128);
    const float2* wp = (const float2*)w;
    float2 gv = gp[lane], wl = wp[lane];
    float s = gv.x * wl.x + gv.y * wl.y;
    for (int off = 32; off > 0; off >>= 1) s += __shfl_xor(s, off, 64);
    if (lane == 0) out[wv] = 1.f / (1.f + expf(-(s + b[0])));
}

// ---------------- launch ----------------

extern "C" void kernel_launch(void* const* d_in, const int* in_sizes, int n_in,
                              void* d_out, int out_size, void* d_ws, size_t ws_size,
                              hipStream_t stream) {
    const float* x   = (const float*)d_in[0];
    const int*   ei  = (const int*)d_in[1];
    const float* W1  = (const float*)d_in[2];  const float* b1  = (const float*)d_in[3];
    const float* W2  = (const float*)d_in[4];  const float* b2  = (const float*)d_in[5];
    const float* W3  = (const float*)d_in[6];  const float* b3  = (const float*)d_in[7];
    const float* L1w = (const float*)d_in[8];  const float* L1b = (const float*)d_in[9];
    const float* L2w = (const float*)d_in[10]; const float* L2b = (const float*)d_in[11];
    const float* L3w = (const float*)d_in[12]; const float* L3b = (const float*)d_in[13];
    float* out = (float*)d_out;

    const int C = 40;
    const int N = in_sizes[0] / C;     // 200000
    const int E = in_sizes[1] / 2;     // 1000000
    const int G = N / 40;              // 5000
    const int H1d = 128, H2d = 256, H3d = 128, M1 = 512, M2 = 128;

    // ---- workspace layout ----
    char* wsb = (char*)d_ws;
    size_t off = 0;
    auto alloc = [&](size_t bytes) -> void* {
        void* p = wsb + off;
        off += (bytes + 255) & ~(size_t)255;
        return p;
    };
    int*    flag   = (int*)alloc(4);
    int*    cnt    = (int*)alloc(4 * (size_t)(N + 1));
    int*    rowptr = (int*)alloc(4 * (size_t)(N + 1));
    int*    cursor = (int*)alloc(4 * (size_t)N);
    int*    csr    = (int*)alloc(4 * (size_t)E);
    int*    bsum   = (int*)alloc(4 * 512);
    float*  dis    = (float*)alloc(4 * (size_t)N);
    bf16_t* Hb     = (bf16_t*)alloc(2 * (size_t)N * H2d);   // ping [N,256] bf16 (102.4 MB)
    bf16_t* Xb     = (bf16_t*)alloc(2 * (size_t)N * H2d);   // pong [N,256] bf16 (102.4 MB)
    bf16_t* g1b    = (bf16_t*)alloc(2 * (size_t)G * M1);
    float*  g2     = (float*)alloc(4 * (size_t)G * M2);
    if (off > ws_size) return;   // fail cleanly instead of faulting

    // aliasing (all within dead regions at time of use):
    bf16_t* xb   = Hb;            // [N,64]  pad(x)          — dead after agg1
    bf16_t* A1b  = Xb;            // [N,64]  agg(x)          — dead after GEMM1
    bf16_t* H1   = Hb;            // [N,128] lrelu(A1 W1+b1) — overwrites xb
    bf16_t* A2   = Xb;            // [N,128] agg(H1)         — overwrites A1b
    bf16_t* H2   = Hb;            // [N,256] lrelu(A2 W2+b2) — overwrites H1
    bf16_t* H3p  = Xb;            // [N,128] H2 W3           — overwrites A2
    bf16_t* X3   = Hb;            // [N,128] lrelu(agg(H3p)+b3) — overwrites H2
    float*  part = (float*)Xb;    // split-K partials (81.9 MB) — overwrites H3p

    // ---- CSR by dst + deg_inv_sqrt ----
    hipMemsetAsync(cnt, 0, sizeof(int) * (size_t)(N + 1), stream);
    k_detect<<<1, 64, 0, stream>>>(ei, flag);
    k_hist<<<CDIV(E, 256), 256, 0, stream>>>(ei, E, flag, cnt, N);
    int total = N + 1;
    int nb = CDIV(total, 1024);
    k_blockred<<<nb, 256, 0, stream>>>(cnt, bsum, total);
    k_scanpartials<<<1, 256, 0, stream>>>(bsum, nb);
    k_scanwrite<<<nb, 256, 0, stream>>>(cnt, bsum, rowptr, cursor, dis, total, N);
    k_fill<<<CDIV(E, 256), 256, 0, stream>>>(ei, E, flag, cursor, csr, N);

    const int NB = CDIV(N, 128);       // 1563
    const int GB = CDIV(G, 128);       // 40
    const int AGG_G = CDIV(N, 4);      // 4 waves/block, one node per wave

    // ---- conv1 (aggregate-first in 40->64-dim) ----
    k_pad<<<CDIV(N * 64, 256), 256, 0, stream>>>(x, xb, N);
    k_agg<64, false><<<AGG_G, 256, 0, stream>>>(xb, rowptr, csr, dis, nullptr, A1b, N);
    gemm_mfma<true, true, true, 1, false><<<dim3(NB, 1), 256, 0, stream>>>(A1b, W1, b1, H1, N, 64, H1d, 0, 40);
    // ---- conv2 (aggregate-first in 128-dim) ----
    k_agg<128, false><<<AGG_G, 256, 0, stream>>>(H1, rowptr, csr, dis, nullptr, A2, N);
    gemm_mfma<true, true, true, 1, false><<<dim3(NB, 2), 256, 0, stream>>>(A2, W2, b2, H2, N, H1d, H2d, 0, H1d);
    // ---- conv3 (transform-first: 256 -> 128, aggregate in 128-dim) ----
    gemm_mfma<true, true, false, 0, false><<<dim3(NB, 1), 256, 0, stream>>>(H2, W3, nullptr, H3p, N, H2d, H3d, 0, H2d);
    k_agg<128, true><<<AGG_G, 256, 0, stream>>>(H3p, rowptr, csr, dis, b3, X3, N);

    // ---- readout MLP1: split-K S=8, Kseg=640 ----
    const int K1 = 40 * H3d; // 5120 ; X3 viewed as [G, 5120] bf16
    gemm_mfma<true, false, false, 0, true><<<dim3(GB, M1 / 128, 8), 256, 0, stream>>>(X3, L1w, nullptr, part, G, K1, M1, K1 / 8, K1);
    k_red<8, true, 1><<<CDIV(G * M1 / 4, 256), 256, 0, stream>>>(part, L1b, g1b, G * M1, M1 - 1);
    // ---- readout MLP2: split-K S=4, Kseg=128 ----
    gemm_mfma<true, false, false, 0, true><<<dim3(GB, 1, 4), 256, 0, stream>>>(g1b, L2w, nullptr, part, G, M1, M2, M1 / 4, M1);
    k_red<4, false, 1><<<CDIV(G * M2 / 4, 256), 256, 0, stream>>>(part, L2b, g2, G * M2, M2 - 1);
    k_head<<<CDIV(G, 4), 256, 0, stream>>>(g2, L3w, L3b, out, G);
}

// Round 9
// 675.883 us; speedup vs baseline: 2.2371x; 1.0925x over previous
//
#include <hip/hip_runtime.h>
#include <cmath>

#define CDIV(a,b) (((a)+(b)-1)/(b))

typedef unsigned short bf16_t;
using short8 = __attribute__((ext_vector_type(8))) short;
using f32x4  = __attribute__((ext_vector_type(4))) float;
using u16x2  = __attribute__((ext_vector_type(2))) unsigned short;
using u16x4  = __attribute__((ext_vector_type(4))) unsigned short;
using u16x8  = __attribute__((ext_vector_type(8))) unsigned short;

__device__ __forceinline__ float bf2f(unsigned short b) {
    unsigned u = ((unsigned)b) << 16;
    float f;
    __builtin_memcpy(&f, &u, 4);
    return f;
}
__device__ __forceinline__ unsigned short f2bf(float f) {
    unsigned u;
    __builtin_memcpy(&u, &f, 4);
    u = (u + 0x7FFFu + ((u >> 16) & 1u)) >> 16;
    return (unsigned short)u;
}

// ---------------- edge-index width detection ----------------
__global__ void k_detect(const int* __restrict__ ei, int* __restrict__ flag) {
    int t = threadIdx.x;  // 64 threads
    unsigned v = (unsigned)ei[2 * t + 1];
    unsigned long long m = __ballot(v != 0u);
    if (t == 0) *flag = (m == 0ULL) ? 1 : 0;  // 1 => int64 layout
}

__device__ __forceinline__ int edge_src(const int* ei, int E, int f, int i) {
    return f ? ei[2 * (size_t)i] : ei[i];
}
__device__ __forceinline__ int edge_dst(const int* ei, int E, int f, int i) {
    return f ? ei[2 * ((size_t)E + (size_t)i)] : ei[(size_t)E + (size_t)i];
}

// ---------------- CSR build ----------------

__global__ void k_hist(const int* __restrict__ ei, int E, const int* __restrict__ flag,
                       int* __restrict__ cnt, int N) {
    int i = blockIdx.x * 256 + threadIdx.x;
    if (i >= E) return;
    int d = edge_dst(ei, E, *flag, i);
    if ((unsigned)d < (unsigned)N) atomicAdd(&cnt[d], 1);
}

__global__ void k_blockred(const int* __restrict__ cnt, int* __restrict__ bsum, int total) {
    __shared__ int sd[256];
    int b = blockIdx.x, t = threadIdx.x;
    int base = b * 1024 + t * 4;
    int s = 0;
#pragma unroll
    for (int i = 0; i < 4; i++) { int idx = base + i; if (idx < total) s += cnt[idx]; }
    sd[t] = s; __syncthreads();
    for (int off = 128; off > 0; off >>= 1) { if (t < off) sd[t] += sd[t + off]; __syncthreads(); }
    if (t == 0) bsum[b] = sd[0];
}

__global__ void k_scanpartials(int* bsum, int nb) {
    __shared__ int sd[256];
    int t = threadIdx.x;
    int v = (t < nb) ? bsum[t] : 0;
    sd[t] = v; __syncthreads();
    for (int off = 1; off < 256; off <<= 1) {
        int y = (t >= off) ? sd[t - off] : 0;
        __syncthreads();
        sd[t] += y;
        __syncthreads();
    }
    if (t < nb) bsum[t] = sd[t] - v;   // exclusive
}

__global__ void k_scanwrite(const int* __restrict__ cnt, const int* __restrict__ bsum,
                            int* __restrict__ rowptr, int* __restrict__ cursor,
                            float* __restrict__ dis, int total, int N) {
    __shared__ int sd[256];
    int b = blockIdx.x, t = threadIdx.x;
    int base = b * 1024 + t * 4;
    int v[4]; int s = 0;
#pragma unroll
    for (int i = 0; i < 4; i++) { int idx = base + i; v[i] = (idx < total) ? cnt[idx] : 0; s += v[i]; }
    sd[t] = s; __syncthreads();
    for (int off = 1; off < 256; off <<= 1) {
        int y = (t >= off) ? sd[t - off] : 0;
        __syncthreads();
        sd[t] += y;
        __syncthreads();
    }
    int pre = bsum[b] + sd[t] - s;
#pragma unroll
    for (int i = 0; i < 4; i++) {
        int idx = base + i;
        if (idx < total) {
            rowptr[idx] = pre;
            if (idx < N) { cursor[idx] = pre; dis[idx] = rsqrtf((float)v[i] + 1.0f); }
            pre += v[i];
        }
    }
}

__global__ void k_fill(const int* __restrict__ ei, int E, const int* __restrict__ flag,
                       int* __restrict__ cursor, int* __restrict__ csr, int N) {
    int i = blockIdx.x * 256 + threadIdx.x;
    if (i >= E) return;
    int f = *flag;
    int s = edge_src(ei, E, f, i);
    int d = edge_dst(ei, E, f, i);
    if ((unsigned)d < (unsigned)N && (unsigned)s < (unsigned)N) {
        int p = atomicAdd(&cursor[d], 1);
        csr[p] = s;
    }
}

// ---------------- pad/convert x: [N,40] fp32 -> [N,64] bf16 (zero-padded) ----

__global__ __launch_bounds__(256) void k_pad(const float* __restrict__ x,
                                             bf16_t* __restrict__ xb, int N) {
    int i = blockIdx.x * 256 + threadIdx.x;
    int row = i >> 6, col = i & 63;
    if (row >= N) return;
    float v = (col < 40) ? x[(size_t)row * 40 + col] : 0.f;
    xb[(size_t)row * 64 + col] = f2bf(v);
}

// ---------------- weight pre-convert: fp32 [M,KW] -> bf16 [M,KP] ------------
// All five weights in one launch; KW, KP multiples of 8.

struct WcSeg { const float* src; bf16_t* dst; int M, KW, KP, nchunk; };

__global__ __launch_bounds__(256) void k_wconv(WcSeg s0, WcSeg s1, WcSeg s2,
                                               WcSeg s3, WcSeg s4, int total) {
    int i = blockIdx.x * 256 + threadIdx.x;
    if (i >= total) return;
    WcSeg s;
    if (i < s0.nchunk) s = s0;
    else if ((i -= s0.nchunk) < s1.nchunk) s = s1;
    else if ((i -= s1.nchunk) < s2.nchunk) s = s2;
    else if ((i -= s2.nchunk) < s3.nchunk) s = s3;
    else { i -= s3.nchunk; s = s4; }
    int cpr = s.KP >> 3;                // chunks per row
    int row = i / cpr, kk = (i % cpr) << 3;
    short8 v = {};
    if (kk < s.KW) {
        const float4* p = (const float4*)(s.src + (size_t)row * s.KW + kk);
        float4 a = p[0], b = p[1];
        v[0] = (short)f2bf(a.x); v[1] = (short)f2bf(a.y);
        v[2] = (short)f2bf(a.z); v[3] = (short)f2bf(a.w);
        v[4] = (short)f2bf(b.x); v[5] = (short)f2bf(b.y);
        v[6] = (short)f2bf(b.z); v[7] = (short)f2bf(b.w);
    }
    *(short8*)(s.dst + (size_t)row * s.KP + kk) = v;
}

// ---------------- MFMA GEMM: C[i][j] = sum_k A[i][k] * Wb[j][k] --------------
// A: [N,K] bf16, Wb: [M,K] bf16 (pre-converted). K multiple of 64, M of 128.
// 128x128 tile, 4 waves (2x2), 4x4 frags of mfma_f32_16x16x32_bf16, BK=64.
// LDS: XOR-swizzled chunk layout (chunk ^= row&7) -> conflict-free staging
// writes AND frag reads. SPLIT: blockIdx.z K-segment, fp32 partials.

template <bool CBF, bool BIAS, int ACT, bool SPLIT>
__global__ __launch_bounds__(256) void gemm_mfma(
        const bf16_t* __restrict__ A, const bf16_t* __restrict__ Wb,
        const float* __restrict__ bias, void* __restrict__ Cv,
        int N, int K, int M, int Kseg) {
    constexpr int BM = 128, BK = 64;
    // staging: 2 x 128x64 shorts = 32768 B; epilogue transpose: 4x64x68 = 34816 B
    __shared__ __align__(16) unsigned short lds[4 * 64 * 68];
    unsigned short* Als = lds;
    unsigned short* Bls = lds + BM * BK;

    int t = threadIdx.x;
    int lane = t & 63, wid = t >> 6;
    int quad = lane >> 4, l15 = lane & 15;
    int wave_m = wid & 1, wave_n = wid >> 1;
    int bm0 = blockIdx.x * BM;
    int bn0 = blockIdx.y * BM;
    int kbeg = SPLIT ? (int)blockIdx.z * Kseg : 0;
    int kend = SPLIT ? min(kbeg + Kseg, K) : K;

    f32x4 acc[4][4] = {};

    for (int k0 = kbeg; k0 < kend; k0 += BK) {
        // ---- stage A and B tiles (128 rows x 8 chunks of 8 bf16 each) ----
#pragma unroll
        for (int it = 0; it < 4; it++) {
            int idx = t + it * 256;
            int row = idx >> 3, c = idx & 7;
            int sw = ((c ^ (row & 7)) << 3);
            {
                int g = bm0 + row;
                short8 v = {};
                if (g < N) v = *(const short8*)(A + (size_t)g * K + k0 + c * 8);
                *(short8*)&Als[row * BK + sw] = v;
            }
            {
                int g = bn0 + row;
                short8 v = {};
                if (g < M) v = *(const short8*)(Wb + (size_t)g * K + k0 + c * 8);
                *(short8*)&Bls[row * BK + sw] = v;
            }
        }
        __syncthreads();

#pragma unroll
        for (int ks = 0; ks < 2; ks++) {
            short8 af[4], bfr[4];
            int ck = ks * 4 + quad;
            int sw = (ck ^ (l15 & 7)) << 3;
#pragma unroll
            for (int mt = 0; mt < 4; mt++)
                af[mt] = *(const short8*)&Als[(wave_m * 64 + mt * 16 + l15) * BK + sw];
#pragma unroll
            for (int nt = 0; nt < 4; nt++)
                bfr[nt] = *(const short8*)&Bls[(wave_n * 64 + nt * 16 + l15) * BK + sw];
#pragma unroll
            for (int mt = 0; mt < 4; mt++)
#pragma unroll
                for (int nt = 0; nt < 4; nt++)
                    acc[mt][nt] = __builtin_amdgcn_mfma_f32_16x16x32_bf16(
                        af[mt], bfr[nt], acc[mt][nt], 0, 0, 0);
        }
        __syncthreads();
    }

    if (!SPLIT && CBF) {
        // ---- coalesced epilogue: per-wave 64x64 patch through LDS ----
        constexpr int TST = 68;
        unsigned short* tw = lds + wid * 64 * TST;
#pragma unroll
        for (int mt = 0; mt < 4; mt++) {
#pragma unroll
            for (int nt = 0; nt < 4; nt++) {
                int tcol = nt * 16 + l15;
                float bv = BIAS ? bias[bn0 + wave_n * 64 + tcol] : 0.f;
#pragma unroll
                for (int r = 0; r < 4; r++) {
                    float x = acc[mt][nt][r];
                    if (BIAS) x += bv;
                    if (ACT == 1) x = x > 0.f ? x : 0.1f * x;
                    tw[(mt * 16 + quad * 4 + r) * TST + tcol] = f2bf(x);
                }
            }
        }
        __syncthreads();
        bf16_t* C = (bf16_t*)Cv;
        int lrow0 = lane >> 3, lcol = (lane & 7) * 8;
#pragma unroll
        for (int it = 0; it < 8; it++) {
            int lrow = it * 8 + lrow0;
            int row = bm0 + wave_m * 64 + lrow;
            if (row < N) {
                u16x8 v = *(const u16x8*)&tw[lrow * TST + lcol];
                *(u16x8*)&C[(size_t)row * M + bn0 + wave_n * 64 + lcol] = v;
            }
        }
    } else {
        // ---- scalar epilogue (fp32 partials / fp32 out) ----
        float* Pz = SPLIT ? ((float*)Cv + (size_t)blockIdx.z * N * M) : (float*)Cv;
#pragma unroll
        for (int mt = 0; mt < 4; mt++) {
            int rbase = bm0 + wave_m * 64 + mt * 16 + quad * 4;
#pragma unroll
            for (int nt = 0; nt < 4; nt++) {
                int col = bn0 + wave_n * 64 + nt * 16 + l15;
                float bv = (BIAS && !SPLIT) ? bias[col] : 0.f;
#pragma unroll
                for (int r = 0; r < 4; r++) {
                    int row = rbase + r;
                    if (row >= N) continue;
                    float x = acc[mt][nt][r];
                    if (!SPLIT) {
                        if (BIAS) x += bv;
                        if (ACT == 1) x = x > 0.f ? x : 0.1f * x;
                    }
                    Pz[(size_t)row * M + col] = x;
                }
            }
        }
    }
}

// ---------------- split-K reduce + bias + leaky-relu ----------------

template <int S, bool CBF, int ACT>
__global__ __launch_bounds__(256) void k_red(
        const float* __restrict__ part, const float* __restrict__ bias,
        void* __restrict__ out, int GM, int Mmask) {
    int i = (blockIdx.x * 256 + threadIdx.x) * 4;
    if (i >= GM) return;
    float4 s = *(const float4*)&part[i];
#pragma unroll
    for (int z = 1; z < S; z++) {
        float4 p = *(const float4*)&part[(size_t)z * GM + i];
        s.x += p.x; s.y += p.y; s.z += p.z; s.w += p.w;
    }
    float4 b = *(const float4*)&bias[i & Mmask];
    float v[4] = {s.x + b.x, s.y + b.y, s.z + b.z, s.w + b.w};
#pragma unroll
    for (int j = 0; j < 4; j++)
        if (ACT == 1) v[j] = v[j] > 0.f ? v[j] : 0.1f * v[j];
    if (CBF) {
        u16x4 o = {f2bf(v[0]), f2bf(v[1]), f2bf(v[2]), f2bf(v[3])};
        *(u16x4*)((bf16_t*)out + i) = o;
    } else {
        float4 o; o.x = v[0]; o.y = v[1]; o.z = v[2]; o.w = v[3];
        *(float4*)((float*)out + i) = o;
    }
}

// ---------------- fused aggregation, quarter-wave gather --------------------

template <int F, bool BACT>
__global__ __launch_bounds__(256) void k_agg(
        const bf16_t* __restrict__ H, const int* __restrict__ rowptr,
        const int* __restrict__ csr, const float* __restrict__ dis,
        const float* __restrict__ bias, bf16_t* __restrict__ out, int N) {
    constexpr int FPQ = F / 16;   // 8 for F=128, 4 for F=64
    int wv = (int)((blockIdx.x * blockDim.x + threadIdx.x) >> 6);
    int lane = threadIdx.x & 63;
    if (wv >= N) return;
    int quad = lane >> 4, l15 = lane & 15;
    float di = dis[wv];
    int s = rowptr[wv], e = rowptr[wv + 1];

    auto load_row = [&](const bf16_t* p, float (&r)[FPQ]) {
        if constexpr (FPQ == 4) {
            u16x4 v = *(const u16x4*)p;
#pragma unroll
            for (int f = 0; f < 4; f++) r[f] = bf2f(v[f]);
        } else {
            u16x8 v = *(const u16x8*)p;
#pragma unroll
            for (int f = 0; f < 8; f++) r[f] = bf2f(v[f]);
        }
    };

    float acc[FPQ], acc2[FPQ];
#pragma unroll
    for (int f = 0; f < FPQ; f++) { acc[f] = 0.f; acc2[f] = 0.f; }
    if (quad == 0) {
        float r[FPQ];
        load_row(H + (size_t)wv * F + l15 * FPQ, r);
        float sl = di * di;   // self-loop norm = 1/deg
#pragma unroll
        for (int f = 0; f < FPQ; f++) acc[f] = r[f] * sl;
    }

    int p = s + quad;
    for (; p + 4 < e; p += 8) {
        int s0 = csr[p], s1 = csr[p + 4];
        float n0 = dis[s0] * di, n1 = dis[s1] * di;
        float r0[FPQ], r1[FPQ];
        load_row(H + (size_t)s0 * F + l15 * FPQ, r0);
        load_row(H + (size_t)s1 * F + l15 * FPQ, r1);
#pragma unroll
        for (int f = 0; f < FPQ; f++) { acc[f] += r0[f] * n0; acc2[f] += r1[f] * n1; }
    }
    if (p < e) {
        int s0 = csr[p];
        float n0 = dis[s0] * di;
        float r0[FPQ];
        load_row(H + (size_t)s0 * F + l15 * FPQ, r0);
#pragma unroll
        for (int f = 0; f < FPQ; f++) acc[f] += r0[f] * n0;
    }

    // cross-quarter reduction (quad bits are lane bits 4,5)
#pragma unroll
    for (int f = 0; f < FPQ; f++) {
        float v = acc[f] + acc2[f];
        v += __shfl_xor(v, 16, 64);
        v += __shfl_xor(v, 32, 64);
        acc[f] = v;
    }

    if (quad == 0) {
        float o[FPQ];
#pragma unroll
        for (int f = 0; f < FPQ; f++) {
            float v = acc[f];
            if (BACT) {
                v += bias[l15 * FPQ + f];
                v = v > 0.f ? v : 0.1f * v;
            }
            o[f] = v;
        }
        bf16_t* op = out + (size_t)wv * F + l15 * FPQ;
        if constexpr (FPQ == 4) {
            u16x4 w = {f2bf(o[0]), f2bf(o[1]), f2bf(o[2]), f2bf(o[3])};
            *(u16x4*)op = w;
        } else {
            u16x8 w = {f2bf(o[0]), f2bf(o[1]), f2bf(o[2]), f2bf(o[3]),
                       f2bf(o[4]), f2bf(o[5]), f2bf(o[6]), f2bf(o[7])};
            *(u16x8*)op = w;
        }
    }
}

// ---------------- final head: dot(g2_row, L3w) + b, sigmoid ----------------

__global__ void k_head(const float* __restrict__ g2, const float* __restrict__ w,
                       const float* __restrict__ b, float* __restrict__ out, int G) {
    int wv = (int)((blockIdx.x * blockDim.x + threadIdx.x) >> 6);
    int lane = threadIdx.x & 63;
    if (wv >= G) return;
    const float2* gp = (const float2*)(g2 + (size_t)wv * 128);
    const float2* wp = (const float2*)w;
    float2 gv = gp[lane], wl = wp[lane];
    float s = gv.x * wl.x + gv.y * wl.y;
    for (int off = 32; off > 0; off >>= 1) s += __shfl_xor(s, off, 64);
    if (lane == 0) out[wv] = 1.f / (1.f + expf(-(s + b[0])));
}

// ---------------- launch ----------------

extern "C" void kernel_launch(void* const* d_in, const int* in_sizes, int n_in,
                              void* d_out, int out_size, void* d_ws, size_t ws_size,
                              hipStream_t stream) {
    const float* x   = (const float*)d_in[0];
    const int*   ei  = (const int*)d_in[1];
    const float* W1  = (const float*)d_in[2];  const float* b1  = (const float*)d_in[3];
    const float* W2  = (const float*)d_in[4];  const float* b2  = (const float*)d_in[5];
    const float* W3  = (const float*)d_in[6];  const float* b3  = (const float*)d_in[7];
    const float* L1w = (const float*)d_in[8];  const float* L1b = (const float*)d_in[9];
    const float* L2w = (const float*)d_in[10]; const float* L2b = (const float*)d_in[11];
    const float* L3w = (const float*)d_in[12]; const float* L3b = (const float*)d_in[13];
    float* out = (float*)d_out;

    const int C = 40;
    const int N = in_sizes[0] / C;     // 200000
    const int E = in_sizes[1] / 2;     // 1000000
    const int G = N / 40;              // 5000
    const int H1d = 128, H2d = 256, H3d = 128, M1 = 512, M2 = 128;
    const int K1 = 40 * H3d;           // 5120

    // ---- workspace layout ----
    char* wsb = (char*)d_ws;
    size_t off = 0;
    auto alloc = [&](size_t bytes) -> void* {
        void* p = wsb + off;
        off += (bytes + 255) & ~(size_t)255;
        return p;
    };
    int*    flag   = (int*)alloc(4);
    int*    cnt    = (int*)alloc(4 * (size_t)(N + 1));
    int*    rowptr = (int*)alloc(4 * (size_t)(N + 1));
    int*    cursor = (int*)alloc(4 * (size_t)N);
    int*    csr    = (int*)alloc(4 * (size_t)E);
    int*    bsum   = (int*)alloc(4 * 512);
    float*  dis    = (float*)alloc(4 * (size_t)N);
    bf16_t* Hb     = (bf16_t*)alloc(2 * (size_t)N * H2d);   // ping [N,256] bf16 (102.4 MB)
    bf16_t* Xb     = (bf16_t*)alloc(2 * (size_t)N * H2d);   // pong [N,256] bf16 (102.4 MB)
    bf16_t* g1b    = (bf16_t*)alloc(2 * (size_t)G * M1);
    float*  g2     = (float*)alloc(4 * (size_t)G * M2);
    bf16_t* W1b    = (bf16_t*)alloc(2 * (size_t)H1d * 64);
    bf16_t* W2b    = (bf16_t*)alloc(2 * (size_t)H2d * H1d);
    bf16_t* W3b    = (bf16_t*)alloc(2 * (size_t)H3d * H2d);
    bf16_t* L1wb   = (bf16_t*)alloc(2 * (size_t)M1 * K1);
    bf16_t* L2wb   = (bf16_t*)alloc(2 * (size_t)M2 * M1);
    if (off > ws_size) return;   // fail cleanly instead of faulting

    // aliasing (all within dead regions at time of use):
    bf16_t* xb   = Hb;            // [N,64]  pad(x)          — dead after agg1
    bf16_t* A1b  = Xb;            // [N,64]  agg(x)          — dead after GEMM1
    bf16_t* H1   = Hb;            // [N,128] lrelu(A1 W1+b1) — overwrites xb
    bf16_t* A2   = Xb;            // [N,128] agg(H1)         — overwrites A1b
    bf16_t* H2   = Hb;            // [N,256] lrelu(A2 W2+b2) — overwrites H1
    bf16_t* H3p  = Xb;            // [N,128] H2 W3           — overwrites A2
    bf16_t* X3   = Hb;            // [N,128] lrelu(agg(H3p)+b3) — overwrites H2
    float*  part = (float*)Xb;    // split-K partials (61.4 MB) — overwrites H3p

    // ---- weight pre-convert (fp32 -> bf16, K padded) ----
    WcSeg s0 = {W1,  W1b,  H1d, 40,  64,  H1d * 64 / 8};
    WcSeg s1 = {W2,  W2b,  H2d, H1d, H1d, H2d * H1d / 8};
    WcSeg s2 = {W3,  W3b,  H3d, H2d, H2d, H3d * H2d / 8};
    WcSeg s3 = {L1w, L1wb, M1,  K1,  K1,  M1 * K1 / 8};
    WcSeg s4 = {L2w, L2wb, M2,  M1,  M1,  M2 * M1 / 8};
    int wtotal = s0.nchunk + s1.nchunk + s2.nchunk + s3.nchunk + s4.nchunk;
    k_wconv<<<CDIV(wtotal, 256), 256, 0, stream>>>(s0, s1, s2, s3, s4, wtotal);

    // ---- CSR by dst + deg_inv_sqrt ----
    hipMemsetAsync(cnt, 0, sizeof(int) * (size_t)(N + 1), stream);
    k_detect<<<1, 64, 0, stream>>>(ei, flag);
    k_hist<<<CDIV(E, 256), 256, 0, stream>>>(ei, E, flag, cnt, N);
    int total = N + 1;
    int nb = CDIV(total, 1024);
    k_blockred<<<nb, 256, 0, stream>>>(cnt, bsum, total);
    k_scanpartials<<<1, 256, 0, stream>>>(bsum, nb);
    k_scanwrite<<<nb, 256, 0, stream>>>(cnt, bsum, rowptr, cursor, dis, total, N);
    k_fill<<<CDIV(E, 256), 256, 0, stream>>>(ei, E, flag, cursor, csr, N);

    const int NB = CDIV(N, 128);       // 1563
    const int GB = CDIV(G, 128);       // 40
    const int AGG_G = CDIV(N, 4);      // 4 waves/block, one node per wave

    // ---- conv1 (aggregate-first in 40->64-dim) ----
    k_pad<<<CDIV(N * 64, 256), 256, 0, stream>>>(x, xb, N);
    k_agg<64, false><<<AGG_G, 256, 0, stream>>>(xb, rowptr, csr, dis, nullptr, A1b, N);
    gemm_mfma<true, true, 1, false><<<dim3(NB, 1), 256, 0, stream>>>(A1b, W1b, b1, H1, N, 64, H1d, 0);
    // ---- conv2 (aggregate-first in 128-dim) ----
    k_agg<128, false><<<AGG_G, 256, 0, stream>>>(H1, rowptr, csr, dis, nullptr, A2, N);
    gemm_mfma<true, true, 1, false><<<dim3(NB, 2), 256, 0, stream>>>(A2, W2b, b2, H2, N, H1d, H2d, 0);
    // ---- conv3 (transform-first: 256 -> 128, aggregate in 128-dim) ----
    gemm_mfma<true, false, 0, false><<<dim3(NB, 1), 256, 0, stream>>>(H2, W3b, nullptr, H3p, N, H2d, H3d, 0);
    k_agg<128, true><<<AGG_G, 256, 0, stream>>>(H3p, rowptr, csr, dis, b3, X3, N);

    // ---- readout MLP1: split-K S=6 (960 blocks <= 1024 resident), Kseg=896 ----
    gemm_mfma<false, false, 0, true><<<dim3(GB, M1 / 128, 6), 256, 0, stream>>>(X3, L1wb, nullptr, part, G, K1, M1, 896);
    k_red<6, true, 1><<<CDIV(G * M1 / 4, 256), 256, 0, stream>>>(part, L1b, g1b, G * M1, M1 - 1);
    // ---- readout MLP2: split-K S=4, Kseg=128 ----
    gemm_mfma<false, false, 0, true><<<dim3(GB, 1, 4), 256, 0, stream>>>(g1b, L2wb, nullptr, part, G, M1, M2, M1 / 4);
    k_red<4, false, 1><<<CDIV(G * M2 / 4, 256), 256, 0, stream>>>(part, L2b, g2, G * M2, M2 - 1);
    k_head<<<CDIV(G, 4), 256, 0, stream>>>(g2, L3w, L3b, out, G);
}

// Round 10
// 593.376 us; speedup vs baseline: 2.5481x; 1.1390x over previous
//
#include <hip/hip_runtime.h>
#include <cmath>

#define CDIV(a,b) (((a)+(b)-1)/(b))

typedef unsigned short bf16_t;
using short8 = __attribute__((ext_vector_type(8))) short;
using f32x4  = __attribute__((ext_vector_type(4))) float;
using u16x4  = __attribute__((ext_vector_type(4))) unsigned short;
using u16x8  = __attribute__((ext_vector_type(8))) unsigned short;

__device__ __forceinline__ float bf2f(unsigned short b) {
    unsigned u = ((unsigned)b) << 16;
    float f;
    __builtin_memcpy(&f, &u, 4);
    return f;
}
__device__ __forceinline__ unsigned short f2bf(float f) {
    unsigned u;
    __builtin_memcpy(&u, &f, 4);
    u = (u + 0x7FFFu + ((u >> 16) & 1u)) >> 16;
    return (unsigned short)u;
}

// ---------------- edge-index width detection ----------------
__global__ void k_detect(const int* __restrict__ ei, int* __restrict__ flag) {
    int t = threadIdx.x;  // 64 threads
    unsigned v = (unsigned)ei[2 * t + 1];
    unsigned long long m = __ballot(v != 0u);
    if (t == 0) *flag = (m == 0ULL) ? 1 : 0;  // 1 => int64 layout
}

__device__ __forceinline__ int edge_src(const int* ei, int E, int f, int i) {
    return f ? ei[2 * (size_t)i] : ei[i];
}
__device__ __forceinline__ int edge_dst(const int* ei, int E, int f, int i) {
    return f ? ei[2 * ((size_t)E + (size_t)i)] : ei[(size_t)E + (size_t)i];
}

// ---------------- CSR build ----------------

__global__ void k_hist(const int* __restrict__ ei, int E, const int* __restrict__ flag,
                       int* __restrict__ cnt, int N) {
    int i = blockIdx.x * 256 + threadIdx.x;
    if (i >= E) return;
    int d = edge_dst(ei, E, *flag, i);
    if ((unsigned)d < (unsigned)N) atomicAdd(&cnt[d], 1);
}

__global__ void k_blockred(const int* __restrict__ cnt, int* __restrict__ bsum, int total) {
    __shared__ int sd[256];
    int b = blockIdx.x, t = threadIdx.x;
    int base = b * 1024 + t * 4;
    int s = 0;
#pragma unroll
    for (int i = 0; i < 4; i++) { int idx = base + i; if (idx < total) s += cnt[idx]; }
    sd[t] = s; __syncthreads();
    for (int off = 128; off > 0; off >>= 1) { if (t < off) sd[t] += sd[t + off]; __syncthreads(); }
    if (t == 0) bsum[b] = sd[0];
}

__global__ void k_scanpartials(int* bsum, int nb) {
    __shared__ int sd[256];
    int t = threadIdx.x;
    int v = (t < nb) ? bsum[t] : 0;
    sd[t] = v; __syncthreads();
    for (int off = 1; off < 256; off <<= 1) {
        int y = (t >= off) ? sd[t - off] : 0;
        __syncthreads();
        sd[t] += y;
        __syncthreads();
    }
    if (t < nb) bsum[t] = sd[t] - v;   // exclusive
}

__global__ void k_scanwrite(const int* __restrict__ cnt, const int* __restrict__ bsum,
                            int* __restrict__ rowptr, int* __restrict__ cursor,
                            float* __restrict__ dis, int total, int N) {
    __shared__ int sd[256];
    int b = blockIdx.x, t = threadIdx.x;
    int base = b * 1024 + t * 4;
    int v[4]; int s = 0;
#pragma unroll
    for (int i = 0; i < 4; i++) { int idx = base + i; v[i] = (idx < total) ? cnt[idx] : 0; s += v[i]; }
    sd[t] = s; __syncthreads();
    for (int off = 1; off < 256; off <<= 1) {
        int y = (t >= off) ? sd[t - off] : 0;
        __syncthreads();
        sd[t] += y;
        __syncthreads();
    }
    int pre = bsum[b] + sd[t] - s;
#pragma unroll
    for (int i = 0; i < 4; i++) {
        int idx = base + i;
        if (idx < total) {
            rowptr[idx] = pre;
            if (idx < N) { cursor[idx] = pre; dis[idx] = rsqrtf((float)v[i] + 1.0f); }
            pre += v[i];
        }
    }
}

__global__ void k_fill(const int* __restrict__ ei, int E, const int* __restrict__ flag,
                       int* __restrict__ cursor, int* __restrict__ csr, int N) {
    int i = blockIdx.x * 256 + threadIdx.x;
    if (i >= E) return;
    int f = *flag;
    int s = edge_src(ei, E, f, i);
    int d = edge_dst(ei, E, f, i);
    if ((unsigned)d < (unsigned)N && (unsigned)s < (unsigned)N) {
        int p = atomicAdd(&cursor[d], 1);
        csr[p] = s;
    }
}

// ---------------- pad/convert x: [N,40] fp32 -> [N,64] bf16 (zero-padded) ----

__global__ __launch_bounds__(256) void k_pad(const float* __restrict__ x,
                                             bf16_t* __restrict__ xb, int N) {
    int i = blockIdx.x * 256 + threadIdx.x;
    int row = i >> 6, col = i & 63;
    if (row >= N) return;
    float v = (col < 40) ? x[(size_t)row * 40 + col] : 0.f;
    xb[(size_t)row * 64 + col] = f2bf(v);
}

// ---------------- weight pre-convert: fp32 [M,KW] -> bf16 [M,KP] ------------

struct WcSeg { const float* src; bf16_t* dst; int M, KW, KP, nchunk; };

__global__ __launch_bounds__(256) void k_wconv(WcSeg s0, WcSeg s1, WcSeg s2,
                                               WcSeg s3, WcSeg s4, int total) {
    int i = blockIdx.x * 256 + threadIdx.x;
    if (i >= total) return;
    WcSeg s;
    if (i < s0.nchunk) s = s0;
    else if ((i -= s0.nchunk) < s1.nchunk) s = s1;
    else if ((i -= s1.nchunk) < s2.nchunk) s = s2;
    else if ((i -= s2.nchunk) < s3.nchunk) s = s3;
    else { i -= s3.nchunk; s = s4; }
    int cpr = s.KP >> 3;                // chunks per row
    int row = i / cpr, kk = (i % cpr) << 3;
    short8 v = {};
    if (kk < s.KW) {
        const float4* p = (const float4*)(s.src + (size_t)row * s.KW + kk);
        float4 a = p[0], b = p[1];
        v[0] = (short)f2bf(a.x); v[1] = (short)f2bf(a.y);
        v[2] = (short)f2bf(a.z); v[3] = (short)f2bf(a.w);
        v[4] = (short)f2bf(b.x); v[5] = (short)f2bf(b.y);
        v[6] = (short)f2bf(b.z); v[7] = (short)f2bf(b.w);
    }
    *(short8*)(s.dst + (size_t)row * s.KP + kk) = v;
}

// ---------------- MFMA GEMM: C[i][j] = sum_k A[i][k] * Wb[j][k] --------------
// A: [N,K] bf16, Wb: [M,K] bf16. K mult of 64, M of 128. 128x128 tile,
// 4 waves (2x2), mfma_f32_16x16x32_bf16, BK=64, XOR-swizzled LDS.
// Grid: x = M-tile (fastest) so blocks sharing an A-tile dispatch adjacently
// (L2/L3 temporal reuse); y = N-tile; z = K-segment when SPLIT.

template <bool CBF, bool BIAS, int ACT, bool SPLIT>
__global__ __launch_bounds__(256) void gemm_mfma(
        const bf16_t* __restrict__ A, const bf16_t* __restrict__ Wb,
        const float* __restrict__ bias, void* __restrict__ Cv,
        int N, int K, int M, int Kseg) {
    constexpr int BM = 128, BK = 64;
    __shared__ __align__(16) unsigned short lds[4 * 64 * 68];
    unsigned short* Als = lds;
    unsigned short* Bls = lds + BM * BK;

    int t = threadIdx.x;
    int lane = t & 63, wid = t >> 6;
    int quad = lane >> 4, l15 = lane & 15;
    int wave_m = wid & 1, wave_n = wid >> 1;
    int bm0 = blockIdx.y * BM;     // node tile
    int bn0 = blockIdx.x * BM;     // M tile (fastest-varying)
    int kbeg = SPLIT ? (int)blockIdx.z * Kseg : 0;
    int kend = SPLIT ? min(kbeg + Kseg, K) : K;

    f32x4 acc[4][4] = {};

    for (int k0 = kbeg; k0 < kend; k0 += BK) {
#pragma unroll
        for (int it = 0; it < 4; it++) {
            int idx = t + it * 256;
            int row = idx >> 3, c = idx & 7;
            int sw = ((c ^ (row & 7)) << 3);
            {
                int g = bm0 + row;
                short8 v = {};
                if (g < N) v = *(const short8*)(A + (size_t)g * K + k0 + c * 8);
                *(short8*)&Als[row * BK + sw] = v;
            }
            {
                int g = bn0 + row;
                short8 v = {};
                if (g < M) v = *(const short8*)(Wb + (size_t)g * K + k0 + c * 8);
                *(short8*)&Bls[row * BK + sw] = v;
            }
        }
        __syncthreads();

#pragma unroll
        for (int ks = 0; ks < 2; ks++) {
            short8 af[4], bfr[4];
            int ck = ks * 4 + quad;
            int sw = (ck ^ (l15 & 7)) << 3;
#pragma unroll
            for (int mt = 0; mt < 4; mt++)
                af[mt] = *(const short8*)&Als[(wave_m * 64 + mt * 16 + l15) * BK + sw];
#pragma unroll
            for (int nt = 0; nt < 4; nt++)
                bfr[nt] = *(const short8*)&Bls[(wave_n * 64 + nt * 16 + l15) * BK + sw];
#pragma unroll
            for (int mt = 0; mt < 4; mt++)
#pragma unroll
                for (int nt = 0; nt < 4; nt++)
                    acc[mt][nt] = __builtin_amdgcn_mfma_f32_16x16x32_bf16(
                        af[mt], bfr[nt], acc[mt][nt], 0, 0, 0);
        }
        __syncthreads();
    }

    if (!SPLIT && CBF) {
        // ---- coalesced epilogue: per-wave 64x64 patch through LDS ----
        constexpr int TST = 68;
        unsigned short* tw = lds + wid * 64 * TST;
#pragma unroll
        for (int mt = 0; mt < 4; mt++) {
#pragma unroll
            for (int nt = 0; nt < 4; nt++) {
                int tcol = nt * 16 + l15;
                float bv = BIAS ? bias[bn0 + wave_n * 64 + tcol] : 0.f;
#pragma unroll
                for (int r = 0; r < 4; r++) {
                    float x = acc[mt][nt][r];
                    if (BIAS) x += bv;
                    if (ACT == 1) x = x > 0.f ? x : 0.1f * x;
                    tw[(mt * 16 + quad * 4 + r) * TST + tcol] = f2bf(x);
                }
            }
        }
        __syncthreads();
        bf16_t* C = (bf16_t*)Cv;
        int lrow0 = lane >> 3, lcol = (lane & 7) * 8;
#pragma unroll
        for (int it = 0; it < 8; it++) {
            int lrow = it * 8 + lrow0;
            int row = bm0 + wave_m * 64 + lrow;
            if (row < N) {
                u16x8 v = *(const u16x8*)&tw[lrow * TST + lcol];
                *(u16x8*)&C[(size_t)row * M + bn0 + wave_n * 64 + lcol] = v;
            }
        }
    } else {
        float* Pz = SPLIT ? ((float*)Cv + (size_t)blockIdx.z * N * M) : (float*)Cv;
#pragma unroll
        for (int mt = 0; mt < 4; mt++) {
            int rbase = bm0 + wave_m * 64 + mt * 16 + quad * 4;
#pragma unroll
            for (int nt = 0; nt < 4; nt++) {
                int col = bn0 + wave_n * 64 + nt * 16 + l15;
                float bv = (BIAS && !SPLIT) ? bias[col] : 0.f;
#pragma unroll
                for (int r = 0; r < 4; r++) {
                    int row = rbase + r;
                    if (row >= N) continue;
                    float x = acc[mt][nt][r];
                    if (!SPLIT) {
                        if (BIAS) x += bv;
                        if (ACT == 1) x = x > 0.f ? x : 0.1f * x;
                    }
                    Pz[(size_t)row * M + col] = x;
                }
            }
        }
    }
}

// ---------------- split-K reduce + bias + leaky-relu (MLP1) ----------------

template <int S, bool CBF, int ACT>
__global__ __launch_bounds__(256) void k_red(
        const float* __restrict__ part, const float* __restrict__ bias,
        void* __restrict__ out, int GM, int Mmask) {
    int i = (blockIdx.x * 256 + threadIdx.x) * 4;
    if (i >= GM) return;
    float4 s = *(const float4*)&part[i];
#pragma unroll
    for (int z = 1; z < S; z++) {
        float4 p = *(const float4*)&part[(size_t)z * GM + i];
        s.x += p.x; s.y += p.y; s.z += p.z; s.w += p.w;
    }
    float4 b = *(const float4*)&bias[i & Mmask];
    float v[4] = {s.x + b.x, s.y + b.y, s.z + b.z, s.w + b.w};
#pragma unroll
    for (int j = 0; j < 4; j++)
        if (ACT == 1) v[j] = v[j] > 0.f ? v[j] : 0.1f * v[j];
    if (CBF) {
        u16x4 o = {f2bf(v[0]), f2bf(v[1]), f2bf(v[2]), f2bf(v[3])};
        *(u16x4*)((bf16_t*)out + i) = o;
    } else {
        float4 o; o.x = v[0]; o.y = v[1]; o.z = v[2]; o.w = v[3];
        *(float4*)((float*)out + i) = o;
    }
}

// ---------------- fused aggregation, sub-wave-per-node ----------------------
// One SUB-lane group per node (SUB = F/8: 16 lanes for F=128, 8 for F=64);
// each lane holds 8 bf16 (16 B) of its node's row. Each sub-wave walks its
// node's CSR range sequentially (unroll 2) -> 4-8 nodes per wave, no
// cross-lane reduction, no masked lanes.

template <int F, bool BACT>
__global__ __launch_bounds__(256) void k_agg(
        const bf16_t* __restrict__ H, const int* __restrict__ rowptr,
        const int* __restrict__ csr, const float* __restrict__ dis,
        const float* __restrict__ bias, bf16_t* __restrict__ out, int N) {
    constexpr int SUB = F / 8;          // lanes per node
    constexpr int NPW = 64 / SUB;       // nodes per wave
    constexpr int SH  = (SUB == 16) ? 4 : 3;
    int gtid = blockIdx.x * 256 + threadIdx.x;
    int wave = gtid >> 6, lane = gtid & 63;
    int sub = lane >> SH, sl = lane & (SUB - 1);
    int node = wave * NPW + sub;
    if (node >= N) return;
    float di = dis[node];
    int s = rowptr[node], e = rowptr[node + 1];

    auto load_row = [&](const bf16_t* p, float (&r)[8]) {
        u16x8 v = *(const u16x8*)p;
#pragma unroll
        for (int f = 0; f < 8; f++) r[f] = bf2f(v[f]);
    };

    float acc[8], acc2[8];
    {
        float r[8];
        load_row(H + (size_t)node * F + sl * 8, r);
        float sln = di * di;   // self-loop norm = 1/deg
#pragma unroll
        for (int f = 0; f < 8; f++) { acc[f] = r[f] * sln; acc2[f] = 0.f; }
    }
    int p = s;
    for (; p + 2 <= e; p += 2) {
        int s0 = csr[p], s1 = csr[p + 1];
        float n0 = dis[s0] * di, n1 = dis[s1] * di;
        float r0[8], r1[8];
        load_row(H + (size_t)s0 * F + sl * 8, r0);
        load_row(H + (size_t)s1 * F + sl * 8, r1);
#pragma unroll
        for (int f = 0; f < 8; f++) { acc[f] += r0[f] * n0; acc2[f] += r1[f] * n1; }
    }
    if (p < e) {
        int s0 = csr[p];
        float n0 = dis[s0] * di;
        float r0[8];
        load_row(H + (size_t)s0 * F + sl * 8, r0);
#pragma unroll
        for (int f = 0; f < 8; f++) acc[f] += r0[f] * n0;
    }

    float o[8];
#pragma unroll
    for (int f = 0; f < 8; f++) {
        float v = acc[f] + acc2[f];
        if (BACT) {
            v += bias[sl * 8 + f];
            v = v > 0.f ? v : 0.1f * v;
        }
        o[f] = v;
    }
    u16x8 w = {f2bf(o[0]), f2bf(o[1]), f2bf(o[2]), f2bf(o[3]),
               f2bf(o[4]), f2bf(o[5]), f2bf(o[6]), f2bf(o[7])};
    *(u16x8*)(out + (size_t)node * F + sl * 8) = w;
}

// ---------------- fused MLP2-reduce + bias + lrelu + head ------------------
// part: [4][G*128] fp32 split-K partials of g @ L2w^T. One wave per graph:
// reduce 4 slices, +L2b, lrelu, dot with L3w, +L3b, sigmoid.

__global__ __launch_bounds__(256) void k_head2(
        const float* __restrict__ part, const float* __restrict__ L2b,
        const float* __restrict__ L3w, const float* __restrict__ L3b,
        float* __restrict__ out, int G) {
    int wv = (int)((blockIdx.x * blockDim.x + threadIdx.x) >> 6);
    int lane = threadIdx.x & 63;
    if (wv >= G) return;
    size_t base = (size_t)wv * 128 + lane * 2;
    size_t GM = (size_t)G * 128;
    float2 s = *(const float2*)&part[base];
#pragma unroll
    for (int z = 1; z < 4; z++) {
        float2 p = *(const float2*)&part[z * GM + base];
        s.x += p.x; s.y += p.y;
    }
    float2 b = *(const float2*)&L2b[lane * 2];
    float vx = s.x + b.x, vy = s.y + b.y;
    vx = vx > 0.f ? vx : 0.1f * vx;
    vy = vy > 0.f ? vy : 0.1f * vy;
    float2 wl = *(const float2*)&L3w[lane * 2];
    float d = vx * wl.x + vy * wl.y;
    for (int off = 32; off > 0; off >>= 1) d += __shfl_xor(d, off, 64);
    if (lane == 0) out[wv] = 1.f / (1.f + expf(-(d + L3b[0])));
}

// ---------------- launch ----------------

extern "C" void kernel_launch(void* const* d_in, const int* in_sizes, int n_in,
                              void* d_out, int out_size, void* d_ws, size_t ws_size,
                              hipStream_t stream) {
    const float* x   = (const float*)d_in[0];
    const int*   ei  = (const int*)d_in[1];
    const float* W1  = (const float*)d_in[2];  const float* b1  = (const float*)d_in[3];
    const float* W2  = (const float*)d_in[4];  const float* b2  = (const float*)d_in[5];
    const float* W3  = (const float*)d_in[6];  const float* b3  = (const float*)d_in[7];
    const float* L1w = (const float*)d_in[8];  const float* L1b = (const float*)d_in[9];
    const float* L2w = (const float*)d_in[10]; const float* L2b = (const float*)d_in[11];
    const float* L3w = (const float*)d_in[12]; const float* L3b = (const float*)d_in[13];
    float* out = (float*)d_out;

    const int C = 40;
    const int N = in_sizes[0] / C;     // 200000
    const int E = in_sizes[1] / 2;     // 1000000
    const int G = N / 40;              // 5000
    const int H1d = 128, H2d = 256, H3d = 128, M1 = 512, M2 = 128;
    const int K1 = 40 * H3d;           // 5120

    // ---- workspace layout ----
    char* wsb = (char*)d_ws;
    size_t off = 0;
    auto alloc = [&](size_t bytes) -> void* {
        void* p = wsb + off;
        off += (bytes + 255) & ~(size_t)255;
        return p;
    };
    int*    flag   = (int*)alloc(4);
    int*    cnt    = (int*)alloc(4 * (size_t)(N + 1));
    int*    rowptr = (int*)alloc(4 * (size_t)(N + 1));
    int*    cursor = (int*)alloc(4 * (size_t)N);
    int*    csr    = (int*)alloc(4 * (size_t)E);
    int*    bsum   = (int*)alloc(4 * 512);
    float*  dis    = (float*)alloc(4 * (size_t)N);
    bf16_t* Hb     = (bf16_t*)alloc(2 * (size_t)N * H2d);   // ping [N,256] bf16 (102.4 MB)
    bf16_t* Xb     = (bf16_t*)alloc(2 * (size_t)N * H2d);   // pong [N,256] bf16 (102.4 MB)
    bf16_t* g1b    = (bf16_t*)alloc(2 * (size_t)G * M1);
    bf16_t* W1b    = (bf16_t*)alloc(2 * (size_t)H1d * 64);
    bf16_t* W2b    = (bf16_t*)alloc(2 * (size_t)H2d * H1d);
    bf16_t* W3b    = (bf16_t*)alloc(2 * (size_t)H3d * H2d);
    bf16_t* L1wb   = (bf16_t*)alloc(2 * (size_t)M1 * K1);
    bf16_t* L2wb   = (bf16_t*)alloc(2 * (size_t)M2 * M1);
    if (off > ws_size) return;   // fail cleanly instead of faulting

    // aliasing (all within dead regions at time of use):
    bf16_t* xb   = Hb;            // [N,64]  pad(x)          — dead after agg1
    bf16_t* A1b  = Xb;            // [N,64]  agg(x)          — dead after GEMM1
    bf16_t* H1   = Hb;            // [N,128] lrelu(A1 W1+b1) — overwrites xb
    bf16_t* A2   = Xb;            // [N,128] agg(H1)         — overwrites A1b
    bf16_t* H2   = Hb;            // [N,256] lrelu(A2 W2+b2) — overwrites H1
    bf16_t* H3p  = Xb;            // [N,128] H2 W3           — overwrites A2
    bf16_t* X3   = Hb;            // [N,128] lrelu(agg(H3p)+b3) — overwrites H2
    float*  part = (float*)Xb;    // split-K partials (61.4 MB) — overwrites H3p

    // ---- weight pre-convert (fp32 -> bf16, K padded) ----
    WcSeg s0 = {W1,  W1b,  H1d, 40,  64,  H1d * 64 / 8};
    WcSeg s1 = {W2,  W2b,  H2d, H1d, H1d, H2d * H1d / 8};
    WcSeg s2 = {W3,  W3b,  H3d, H2d, H2d, H3d * H2d / 8};
    WcSeg s3 = {L1w, L1wb, M1,  K1,  K1,  M1 * K1 / 8};
    WcSeg s4 = {L2w, L2wb, M2,  M1,  M1,  M2 * M1 / 8};
    int wtotal = s0.nchunk + s1.nchunk + s2.nchunk + s3.nchunk + s4.nchunk;
    k_wconv<<<CDIV(wtotal, 256), 256, 0, stream>>>(s0, s1, s2, s3, s4, wtotal);

    // ---- CSR by dst + deg_inv_sqrt ----
    hipMemsetAsync(cnt, 0, sizeof(int) * (size_t)(N + 1), stream);
    k_detect<<<1, 64, 0, stream>>>(ei, flag);
    k_hist<<<CDIV(E, 256), 256, 0, stream>>>(ei, E, flag, cnt, N);
    int total = N + 1;
    int nb = CDIV(total, 1024);
    k_blockred<<<nb, 256, 0, stream>>>(cnt, bsum, total);
    k_scanpartials<<<1, 256, 0, stream>>>(bsum, nb);
    k_scanwrite<<<nb, 256, 0, stream>>>(cnt, bsum, rowptr, cursor, dis, total, N);
    k_fill<<<CDIV(E, 256), 256, 0, stream>>>(ei, E, flag, cursor, csr, N);

    const int NB = CDIV(N, 128);       // 1563
    const int GB = CDIV(G, 128);       // 40

    // ---- conv1 (aggregate-first in 40->64-dim) ----
    k_pad<<<CDIV(N * 64, 256), 256, 0, stream>>>(x, xb, N);
    k_agg<64, false><<<CDIV(N, 32), 256, 0, stream>>>(xb, rowptr, csr, dis, nullptr, A1b, N);
    gemm_mfma<true, true, 1, false><<<dim3(1, NB), 256, 0, stream>>>(A1b, W1b, b1, H1, N, 64, H1d, 0);
    // ---- conv2 (aggregate-first in 128-dim) ----
    k_agg<128, false><<<CDIV(N, 16), 256, 0, stream>>>(H1, rowptr, csr, dis, nullptr, A2, N);
    gemm_mfma<true, true, 1, false><<<dim3(2, NB), 256, 0, stream>>>(A2, W2b, b2, H2, N, H1d, H2d, 0);
    // ---- conv3 (transform-first: 256 -> 128, aggregate in 128-dim) ----
    gemm_mfma<true, false, 0, false><<<dim3(1, NB), 256, 0, stream>>>(H2, W3b, nullptr, H3p, N, H2d, H3d, 0);
    k_agg<128, true><<<CDIV(N, 16), 256, 0, stream>>>(H3p, rowptr, csr, dis, b3, X3, N);

    // ---- readout MLP1: split-K S=6 (960 blocks), Kseg=896 ----
    gemm_mfma<false, false, 0, true><<<dim3(M1 / 128, GB, 6), 256, 0, stream>>>(X3, L1wb, nullptr, part, G, K1, M1, 896);
    k_red<6, true, 1><<<CDIV(G * M1 / 4, 256), 256, 0, stream>>>(part, L1b, g1b, G * M1, M1 - 1);
    // ---- readout MLP2: split-K S=4 + fused reduce/head ----
    gemm_mfma<false, false, 0, true><<<dim3(1, GB, 4), 256, 0, stream>>>(g1b, L2wb, nullptr, part, G, M1, M2, M1 / 4);
    k_head2<<<CDIV(G, 4), 256, 0, stream>>>(part, L2b, L3w, L3b, out, G);
}

// Round 11
// 588.613 us; speedup vs baseline: 2.5688x; 1.0081x over previous
//
#include <hip/hip_runtime.h>
#include <cmath>

#define CDIV(a,b) (((a)+(b)-1)/(b))

typedef unsigned short bf16_t;
using short8 = __attribute__((ext_vector_type(8))) short;
using f32x4  = __attribute__((ext_vector_type(4))) float;
using u16x4  = __attribute__((ext_vector_type(4))) unsigned short;
using u16x8  = __attribute__((ext_vector_type(8))) unsigned short;

__device__ __forceinline__ float bf2f(unsigned short b) {
    unsigned u = ((unsigned)b) << 16;
    float f;
    __builtin_memcpy(&f, &u, 4);
    return f;
}
__device__ __forceinline__ unsigned short f2bf(float f) {
    unsigned u;
    __builtin_memcpy(&u, &f, 4);
    u = (u + 0x7FFFu + ((u >> 16) & 1u)) >> 16;
    return (unsigned short)u;
}

// ---------------- edge-index width detection ----------------
__global__ void k_detect(const int* __restrict__ ei, int* __restrict__ flag) {
    int t = threadIdx.x;  // 64 threads
    unsigned v = (unsigned)ei[2 * t + 1];
    unsigned long long m = __ballot(v != 0u);
    if (t == 0) *flag = (m == 0ULL) ? 1 : 0;  // 1 => int64 layout
}

__device__ __forceinline__ int edge_src(const int* ei, int E, int f, int i) {
    return f ? ei[2 * (size_t)i] : ei[i];
}
__device__ __forceinline__ int edge_dst(const int* ei, int E, int f, int i) {
    return f ? ei[2 * ((size_t)E + (size_t)i)] : ei[(size_t)E + (size_t)i];
}

// ---------------- CSR build (8x XCD-privatized counting sort) ----------------

__global__ void k_hist(const int* __restrict__ ei, int E, const int* __restrict__ flag,
                       int* __restrict__ cnt8, int N) {
    int i = blockIdx.x * 256 + threadIdx.x;
    if (i >= E) return;
    int d = edge_dst(ei, E, *flag, i);
    if ((unsigned)d < (unsigned)N)
        atomicAdd(&cnt8[(blockIdx.x & 7) * N + d], 1);
}

// block-sum over 1024 node-ids (summing the 8 histogram copies)
__global__ void k_blockred(const int* __restrict__ cnt8, int* __restrict__ bsum, int N) {
    __shared__ int sd[256];
    int b = blockIdx.x, t = threadIdx.x;
    int base = b * 1024 + t * 4;
    int s = 0;
#pragma unroll
    for (int i = 0; i < 4; i++) {
        int idx = base + i;
        if (idx < N)
#pragma unroll
            for (int r = 0; r < 8; r++) s += cnt8[r * N + idx];
    }
    sd[t] = s; __syncthreads();
    for (int off = 128; off > 0; off >>= 1) { if (t < off) sd[t] += sd[t + off]; __syncthreads(); }
    if (t == 0) bsum[b] = sd[0];
}

__global__ void k_scanpartials(int* bsum, int nb) {
    __shared__ int sd[256];
    int t = threadIdx.x;
    int v = (t < nb) ? bsum[t] : 0;
    sd[t] = v; __syncthreads();
    for (int off = 1; off < 256; off <<= 1) {
        int y = (t >= off) ? sd[t - off] : 0;
        __syncthreads();
        sd[t] += y;
        __syncthreads();
    }
    if (t < nb) bsum[t] = sd[t] - v;   // exclusive
}

// writes rowptr, deg_inv_sqrt, and the 8 per-copy cursor bases
__global__ void k_scanwrite(const int* __restrict__ cnt8, const int* __restrict__ bsum,
                            int* __restrict__ rowptr, int* __restrict__ cur8,
                            float* __restrict__ dis, int N) {
    __shared__ int sd[256];
    int b = blockIdx.x, t = threadIdx.x;
    int base = b * 1024 + t * 4;
    int c[4][8]; int tot[4]; int s = 0;
#pragma unroll
    for (int i = 0; i < 4; i++) {
        int idx = base + i;
        tot[i] = 0;
        if (idx < N) {
#pragma unroll
            for (int r = 0; r < 8; r++) { c[i][r] = cnt8[r * N + idx]; tot[i] += c[i][r]; }
        }
        s += tot[i];
    }
    sd[t] = s; __syncthreads();
    for (int off = 1; off < 256; off <<= 1) {
        int y = (t >= off) ? sd[t - off] : 0;
        __syncthreads();
        sd[t] += y;
        __syncthreads();
    }
    int pre = bsum[b] + sd[t] - s;
#pragma unroll
    for (int i = 0; i < 4; i++) {
        int idx = base + i;
        if (idx < N) {
            rowptr[idx] = pre;
            dis[idx] = rsqrtf((float)tot[i] + 1.0f);
            int run = pre;
#pragma unroll
            for (int r = 0; r < 8; r++) { cur8[r * N + idx] = run; run += c[i][r]; }
            pre += tot[i];
        } else if (idx == N) {
            rowptr[N] = pre;
        }
    }
}

__global__ void k_fill(const int* __restrict__ ei, int E, const int* __restrict__ flag,
                       int* __restrict__ cur8, int* __restrict__ csr, int N) {
    int i = blockIdx.x * 256 + threadIdx.x;
    if (i >= E) return;
    int f = *flag;
    int s = edge_src(ei, E, f, i);
    int d = edge_dst(ei, E, f, i);
    if ((unsigned)d < (unsigned)N && (unsigned)s < (unsigned)N) {
        int p = atomicAdd(&cur8[(blockIdx.x & 7) * N + d], 1);
        csr[p] = s;
    }
}

// ---------------- pad/convert x: [N,40] fp32 -> [N,64] bf16 (zero-padded) ----

__global__ __launch_bounds__(256) void k_pad(const float* __restrict__ x,
                                             bf16_t* __restrict__ xb, int N) {
    int i = blockIdx.x * 256 + threadIdx.x;
    int row = i >> 6, col = i & 63;
    if (row >= N) return;
    float v = (col < 40) ? x[(size_t)row * 40 + col] : 0.f;
    xb[(size_t)row * 64 + col] = f2bf(v);
}

// ---------------- weight pre-convert: fp32 [M,KW] -> bf16 [M,KP] ------------

struct WcSeg { const float* src; bf16_t* dst; int M, KW, KP, nchunk; };

__global__ __launch_bounds__(256) void k_wconv(WcSeg s0, WcSeg s1, WcSeg s2,
                                               WcSeg s3, WcSeg s4, int total) {
    int i = blockIdx.x * 256 + threadIdx.x;
    if (i >= total) return;
    WcSeg s;
    if (i < s0.nchunk) s = s0;
    else if ((i -= s0.nchunk) < s1.nchunk) s = s1;
    else if ((i -= s1.nchunk) < s2.nchunk) s = s2;
    else if ((i -= s2.nchunk) < s3.nchunk) s = s3;
    else { i -= s3.nchunk; s = s4; }
    int cpr = s.KP >> 3;                // chunks per row
    int row = i / cpr, kk = (i % cpr) << 3;
    short8 v = {};
    if (kk < s.KW) {
        const float4* p = (const float4*)(s.src + (size_t)row * s.KW + kk);
        float4 a = p[0], b = p[1];
        v[0] = (short)f2bf(a.x); v[1] = (short)f2bf(a.y);
        v[2] = (short)f2bf(a.z); v[3] = (short)f2bf(a.w);
        v[4] = (short)f2bf(b.x); v[5] = (short)f2bf(b.y);
        v[6] = (short)f2bf(b.z); v[7] = (short)f2bf(b.w);
    }
    *(short8*)(s.dst + (size_t)row * s.KP + kk) = v;
}

// ---------------- MFMA GEMM: C[i][j] = sum_k A[i][k] * Wb[j][k] --------------
// A: [N,K] bf16, Wb: [M,K] bf16. K mult of 64, M of 128. 128x128 tile,
// 4 waves (2x2), mfma_f32_16x16x32_bf16, BK=64, XOR-swizzled LDS.
// Grid: x = M-tile (fastest), y = N-tile, z = K-segment when SPLIT.

template <bool CBF, bool BIAS, int ACT, bool SPLIT>
__global__ __launch_bounds__(256) void gemm_mfma(
        const bf16_t* __restrict__ A, const bf16_t* __restrict__ Wb,
        const float* __restrict__ bias, void* __restrict__ Cv,
        int N, int K, int M, int Kseg) {
    constexpr int BM = 128, BK = 64;
    __shared__ __align__(16) unsigned short lds[4 * 64 * 68];
    unsigned short* Als = lds;
    unsigned short* Bls = lds + BM * BK;

    int t = threadIdx.x;
    int lane = t & 63, wid = t >> 6;
    int quad = lane >> 4, l15 = lane & 15;
    int wave_m = wid & 1, wave_n = wid >> 1;
    int bm0 = blockIdx.y * BM;     // node tile
    int bn0 = blockIdx.x * BM;     // M tile (fastest-varying)
    int kbeg = SPLIT ? (int)blockIdx.z * Kseg : 0;
    int kend = SPLIT ? min(kbeg + Kseg, K) : K;

    f32x4 acc[4][4] = {};

    for (int k0 = kbeg; k0 < kend; k0 += BK) {
#pragma unroll
        for (int it = 0; it < 4; it++) {
            int idx = t + it * 256;
            int row = idx >> 3, c = idx & 7;
            int sw = ((c ^ (row & 7)) << 3);
            {
                int g = bm0 + row;
                short8 v = {};
                if (g < N) v = *(const short8*)(A + (size_t)g * K + k0 + c * 8);
                *(short8*)&Als[row * BK + sw] = v;
            }
            {
                int g = bn0 + row;
                short8 v = {};
                if (g < M) v = *(const short8*)(Wb + (size_t)g * K + k0 + c * 8);
                *(short8*)&Bls[row * BK + sw] = v;
            }
        }
        __syncthreads();

#pragma unroll
        for (int ks = 0; ks < 2; ks++) {
            short8 af[4], bfr[4];
            int ck = ks * 4 + quad;
            int sw = (ck ^ (l15 & 7)) << 3;
#pragma unroll
            for (int mt = 0; mt < 4; mt++)
                af[mt] = *(const short8*)&Als[(wave_m * 64 + mt * 16 + l15) * BK + sw];
#pragma unroll
            for (int nt = 0; nt < 4; nt++)
                bfr[nt] = *(const short8*)&Bls[(wave_n * 64 + nt * 16 + l15) * BK + sw];
#pragma unroll
            for (int mt = 0; mt < 4; mt++)
#pragma unroll
                for (int nt = 0; nt < 4; nt++)
                    acc[mt][nt] = __builtin_amdgcn_mfma_f32_16x16x32_bf16(
                        af[mt], bfr[nt], acc[mt][nt], 0, 0, 0);
        }
        __syncthreads();
    }

    if (!SPLIT && CBF) {
        // ---- coalesced epilogue: per-wave 64x64 patch through LDS ----
        constexpr int TST = 68;
        unsigned short* tw = lds + wid * 64 * TST;
#pragma unroll
        for (int mt = 0; mt < 4; mt++) {
#pragma unroll
            for (int nt = 0; nt < 4; nt++) {
                int tcol = nt * 16 + l15;
                float bv = BIAS ? bias[bn0 + wave_n * 64 + tcol] : 0.f;
#pragma unroll
                for (int r = 0; r < 4; r++) {
                    float x = acc[mt][nt][r];
                    if (BIAS) x += bv;
                    if (ACT == 1) x = x > 0.f ? x : 0.1f * x;
                    tw[(mt * 16 + quad * 4 + r) * TST + tcol] = f2bf(x);
                }
            }
        }
        __syncthreads();
        bf16_t* C = (bf16_t*)Cv;
        int lrow0 = lane >> 3, lcol = (lane & 7) * 8;
#pragma unroll
        for (int it = 0; it < 8; it++) {
            int lrow = it * 8 + lrow0;
            int row = bm0 + wave_m * 64 + lrow;
            if (row < N) {
                u16x8 v = *(const u16x8*)&tw[lrow * TST + lcol];
                *(u16x8*)&C[(size_t)row * M + bn0 + wave_n * 64 + lcol] = v;
            }
        }
    } else {
        float* Pz = SPLIT ? ((float*)Cv + (size_t)blockIdx.z * N * M) : (float*)Cv;
#pragma unroll
        for (int mt = 0; mt < 4; mt++) {
            int rbase = bm0 + wave_m * 64 + mt * 16 + quad * 4;
#pragma unroll
            for (int nt = 0; nt < 4; nt++) {
                int col = bn0 + wave_n * 64 + nt * 16 + l15;
                float bv = (BIAS && !SPLIT) ? bias[col] : 0.f;
#pragma unroll
                for (int r = 0; r < 4; r++) {
                    int row = rbase + r;
                    if (row >= N) continue;
                    float x = acc[mt][nt][r];
                    if (!SPLIT) {
                        if (BIAS) x += bv;
                        if (ACT == 1) x = x > 0.f ? x : 0.1f * x;
                    }
                    Pz[(size_t)row * M + col] = x;
                }
            }
        }
    }
}

// ---------------- split-K reduce + bias + leaky-relu (MLP1) ----------------

template <int S, bool CBF, int ACT>
__global__ __launch_bounds__(256) void k_red(
        const float* __restrict__ part, const float* __restrict__ bias,
        void* __restrict__ out, int GM, int Mmask) {
    int i = (blockIdx.x * 256 + threadIdx.x) * 4;
    if (i >= GM) return;
    float4 s = *(const float4*)&part[i];
#pragma unroll
    for (int z = 1; z < S; z++) {
        float4 p = *(const float4*)&part[(size_t)z * GM + i];
        s.x += p.x; s.y += p.y; s.z += p.z; s.w += p.w;
    }
    float4 b = *(const float4*)&bias[i & Mmask];
    float v[4] = {s.x + b.x, s.y + b.y, s.z + b.z, s.w + b.w};
#pragma unroll
    for (int j = 0; j < 4; j++)
        if (ACT == 1) v[j] = v[j] > 0.f ? v[j] : 0.1f * v[j];
    if (CBF) {
        u16x4 o = {f2bf(v[0]), f2bf(v[1]), f2bf(v[2]), f2bf(v[3])};
        *(u16x4*)((bf16_t*)out + i) = o;
    } else {
        float4 o; o.x = v[0]; o.y = v[1]; o.z = v[2]; o.w = v[3];
        *(float4*)((float*)out + i) = o;
    }
}

// ---------------- fused aggregation, sub-wave-per-node ----------------------

template <int F, bool BACT>
__global__ __launch_bounds__(256) void k_agg(
        const bf16_t* __restrict__ H, const int* __restrict__ rowptr,
        const int* __restrict__ csr, const float* __restrict__ dis,
        const float* __restrict__ bias, bf16_t* __restrict__ out, int N) {
    constexpr int SUB = F / 8;          // lanes per node
    constexpr int NPW = 64 / SUB;       // nodes per wave
    constexpr int SH  = (SUB == 16) ? 4 : 3;
    int gtid = blockIdx.x * 256 + threadIdx.x;
    int wave = gtid >> 6, lane = gtid & 63;
    int sub = lane >> SH, sl = lane & (SUB - 1);
    int node = wave * NPW + sub;
    if (node >= N) return;
    float di = dis[node];
    int s = rowptr[node], e = rowptr[node + 1];

    auto load_row = [&](const bf16_t* p, float (&r)[8]) {
        u16x8 v = *(const u16x8*)p;
#pragma unroll
        for (int f = 0; f < 8; f++) r[f] = bf2f(v[f]);
    };

    float acc[8], acc2[8];
    {
        float r[8];
        load_row(H + (size_t)node * F + sl * 8, r);
        float sln = di * di;   // self-loop norm = 1/deg
#pragma unroll
        for (int f = 0; f < 8; f++) { acc[f] = r[f] * sln; acc2[f] = 0.f; }
    }
    int p = s;
    for (; p + 2 <= e; p += 2) {
        int s0 = csr[p], s1 = csr[p + 1];
        float n0 = dis[s0] * di, n1 = dis[s1] * di;
        float r0[8], r1[8];
        load_row(H + (size_t)s0 * F + sl * 8, r0);
        load_row(H + (size_t)s1 * F + sl * 8, r1);
#pragma unroll
        for (int f = 0; f < 8; f++) { acc[f] += r0[f] * n0; acc2[f] += r1[f] * n1; }
    }
    if (p < e) {
        int s0 = csr[p];
        float n0 = dis[s0] * di;
        float r0[8];
        load_row(H + (size_t)s0 * F + sl * 8, r0);
#pragma unroll
        for (int f = 0; f < 8; f++) acc[f] += r0[f] * n0;
    }

    float o[8];
#pragma unroll
    for (int f = 0; f < 8; f++) {
        float v = acc[f] + acc2[f];
        if (BACT) {
            v += bias[sl * 8 + f];
            v = v > 0.f ? v : 0.1f * v;
        }
        o[f] = v;
    }
    u16x8 w = {f2bf(o[0]), f2bf(o[1]), f2bf(o[2]), f2bf(o[3]),
               f2bf(o[4]), f2bf(o[5]), f2bf(o[6]), f2bf(o[7])};
    *(u16x8*)(out + (size_t)node * F + sl * 8) = w;
}

// ---------------- fused MLP2-reduce + bias + lrelu + head ------------------

__global__ __launch_bounds__(256) void k_head2(
        const float* __restrict__ part, const float* __restrict__ L2b,
        const float* __restrict__ L3w, const float* __restrict__ L3b,
        float* __restrict__ out, int G) {
    int wv = (int)((blockIdx.x * blockDim.x + threadIdx.x) >> 6);
    int lane = threadIdx.x & 63;
    if (wv >= G) return;
    size_t base = (size_t)wv * 128 + lane * 2;
    size_t GM = (size_t)G * 128;
    float2 s = *(const float2*)&part[base];
#pragma unroll
    for (int z = 1; z < 4; z++) {
        float2 p = *(const float2*)&part[z * GM + base];
        s.x += p.x; s.y += p.y;
    }
    float2 b = *(const float2*)&L2b[lane * 2];
    float vx = s.x + b.x, vy = s.y + b.y;
    vx = vx > 0.f ? vx : 0.1f * vx;
    vy = vy > 0.f ? vy : 0.1f * vy;
    float2 wl = *(const float2*)&L3w[lane * 2];
    float d = vx * wl.x + vy * wl.y;
    for (int off = 32; off > 0; off >>= 1) d += __shfl_xor(d, off, 64);
    if (lane == 0) out[wv] = 1.f / (1.f + expf(-(d + L3b[0])));
}

// ---------------- launch ----------------

extern "C" void kernel_launch(void* const* d_in, const int* in_sizes, int n_in,
                              void* d_out, int out_size, void* d_ws, size_t ws_size,
                              hipStream_t stream) {
    const float* x   = (const float*)d_in[0];
    const int*   ei  = (const int*)d_in[1];
    const float* W1  = (const float*)d_in[2];  const float* b1  = (const float*)d_in[3];
    const float* W2  = (const float*)d_in[4];  const float* b2  = (const float*)d_in[5];
    const float* W3  = (const float*)d_in[6];  const float* b3  = (const float*)d_in[7];
    const float* L1w = (const float*)d_in[8];  const float* L1b = (const float*)d_in[9];
    const float* L2w = (const float*)d_in[10]; const float* L2b = (const float*)d_in[11];
    const float* L3w = (const float*)d_in[12]; const float* L3b = (const float*)d_in[13];
    float* out = (float*)d_out;

    const int C = 40;
    const int N = in_sizes[0] / C;     // 200000
    const int E = in_sizes[1] / 2;     // 1000000
    const int G = N / 40;              // 5000
    const int H1d = 128, H2d = 256, H3d = 128, M1 = 512, M2 = 128;
    const int K1 = 40 * H3d;           // 5120

    // ---- workspace layout ----
    char* wsb = (char*)d_ws;
    size_t off = 0;
    auto alloc = [&](size_t bytes) -> void* {
        void* p = wsb + off;
        off += (bytes + 255) & ~(size_t)255;
        return p;
    };
    int*    flag   = (int*)alloc(4);
    int*    cnt8   = (int*)alloc(4 * 8 * (size_t)N);
    int*    rowptr = (int*)alloc(4 * (size_t)(N + 1));
    int*    cur8   = (int*)alloc(4 * 8 * (size_t)N);
    int*    csr    = (int*)alloc(4 * (size_t)E);
    int*    bsum   = (int*)alloc(4 * 512);
    float*  dis    = (float*)alloc(4 * (size_t)N);
    bf16_t* Hb     = (bf16_t*)alloc(2 * (size_t)N * H2d);   // ping [N,256] bf16 (102.4 MB)
    bf16_t* Xb     = (bf16_t*)alloc(2 * (size_t)N * H2d);   // pong [N,256] bf16 (102.4 MB)
    bf16_t* g1b    = (bf16_t*)alloc(2 * (size_t)G * M1);
    bf16_t* W1b    = (bf16_t*)alloc(2 * (size_t)H1d * 64);
    bf16_t* W2b    = (bf16_t*)alloc(2 * (size_t)H2d * H1d);
    bf16_t* W3b    = (bf16_t*)alloc(2 * (size_t)H3d * H2d);
    bf16_t* L1wb   = (bf16_t*)alloc(2 * (size_t)M1 * K1);
    bf16_t* L2wb   = (bf16_t*)alloc(2 * (size_t)M2 * M1);
    if (off > ws_size) return;   // fail cleanly instead of faulting

    // aliasing (all within dead regions at time of use):
    bf16_t* xb   = Hb;            // [N,64]  pad(x)          — dead after agg1
    bf16_t* A1b  = Xb;            // [N,64]  agg(x)          — dead after GEMM1
    bf16_t* H1   = Hb;            // [N,128] lrelu(A1 W1+b1) — overwrites xb
    bf16_t* A2   = Xb;            // [N,128] agg(H1)         — overwrites A1b
    bf16_t* H2   = Hb;            // [N,256] lrelu(A2 W2+b2) — overwrites H1
    bf16_t* H3p  = Xb;            // [N,128] H2 W3           — overwrites A2
    bf16_t* X3   = Hb;            // [N,128] lrelu(agg(H3p)+b3) — overwrites H2
    float*  part = (float*)Xb;    // split-K partials (61.4 MB) — overwrites H3p

    // ---- weight pre-convert (fp32 -> bf16, K padded) ----
    WcSeg s0 = {W1,  W1b,  H1d, 40,  64,  H1d * 64 / 8};
    WcSeg s1 = {W2,  W2b,  H2d, H1d, H1d, H2d * H1d / 8};
    WcSeg s2 = {W3,  W3b,  H3d, H2d, H2d, H3d * H2d / 8};
    WcSeg s3 = {L1w, L1wb, M1,  K1,  K1,  M1 * K1 / 8};
    WcSeg s4 = {L2w, L2wb, M2,  M1,  M1,  M2 * M1 / 8};
    int wtotal = s0.nchunk + s1.nchunk + s2.nchunk + s3.nchunk + s4.nchunk;
    k_wconv<<<CDIV(wtotal, 256), 256, 0, stream>>>(s0, s1, s2, s3, s4, wtotal);

    // ---- CSR by dst (8x privatized) + deg_inv_sqrt ----
    hipMemsetAsync(cnt8, 0, sizeof(int) * 8 * (size_t)N, stream);
    k_detect<<<1, 64, 0, stream>>>(ei, flag);
    k_hist<<<CDIV(E, 256), 256, 0, stream>>>(ei, E, flag, cnt8, N);
    int nb = CDIV(N + 1, 1024);        // 196 <= 256
    k_blockred<<<nb, 256, 0, stream>>>(cnt8, bsum, N);
    k_scanpartials<<<1, 256, 0, stream>>>(bsum, nb);
    k_scanwrite<<<nb, 256, 0, stream>>>(cnt8, bsum, rowptr, cur8, dis, N);
    k_fill<<<CDIV(E, 256), 256, 0, stream>>>(ei, E, flag, cur8, csr, N);

    const int NB = CDIV(N, 128);       // 1563
    const int GB = CDIV(G, 128);       // 40

    // ---- conv1 (aggregate-first in 40->64-dim) ----
    k_pad<<<CDIV(N * 64, 256), 256, 0, stream>>>(x, xb, N);
    k_agg<64, false><<<CDIV(N, 32), 256, 0, stream>>>(xb, rowptr, csr, dis, nullptr, A1b, N);
    gemm_mfma<true, true, 1, false><<<dim3(1, NB), 256, 0, stream>>>(A1b, W1b, b1, H1, N, 64, H1d, 0);
    // ---- conv2 (aggregate-first in 128-dim) ----
    k_agg<128, false><<<CDIV(N, 16), 256, 0, stream>>>(H1, rowptr, csr, dis, nullptr, A2, N);
    gemm_mfma<true, true, 1, false><<<dim3(2, NB), 256, 0, stream>>>(A2, W2b, b2, H2, N, H1d, H2d, 0);
    // ---- conv3 (transform-first: 256 -> 128, aggregate in 128-dim) ----
    gemm_mfma<true, false, 0, false><<<dim3(1, NB), 256, 0, stream>>>(H2, W3b, nullptr, H3p, N, H2d, H3d, 0);
    k_agg<128, true><<<CDIV(N, 16), 256, 0, stream>>>(H3p, rowptr, csr, dis, b3, X3, N);

    // ---- readout MLP1: split-K S=6 (960 blocks), Kseg=896 ----
    gemm_mfma<false, false, 0, true><<<dim3(M1 / 128, GB, 6), 256, 0, stream>>>(X3, L1wb, nullptr, part, G, K1, M1, 896);
    k_red<6, true, 1><<<CDIV(G * M1 / 4, 256), 256, 0, stream>>>(part, L1b, g1b, G * M1, M1 - 1);
    // ---- readout MLP2: split-K S=4 + fused reduce/head ----
    gemm_mfma<false, false, 0, true><<<dim3(1, GB, 4), 256, 0, stream>>>(g1b, L2wb, nullptr, part, G, M1, M2, M1 / 4);
    k_head2<<<CDIV(G, 4), 256, 0, stream>>>(part, L2b, L3w, L3b, out, G);
}